// Round 9
// baseline (474.552 us; speedup 1.0000x reference)
//
#include <hip/hip_runtime.h>
#include <math.h>

#define HID 128
#define NSTR 6              // STRUCT-1
#define GAMMA 1.0f
#define DELTA 0.5f
#define LN_EPS 1e-5f
#define KPAD 72             // bf16 elems per LDS row (64 + 8 pad)

typedef __attribute__((ext_vector_type(4))) float f4;
typedef __attribute__((ext_vector_type(8))) short bf16x8;
typedef __attribute__((ext_vector_type(4))) float f32x4;

// f32 -> bf16 (round-to-nearest-even) and helpers
__device__ __forceinline__ unsigned short f2bf(float f) {
    unsigned u = __float_as_uint(f);
    unsigned r = u + 0x7FFFu + ((u >> 16) & 1u);
    return (unsigned short)(r >> 16);
}
__device__ __forceinline__ float bf2f(unsigned short h) {
    return __uint_as_float((unsigned)h << 16);
}
__device__ __forceinline__ void split2(float v, unsigned short& h, unsigned short& l) {
    h = f2bf(v);
    l = f2bf(v - bf2f(h));
}
__device__ __forceinline__ void bf2f2(unsigned u, float& lo, float& hi) {
    lo = __uint_as_float(u << 16);
    hi = __uint_as_float(u & 0xFFFF0000u);
}
__device__ __forceinline__ void unpack8(const uint4 u, float* f) {
    bf2f2(u.x, f[0], f[1]); bf2f2(u.y, f[2], f[3]);
    bf2f2(u.z, f[4], f[5]); bf2f2(u.w, f[6], f[7]);
}

// ---------------------------------------------------------------------------
// k_prep: split (optionally transpose) 4 weight matrices into WT slots.
// tr=1: table[c][k] = W[k][c] (for O = A@W);  tr=0: table[c][k] = W[c][k].
// ---------------------------------------------------------------------------
struct PrepArgs { const float* W[4]; int tr[4]; };

__global__ __launch_bounds__(256) void k_prep(PrepArgs p, unsigned short* WT)
{
    __shared__ float T[128][17];
    const int m = blockIdx.y, c0 = blockIdx.x * 16;
    const int tid = threadIdx.x;
    const float* __restrict__ W = p.W[m];
    unsigned short* hi = WT + (size_t)m * 2 * HID * HID;
    unsigned short* lo = hi + HID * HID;
    if (p.tr[m]) {
        for (int idx = tid; idx < 2048; idx += 256) {
            const int k = idx >> 4, c = idx & 15;
            T[k][c] = W[k * HID + c0 + c];
        }
        __syncthreads();
        for (int idx = tid; idx < 2048; idx += 256) {
            const int c = idx >> 7, k = idx & 127;
            unsigned short h, l;
            split2(T[k][c], h, l);
            hi[(size_t)(c0 + c) * HID + k] = h;
            lo[(size_t)(c0 + c) * HID + k] = l;
        }
    } else {
        for (int idx = tid; idx < 2048; idx += 256) {
            const int c = idx >> 7, k = idx & 127;
            unsigned short h, l;
            split2(W[(size_t)(c0 + c) * HID + k], h, l);
            hi[(size_t)(c0 + c) * HID + k] = h;
            lo[(size_t)(c0 + c) * HID + k] = l;
        }
    }
}

// k_m2: M2 = W_p @ W_pp^T split into slot (table for U = H @ M2^T)
__global__ __launch_bounds__(256) void k_m2(
    const float* __restrict__ Wp, const float* __restrict__ Wpp,
    unsigned short* __restrict__ slot)
{
    __shared__ float Bs[128][129];
    __shared__ float As[16][129];
    const int tid = threadIdx.x, c0 = blockIdx.x * 16;
    for (int idx = tid; idx < 128 * 128; idx += 256)
        Bs[idx >> 7][idx & 127] = Wpp[idx];
    for (int idx = tid; idx < 16 * 128; idx += 256)
        As[idx >> 7][idx & 127] = Wp[(size_t)(c0 + (idx >> 7)) * HID + (idx & 127)];
    __syncthreads();
    unsigned short* hi = slot;
    unsigned short* lo = slot + HID * HID;
    for (int it = 0; it < 8; ++it) {
        const int idx = tid + 256 * it;
        const int c = idx >> 7, k = idx & 127;
        float a = 0.f;
        #pragma unroll 4
        for (int j = 0; j < 128; ++j)
            a = fmaf(As[c][j], Bs[k][j], a);
        unsigned short h, l;
        split2(a, h, l);
        hi[(size_t)(c0 + c) * HID + k] = h;
        lo[(size_t)(c0 + c) * HID + k] = l;
    }
}

// HB = bf16(H)
__global__ __launch_bounds__(256) void k_cast(
    const float* __restrict__ H, unsigned short* __restrict__ HB, int total8)
{
    const int idx = blockIdx.x * 256 + threadIdx.x;
    if (idx >= total8) return;
    const size_t o = (size_t)idx * 8;
    const f4 v0 = *(const f4*)&H[o];
    const f4 v1 = *(const f4*)&H[o + 4];
    ushort4 a, b;
    a.x = f2bf(v0[0]); a.y = f2bf(v0[1]); a.z = f2bf(v0[2]); a.w = f2bf(v0[3]);
    b.x = f2bf(v1[0]); b.y = f2bf(v1[1]); b.z = f2bf(v1[2]); b.w = f2bf(v1[3]);
    *(ushort4*)&HB[o] = a;
    *(ushort4*)&HB[o + 4] = b;
}

struct GemmArgsT {
    const unsigned short* Whi[3];
    const unsigned short* Wlo[3];
    const float*          b[3];
    void*                 O[3];
    int                   of32[3];
};

// ---------------------------------------------------------------------------
// MFMA GEMM: O[ph] = A @ B[ph] (+b), split-precision (hi/lo bf16, 3 MFMA).
// ---------------------------------------------------------------------------
__global__ __launch_bounds__(256, 2) void k_gemm(const float* __restrict__ A,
                                                 GemmArgsT g, int N)
{
    extern __shared__ unsigned short lds[];
    unsigned short* Ahi = lds;
    unsigned short* Alo = lds + 128 * KPAD;
    unsigned short* Bhi = lds + 2 * 128 * KPAD;
    unsigned short* Blo = lds + 3 * 128 * KPAD;
    const int tid  = threadIdx.x;
    const int row0 = blockIdx.x * 128;
    const int nrows = min(128, N - row0);
    const int ph   = blockIdx.y;
    const int w    = tid >> 6, lane = tid & 63;
    const int lrow = lane & 15, kgrp = lane >> 4;

    const float* bp = g.b[ph];
    f32x4 acc[2][8];
    #pragma unroll
    for (int tc = 0; tc < 8; ++tc) {
        const float bv = bp ? bp[tc * 16 + lrow] : 0.f;
        acc[0][tc] = f32x4{bv, bv, bv, bv};
        acc[1][tc] = f32x4{bv, bv, bv, bv};
    }

    const unsigned short* __restrict__ Wh = g.Whi[ph];
    const unsigned short* __restrict__ Wl = g.Wlo[ph];

    for (int ch = 0; ch < 2; ++ch) {
        __syncthreads();
        #pragma unroll
        for (int it = 0; it < 8; ++it) {
            const int idx = tid + 256 * it;
            const int r = idx >> 4, kq = (idx & 15) * 4;
            f4 v = {0.f, 0.f, 0.f, 0.f};
            if (r < nrows) v = *(const f4*)&A[(size_t)(row0 + r) * HID + ch * 64 + kq];
            ushort4 h, l;
            split2(v[0], h.x, l.x); split2(v[1], h.y, l.y);
            split2(v[2], h.z, l.z); split2(v[3], h.w, l.w);
            *(ushort4*)&Ahi[r * KPAD + kq] = h;
            *(ushort4*)&Alo[r * KPAD + kq] = l;
        }
        #pragma unroll
        for (int it = 0; it < 4; ++it) {
            const int idx = tid + 256 * it;
            const int c = idx >> 3, k8 = (idx & 7) * 8;
            *(uint4*)&Bhi[c * KPAD + k8] = *(const uint4*)&Wh[(size_t)c * HID + ch * 64 + k8];
            *(uint4*)&Blo[c * KPAD + k8] = *(const uint4*)&Wl[(size_t)c * HID + ch * 64 + k8];
        }
        __syncthreads();

        #pragma unroll
        for (int ks = 0; ks < 2; ++ks) {
            const int ko = ks * 32 + kgrp * 8;
            bf16x8 ah[2], al[2], bh[8], bl[8];
            #pragma unroll
            for (int tr = 0; tr < 2; ++tr) {
                const int rr = w * 32 + tr * 16 + lrow;
                ah[tr] = *(const bf16x8*)&Ahi[rr * KPAD + ko];
                al[tr] = *(const bf16x8*)&Alo[rr * KPAD + ko];
            }
            #pragma unroll
            for (int tc = 0; tc < 8; ++tc) {
                const int cc = tc * 16 + lrow;
                bh[tc] = *(const bf16x8*)&Bhi[cc * KPAD + ko];
                bl[tc] = *(const bf16x8*)&Blo[cc * KPAD + ko];
            }
            #pragma unroll
            for (int tr = 0; tr < 2; ++tr)
                #pragma unroll
                for (int tc = 0; tc < 8; ++tc) {
                    acc[tr][tc] = __builtin_amdgcn_mfma_f32_16x16x32_bf16(ah[tr], bh[tc], acc[tr][tc], 0, 0, 0);
                    acc[tr][tc] = __builtin_amdgcn_mfma_f32_16x16x32_bf16(al[tr], bh[tc], acc[tr][tc], 0, 0, 0);
                    acc[tr][tc] = __builtin_amdgcn_mfma_f32_16x16x32_bf16(ah[tr], bl[tc], acc[tr][tc], 0, 0, 0);
                }
        }
    }

    #pragma unroll
    for (int tr = 0; tr < 2; ++tr)
        #pragma unroll
        for (int j = 0; j < 4; ++j) {
            const int r = w * 32 + tr * 16 + kgrp * 4 + j;
            if (r < nrows) {
                if (g.of32[ph]) {
                    float* O = (float*)g.O[ph];
                    #pragma unroll
                    for (int tc = 0; tc < 8; ++tc)
                        O[(size_t)(row0 + r) * HID + tc * 16 + lrow] = acc[tr][tc][j];
                } else {
                    unsigned short* O = (unsigned short*)g.O[ph];
                    #pragma unroll
                    for (int tc = 0; tc < 8; ++tc)
                        O[(size_t)(row0 + r) * HID + tc * 16 + lrow] = f2bf(acc[tr][tc][j]);
                }
            }
        }
}

// ---------------------------------------------------------------------------
// k_final: out = LN(relu(Matt@WA + H@Wself + s@Wstr + biases) + H)
// Matt f32 (split, 3 MFMA); H split (3 MFMA). ReLU+resid+LN fused.
// ---------------------------------------------------------------------------
__global__ __launch_bounds__(256, 2) void k_final(
    const float* __restrict__ Matt, const float* __restrict__ H,
    const unsigned short* __restrict__ WAhi, const unsigned short* __restrict__ WAlo,
    const unsigned short* __restrict__ WShi, const unsigned short* __restrict__ WSlo,
    const float* __restrict__ Wstr,
    const float* __restrict__ bself, const float* __restrict__ bA,
    const float* __restrict__ bstr,
    const float* __restrict__ lng, const float* __restrict__ lnb,
    float* __restrict__ out, int N)
{
    extern __shared__ unsigned short lds[];
    unsigned short* Ahi = lds;
    unsigned short* Alo = lds + 128 * KPAD;
    unsigned short* Bhi = lds + 2 * 128 * KPAD;
    unsigned short* Blo = lds + 3 * 128 * KPAD;
    const int tid  = threadIdx.x;
    const int row0 = blockIdx.x * 128;
    const int nrows = min(128, N - row0);
    const int w    = tid >> 6, lane = tid & 63;
    const int lrow = lane & 15, kgrp = lane >> 4;

    f32x4 acc[2][8];
    float gl[8], bl_[8];
    #pragma unroll
    for (int tc = 0; tc < 8; ++tc) {
        const int c = tc * 16 + lrow;
        const float bv = bself[c] + bA[c] + bstr[c];
        acc[0][tc] = f32x4{bv, bv, bv, bv};
        acc[1][tc] = f32x4{bv, bv, bv, bv};
        gl[tc] = lng[c]; bl_[tc] = lnb[c];
    }

    for (int ph = 0; ph < 2; ++ph) {
        const float* __restrict__ Am = ph ? H : Matt;
        const unsigned short* __restrict__ Wh = ph ? WShi : WAhi;
        const unsigned short* __restrict__ Wl = ph ? WSlo : WAlo;
        for (int ch = 0; ch < 2; ++ch) {
            __syncthreads();
            #pragma unroll
            for (int it = 0; it < 8; ++it) {
                const int idx = tid + 256 * it;
                const int r = idx >> 4, kq = (idx & 15) * 4;
                f4 v = {0.f, 0.f, 0.f, 0.f};
                if (r < nrows) v = *(const f4*)&Am[(size_t)(row0 + r) * HID + ch * 64 + kq];
                ushort4 h, l;
                split2(v[0], h.x, l.x); split2(v[1], h.y, l.y);
                split2(v[2], h.z, l.z); split2(v[3], h.w, l.w);
                *(ushort4*)&Ahi[r * KPAD + kq] = h;
                *(ushort4*)&Alo[r * KPAD + kq] = l;
            }
            #pragma unroll
            for (int it = 0; it < 4; ++it) {
                const int idx = tid + 256 * it;
                const int c = idx >> 3, k8 = (idx & 7) * 8;
                *(uint4*)&Bhi[c * KPAD + k8] = *(const uint4*)&Wh[(size_t)c * HID + ch * 64 + k8];
                *(uint4*)&Blo[c * KPAD + k8] = *(const uint4*)&Wl[(size_t)c * HID + ch * 64 + k8];
            }
            __syncthreads();

            #pragma unroll
            for (int ks = 0; ks < 2; ++ks) {
                const int ko = ks * 32 + kgrp * 8;
                bf16x8 ah[2], al[2], bh[8], bl[8];
                #pragma unroll
                for (int tr = 0; tr < 2; ++tr) {
                    const int rr = w * 32 + tr * 16 + lrow;
                    ah[tr] = *(const bf16x8*)&Ahi[rr * KPAD + ko];
                    al[tr] = *(const bf16x8*)&Alo[rr * KPAD + ko];
                }
                #pragma unroll
                for (int tc = 0; tc < 8; ++tc) {
                    const int cc = tc * 16 + lrow;
                    bh[tc] = *(const bf16x8*)&Bhi[cc * KPAD + ko];
                    bl[tc] = *(const bf16x8*)&Blo[cc * KPAD + ko];
                }
                #pragma unroll
                for (int tr = 0; tr < 2; ++tr)
                    #pragma unroll
                    for (int tc = 0; tc < 8; ++tc) {
                        acc[tr][tc] = __builtin_amdgcn_mfma_f32_16x16x32_bf16(ah[tr], bh[tc], acc[tr][tc], 0, 0, 0);
                        acc[tr][tc] = __builtin_amdgcn_mfma_f32_16x16x32_bf16(al[tr], bh[tc], acc[tr][tc], 0, 0, 0);
                        acc[tr][tc] = __builtin_amdgcn_mfma_f32_16x16x32_bf16(ah[tr], bl[tc], acc[tr][tc], 0, 0, 0);
                    }
            }

            if (ph == 1 && ch == 0) {
                #pragma unroll
                for (int tr = 0; tr < 2; ++tr)
                    #pragma unroll
                    for (int j = 0; j < 4; ++j) {
                        const int rr = w * 32 + tr * 16 + kgrp * 4 + j;
                        float s[NSTR];
                        #pragma unroll
                        for (int k = 0; k < NSTR; ++k)
                            s[k] = bf2f(Ahi[rr * KPAD + k]) + bf2f(Alo[rr * KPAD + k]);
                        #pragma unroll
                        for (int tc = 0; tc < 8; ++tc) {
                            float a = 0.f;
                            #pragma unroll
                            for (int k = 0; k < NSTR; ++k)
                                a = fmaf(s[k], Wstr[k * HID + tc * 16 + lrow], a);
                            acc[tr][tc][j] += a;
                        }
                    }
            }
        }
    }

    #pragma unroll
    for (int tr = 0; tr < 2; ++tr)
        #pragma unroll
        for (int j = 0; j < 4; ++j) {
            const int r = w * 32 + tr * 16 + kgrp * 4 + j;
            const bool valid = r < nrows;
            const size_t rb = (size_t)(row0 + r) * HID;
            float v[8], s1 = 0.f, s2 = 0.f;
            #pragma unroll
            for (int tc = 0; tc < 8; ++tc) {
                float x = fmaxf(acc[tr][tc][j], 0.f);
                if (valid) x += H[rb + tc * 16 + lrow];
                v[tc] = x;
                s1 += x; s2 += x * x;
            }
            #pragma unroll
            for (int mk = 1; mk < 16; mk <<= 1) {
                s1 += __shfl_xor(s1, mk);
                s2 += __shfl_xor(s2, mk);
            }
            const float mean = s1 * (1.f / HID);
            const float var  = s2 * (1.f / HID) - mean * mean;
            const float rs   = rsqrtf(var + LN_EPS);
            if (valid) {
                #pragma unroll
                for (int tc = 0; tc < 8; ++tc)
                    out[rb + tc * 16 + lrow] = (v[tc] - mean) * rs * gl[tc] + bl_[tc];
            }
        }
}

// psi[n] = dot(H[n], f_def_w) + f_def_b   (wave per node)
__global__ __launch_bounds__(256) void k_psi(
    const float* __restrict__ H, const float* __restrict__ fw, const float* __restrict__ fb,
    float* __restrict__ psi, int N)
{
    const int wid = threadIdx.x >> 6, lane = threadIdx.x & 63;
    const int n = blockIdx.x * 4 + wid;
    if (n >= N) return;
    const size_t o = (size_t)n * HID;
    float a = H[o + lane] * fw[lane] + H[o + 64 + lane] * fw[64 + lane];
    #pragma unroll
    for (int off = 32; off; off >>= 1) a += __shfl_down(a, off);
    if (lane == 0) psi[n] = a + fb[0];
}

// ---------------------------------------------------------------------------
// Dual CSR build: one histogram pass (both), one 2-block scan, one fill pass
// ---------------------------------------------------------------------------
__global__ __launch_bounds__(256) void k_hist2(
    const int* __restrict__ esrc, const int* __restrict__ etgt,
    int* __restrict__ deg_t, int* __restrict__ deg_s, int E)
{
    const int e = blockIdx.x * 256 + threadIdx.x;
    if (e < E) {
        atomicAdd(&deg_t[etgt[e]], 1);
        atomicAdd(&deg_s[esrc[e]], 1);
    }
}

__global__ __launch_bounds__(1024) void k_scan2(
    const int* __restrict__ deg_t, int* __restrict__ base_t,
    const int* __restrict__ deg_s, int* __restrict__ base_s, int N)
{
    const int* deg  = blockIdx.x ? deg_s  : deg_t;
    int*       base = blockIdx.x ? base_s : base_t;
    __shared__ int warp_sums[16];
    __shared__ int carry_s;
    const int tid = threadIdx.x, lane = tid & 63, wid = tid >> 6;
    if (tid == 0) carry_s = 0;
    __syncthreads();
    for (int i0 = 0; i0 < N; i0 += 1024) {
        const int i = i0 + tid;
        const int v = (i < N) ? deg[i] : 0;
        int x = v;
        #pragma unroll
        for (int d = 1; d < 64; d <<= 1) {
            const int y = __shfl_up(x, d);
            if (lane >= d) x += y;
        }
        if (lane == 63) warp_sums[wid] = x;
        __syncthreads();
        if (wid == 0) {
            int ws = (lane < 16) ? warp_sums[lane] : 0;
            #pragma unroll
            for (int d = 1; d < 16; d <<= 1) {
                const int y = __shfl_up(ws, d);
                if (lane >= d) ws += y;
            }
            if (lane < 16) warp_sums[lane] = ws;
        }
        __syncthreads();
        const int carry = carry_s;
        if (i < N) base[i] = carry + (wid ? warp_sums[wid - 1] : 0) + x - v;
        __syncthreads();
        if (tid == 1023) carry_s = carry + warp_sums[15];
        __syncthreads();
    }
    if (tid == 0) base[N] = carry_s;
}

__global__ __launch_bounds__(256) void k_fill2(
    const int* __restrict__ esrc, const int* __restrict__ etgt,
    const int* __restrict__ base_t, int* __restrict__ cur_t,
    const int* __restrict__ base_s, int* __restrict__ cur_s,
    int* __restrict__ eid_t, int* __restrict__ pos_s,
    int* __restrict__ etgt_s, int E)
{
    const int e = blockIdx.x * 256 + threadIdx.x;
    if (e < E) {
        const int t = etgt[e], s = esrc[e];
        const int p = atomicAdd(&cur_t[t], 1);
        eid_t[base_t[t] + p] = e;
        const int q = atomicAdd(&cur_s[s], 1);
        const int slot = base_s[s] + q;
        pos_s[e] = slot;
        etgt_s[slot] = t;
    }
}

// ---------------------------------------------------------------------------
// k_score: wave per TARGET node, 16-lane edge groups, single 256B gather/edge.
// No atomics: pair scores scattered to CSR-src slots (plain store).
// ---------------------------------------------------------------------------
__global__ __launch_bounds__(256) void k_score(
    const int* __restrict__ eid_t, const int* __restrict__ base_t,
    const int* __restrict__ esrc, const int* __restrict__ pos_s,
    const float* __restrict__ Wt,
    const unsigned short* __restrict__ UB,
    const unsigned short* __restrict__ HB,
    float* __restrict__ score, float* __restrict__ pairv_csr,
    float* __restrict__ sumt_inv, int N)
{
    const int lane = threadIdx.x & 63, wv = threadIdx.x >> 6;
    const int t = blockIdx.x * 4 + wv;
    if (t >= N) return;
    const int b0 = base_t[t], deg = base_t[t + 1] - b0;
    if (deg == 0) { if (lane == 0) sumt_inv[t] = 0.f; return; }
    const int sub = lane & 15, grp = lane >> 4;
    const size_t to = (size_t)t * HID;

    float wt[8], u[8], htg[8];
    {
        const f4 w0 = *(const f4*)&Wt[to + sub * 8];
        const f4 w1 = *(const f4*)&Wt[to + sub * 8 + 4];
        wt[0] = w0[0]; wt[1] = w0[1]; wt[2] = w0[2]; wt[3] = w0[3];
        wt[4] = w1[0]; wt[5] = w1[1]; wt[6] = w1[2]; wt[7] = w1[3];
        unpack8(*(const uint4*)&UB[to + sub * 8], u);
        unpack8(*(const uint4*)&HB[to + sub * 8], htg);
    }

    for (int j0 = 0; j0 < deg; j0 += 4) {
        const int jj = j0 + grp;
        const bool val = jj < deg;
        int eid = 0, src = 0;
        if (val) { eid = eid_t[b0 + jj]; src = esrc[eid]; }
        const size_t so = (size_t)src * HID;
        float hs[8];
        unpack8(*(const uint4*)&HB[so + sub * 8], hs);
        float ps = 0.f, pp = 0.f;
        #pragma unroll
        for (int d = 0; d < 8; ++d) {
            ps = fmaf(wt[d], hs[d], ps);
            pp = fmaf(u[d], hs[d], pp);
        }
        if (sub == 0) {
            #pragma unroll
            for (int d = 0; d < NSTR; ++d) ps = fmaf(htg[d], hs[d], ps);
        }
        #pragma unroll
        for (int mk = 1; mk < 16; mk <<= 1) {
            ps += __shfl_xor(ps, mk);
            pp += __shfl_xor(pp, mk);
        }
        if (sub == 0 && val) {
            score[b0 + jj] = ps;
            pairv_csr[pos_s[eid]] = pp;
        }
    }

    float m = -1e30f;
    for (int i = lane; i < deg; i += 64) m = fmaxf(m, score[b0 + i]);
    #pragma unroll
    for (int mk = 1; mk < 64; mk <<= 1) m = fmaxf(m, __shfl_xor(m, mk));
    float psum = 0.f;
    for (int i = lane; i < deg; i += 64) {
        const float e = expf(score[b0 + i] - m);
        score[b0 + i] = e;
        psum += e;
    }
    #pragma unroll
    for (int mk = 1; mk < 64; mk <<= 1) psum += __shfl_xor(psum, mk);
    if (lane == 0) sumt_inv[t] = 1.f / psum;
}

// ---------------------------------------------------------------------------
// k_beta2: wave per SOURCE node, streaming (no atomics); fuses rho.
// beta softmax over pairv_csr slice; sum_term = sum(e*exp(-psi_t))/sum(e);
// rho1m = 1 - sigmoid(GAMMA*(-log(st+1e-8)-DELTA))
// ---------------------------------------------------------------------------
__global__ __launch_bounds__(256) void k_beta2(
    const int* __restrict__ base_s, const int* __restrict__ etgt_s,
    const float* __restrict__ pairv_csr, const float* __restrict__ psi,
    float* __restrict__ rho1m, int N)
{
    const int lane = threadIdx.x & 63, wv = threadIdx.x >> 6;
    const int s = blockIdx.x * 4 + wv;
    if (s >= N) return;
    const int b0 = base_s[s], deg = base_s[s + 1] - b0;

    float m = -1e30f;
    for (int i = lane; i < deg; i += 64) m = fmaxf(m, pairv_csr[b0 + i]);
    #pragma unroll
    for (int mk = 1; mk < 64; mk <<= 1) m = fmaxf(m, __shfl_xor(m, mk));

    float se = 0.f, sn = 0.f;
    for (int i = lane; i < deg; i += 64) {
        const float e = expf(pairv_csr[b0 + i] - m);
        se += e;
        sn += e * expf(-psi[etgt_s[b0 + i]]);
    }
    #pragma unroll
    for (int mk = 1; mk < 64; mk <<= 1) {
        se += __shfl_xor(se, mk);
        sn += __shfl_xor(sn, mk);
    }
    if (lane == 0) {
        const float st = (deg > 0 && se > 0.f) ? sn / se : 0.f;
        const float d  = -logf(st + 1e-8f);
        rho1m[s] = 1.f - 1.f / (1.f + expf(-(GAMMA * (d - DELTA))));
    }
}

// ---------------------------------------------------------------------------
// k_matt: wave per TARGET, 16-lane edge groups; Hphi bf16 gather; out f32.
// ---------------------------------------------------------------------------
__global__ __launch_bounds__(256) void k_matt(
    const int* __restrict__ eid_t, const int* __restrict__ base_t,
    const int* __restrict__ esrc,
    const float* __restrict__ score, const float* __restrict__ sumt_inv,
    const float* __restrict__ rho1m,
    const unsigned short* __restrict__ HphiB,
    float* __restrict__ matt, int N)
{
    const int lane = threadIdx.x & 63, wv = threadIdx.x >> 6;
    const int t = blockIdx.x * 4 + wv;
    if (t >= N) return;
    const int b0 = base_t[t], deg = base_t[t + 1] - b0;
    const int sub = lane & 15, grp = lane >> 4;
    const size_t to = (size_t)t * HID;

    float acc[8];
    #pragma unroll
    for (int d = 0; d < 8; ++d) acc[d] = 0.f;
    const float inv = (deg > 0) ? sumt_inv[t] : 0.f;

    for (int j0 = 0; j0 < deg; j0 += 4) {
        const int jj = j0 + grp;
        const bool val = jj < deg;
        float c = 0.f;
        size_t so = 0;
        if (val) {
            const int eid = eid_t[b0 + jj];
            const int src = esrc[eid];
            c = score[b0 + jj] * inv * rho1m[src];
            so = (size_t)src * HID;
        }
        float hf[8];
        unpack8(*(const uint4*)&HphiB[so + sub * 8], hf);
        #pragma unroll
        for (int d = 0; d < 8; ++d) acc[d] = fmaf(c, hf[d], acc[d]);
    }
    #pragma unroll
    for (int d = 0; d < 8; ++d) {
        acc[d] += __shfl_xor(acc[d], 16);
        acc[d] += __shfl_xor(acc[d], 32);
    }
    if (grp == 0) {
        f4 o0, o1;
        #pragma unroll
        for (int d = 0; d < 4; ++d) { o0[d] = acc[d]; o1[d] = acc[d + 4]; }
        *(f4*)&matt[to + sub * 8]     = o0;
        *(f4*)&matt[to + sub * 8 + 4] = o1;
    }
}

extern "C" void kernel_launch(void* const* d_in, const int* in_sizes, int n_in,
                              void* d_out, int out_size, void* d_ws, size_t ws_size,
                              hipStream_t stream)
{
    const int*   eidx   = (const int*)  d_in[0];
    const float* H      = (const float*)d_in[1];
    const float* W_att  = (const float*)d_in[2];
    const float* phi_w  = (const float*)d_in[3];
    const float* phi_b  = (const float*)d_in[4];
    const float* W_p    = (const float*)d_in[5];
    const float* W_pp   = (const float*)d_in[6];
    const float* fdef_w = (const float*)d_in[7];
    const float* fdef_b = (const float*)d_in[8];
    const float* Wself  = (const float*)d_in[9];
    const float* bself  = (const float*)d_in[10];
    const float* WA     = (const float*)d_in[11];
    const float* bA     = (const float*)d_in[12];
    const float* Wstr   = (const float*)d_in[13];
    const float* bstr   = (const float*)d_in[14];
    const float* lng    = (const float*)d_in[15];
    const float* lnb    = (const float*)d_in[16];
    float* out = (float*)d_out;

    const int E = in_sizes[0] / 2;
    const int N = in_sizes[1] / HID;
    const int* esrc = eidx;
    const int* etgt = eidx + E;

    // ---- workspace layout (~82 MB) ----
    char* w = (char*)d_ws;
    const size_t NHb  = (size_t)N * HID * sizeof(unsigned short);
    const size_t NH   = (size_t)N * HID * sizeof(float);
    const size_t Epad = (((size_t)E * sizeof(float)) + 255) & ~255ull;
    const size_t Npad = (((size_t)(N + 1) * sizeof(float)) + 255) & ~255ull;

    float*          Wt    = (float*)w;          w += NH;   // f32 tgt table; matt aliases after k_score
    unsigned short* UB    = (unsigned short*)w; w += NHb;
    unsigned short* HB    = (unsigned short*)w; w += NHb;
    unsigned short* HphiB = (unsigned short*)w; w += NHb;
    float* score     = (float*)w; w += Epad;  // CSR-tgt order
    float* pairv_csr = (float*)w; w += Epad;  // CSR-src order
    int*   eid_t     = (int*)  w; w += Epad;
    int*   pos_s     = (int*)  w; w += Epad;
    int*   etgt_s    = (int*)  w; w += Epad;
    char*  zero0 = w;                         // 4 contiguous zero-init arrays
    int*   deg_t = (int*)w; w += Npad;
    int*   cur_t = (int*)w; w += Npad;
    int*   deg_s = (int*)w; w += Npad;
    int*   cur_s = (int*)w; w += Npad;
    int*   base_t   = (int*)  w; w += Npad;   // N+1
    int*   base_s   = (int*)  w; w += Npad;   // N+1
    float* sumt_inv = (float*)w; w += Npad;
    float* psi      = (float*)w; w += Npad;
    float* rho1m    = (float*)w; w += Npad;
    unsigned short* WT = (unsigned short*)w;  // 5 slots x 2 planes x 128x128
    w += 5 * 2 * HID * HID * sizeof(unsigned short);
    float* matt = Wt;   // alias: Wt dead after k_score

    const int nblk128 = (N + 127) / 128;
    const int nblkN4  = (N + 3) / 4;
    const int nblkE   = (E + 255) / 256;
    const size_t lds_mfma = 4 * 128 * KPAD * sizeof(unsigned short);  // 72 KB
    const size_t MSZ = (size_t)2 * HID * HID;

    hipMemsetAsync(zero0, 0, 4 * Npad, stream);  // deg_t, cur_t, deg_s, cur_s

    PrepArgs pa;
    pa.W[0] = W_att; pa.tr[0] = 0;
    pa.W[1] = phi_w; pa.tr[1] = 1;
    pa.W[2] = WA;    pa.tr[2] = 1;
    pa.W[3] = Wself; pa.tr[3] = 1;
    k_prep<<<dim3(8, 4), 256, 0, stream>>>(pa, WT);
    k_m2<<<8, 256, 0, stream>>>(W_p, W_pp, WT + 4 * MSZ);

    k_cast<<<(N * HID / 8 + 255) / 256, 256, 0, stream>>>(H, HB, N * HID / 8);

    GemmArgsT g3;
    g3.Whi[0] = WT;            g3.Wlo[0] = WT + HID * HID;
    g3.Whi[1] = WT + 4 * MSZ;  g3.Wlo[1] = WT + 4 * MSZ + HID * HID;
    g3.Whi[2] = WT + 1 * MSZ;  g3.Wlo[2] = WT + 1 * MSZ + HID * HID;
    g3.b[0] = nullptr; g3.b[1] = nullptr; g3.b[2] = phi_b;
    g3.O[0] = Wt;    g3.of32[0] = 1;
    g3.O[1] = UB;    g3.of32[1] = 0;
    g3.O[2] = HphiB; g3.of32[2] = 0;
    k_gemm<<<dim3(nblk128, 3), 256, lds_mfma, stream>>>(H, g3, N);

    k_psi<<<nblkN4, 256, 0, stream>>>(H, fdef_w, fdef_b, psi, N);

    k_hist2<<<nblkE, 256, 0, stream>>>(esrc, etgt, deg_t, deg_s, E);
    k_scan2<<<2, 1024, 0, stream>>>(deg_t, base_t, deg_s, base_s, N);
    k_fill2<<<nblkE, 256, 0, stream>>>(esrc, etgt, base_t, cur_t, base_s, cur_s,
                                       eid_t, pos_s, etgt_s, E);

    k_score<<<nblkN4, 256, 0, stream>>>(eid_t, base_t, esrc, pos_s, Wt, UB, HB,
                                        score, pairv_csr, sumt_inv, N);
    k_beta2<<<nblkN4, 256, 0, stream>>>(base_s, etgt_s, pairv_csr, psi, rho1m, N);

    k_matt<<<nblkN4, 256, 0, stream>>>(eid_t, base_t, esrc, score, sumt_inv,
                                       rho1m, HphiB, matt, N);

    k_final<<<nblk128, 256, lds_mfma, stream>>>(matt, H,
                                                WT + 2 * MSZ, WT + 2 * MSZ + HID * HID,
                                                WT + 3 * MSZ, WT + 3 * MSZ + HID * HID,
                                                Wstr, bself, bA, bstr, lng, lnb, out, N);
}

// Round 10
// 370.825 us; speedup vs baseline: 1.2797x; 1.2797x over previous
//
#include <hip/hip_runtime.h>
#include <math.h>

#define HID 128
#define NSTR 6              // STRUCT-1
#define GAMMA 1.0f
#define DELTA 0.5f
#define LN_EPS 1e-5f
#define KPAD 72             // bf16 elems per LDS row (64 + 8 pad)
#define CSR_CHUNK 8192      // edges per block in CSR build

typedef __attribute__((ext_vector_type(4))) float f4;
typedef __attribute__((ext_vector_type(8))) short bf16x8;
typedef __attribute__((ext_vector_type(4))) float f32x4;

// f32 -> bf16 (round-to-nearest-even) and helpers
__device__ __forceinline__ unsigned short f2bf(float f) {
    unsigned u = __float_as_uint(f);
    unsigned r = u + 0x7FFFu + ((u >> 16) & 1u);
    return (unsigned short)(r >> 16);
}
__device__ __forceinline__ float bf2f(unsigned short h) {
    return __uint_as_float((unsigned)h << 16);
}
__device__ __forceinline__ void split2(float v, unsigned short& h, unsigned short& l) {
    h = f2bf(v);
    l = f2bf(v - bf2f(h));
}
__device__ __forceinline__ void bf2f2(unsigned u, float& lo, float& hi) {
    lo = __uint_as_float(u << 16);
    hi = __uint_as_float(u & 0xFFFF0000u);
}
__device__ __forceinline__ void unpack8(const uint4 u, float* f) {
    bf2f2(u.x, f[0], f[1]); bf2f2(u.y, f[2], f[3]);
    bf2f2(u.z, f[4], f[5]); bf2f2(u.w, f[6], f[7]);
}

// ---------------------------------------------------------------------------
// k_prep: split (optionally transpose) 4 weight matrices into WT slots.
// ---------------------------------------------------------------------------
struct PrepArgs { const float* W[4]; int tr[4]; };

__global__ __launch_bounds__(256) void k_prep(PrepArgs p, unsigned short* WT)
{
    __shared__ float T[128][17];
    const int m = blockIdx.y, c0 = blockIdx.x * 16;
    const int tid = threadIdx.x;
    const float* __restrict__ W = p.W[m];
    unsigned short* hi = WT + (size_t)m * 2 * HID * HID;
    unsigned short* lo = hi + HID * HID;
    if (p.tr[m]) {
        for (int idx = tid; idx < 2048; idx += 256) {
            const int k = idx >> 4, c = idx & 15;
            T[k][c] = W[k * HID + c0 + c];
        }
        __syncthreads();
        for (int idx = tid; idx < 2048; idx += 256) {
            const int c = idx >> 7, k = idx & 127;
            unsigned short h, l;
            split2(T[k][c], h, l);
            hi[(size_t)(c0 + c) * HID + k] = h;
            lo[(size_t)(c0 + c) * HID + k] = l;
        }
    } else {
        for (int idx = tid; idx < 2048; idx += 256) {
            const int c = idx >> 7, k = idx & 127;
            unsigned short h, l;
            split2(W[(size_t)(c0 + c) * HID + k], h, l);
            hi[(size_t)(c0 + c) * HID + k] = h;
            lo[(size_t)(c0 + c) * HID + k] = l;
        }
    }
}

// k_m2: M2 = W_p @ W_pp^T split into slot
__global__ __launch_bounds__(256) void k_m2(
    const float* __restrict__ Wp, const float* __restrict__ Wpp,
    unsigned short* __restrict__ slot)
{
    __shared__ float Bs[128][129];
    __shared__ float As[16][129];
    const int tid = threadIdx.x, c0 = blockIdx.x * 16;
    for (int idx = tid; idx < 128 * 128; idx += 256)
        Bs[idx >> 7][idx & 127] = Wpp[idx];
    for (int idx = tid; idx < 16 * 128; idx += 256)
        As[idx >> 7][idx & 127] = Wp[(size_t)(c0 + (idx >> 7)) * HID + (idx & 127)];
    __syncthreads();
    unsigned short* hi = slot;
    unsigned short* lo = slot + HID * HID;
    for (int it = 0; it < 8; ++it) {
        const int idx = tid + 256 * it;
        const int c = idx >> 7, k = idx & 127;
        float a = 0.f;
        #pragma unroll 4
        for (int j = 0; j < 128; ++j)
            a = fmaf(As[c][j], Bs[k][j], a);
        unsigned short h, l;
        split2(a, h, l);
        hi[(size_t)(c0 + c) * HID + k] = h;
        lo[(size_t)(c0 + c) * HID + k] = l;
    }
}

// HB = bf16(H)
__global__ __launch_bounds__(256) void k_cast(
    const float* __restrict__ H, unsigned short* __restrict__ HB, int total8)
{
    const int idx = blockIdx.x * 256 + threadIdx.x;
    if (idx >= total8) return;
    const size_t o = (size_t)idx * 8;
    const f4 v0 = *(const f4*)&H[o];
    const f4 v1 = *(const f4*)&H[o + 4];
    ushort4 a, b;
    a.x = f2bf(v0[0]); a.y = f2bf(v0[1]); a.z = f2bf(v0[2]); a.w = f2bf(v0[3]);
    b.x = f2bf(v1[0]); b.y = f2bf(v1[1]); b.z = f2bf(v1[2]); b.w = f2bf(v1[3]);
    *(ushort4*)&HB[o] = a;
    *(ushort4*)&HB[o + 4] = b;
}

struct GemmArgsT {
    const unsigned short* Whi[3];
    const unsigned short* Wlo[3];
    const float*          b[3];
    void*                 O[3];
    int                   of32[3];
};

// ---------------------------------------------------------------------------
// MFMA GEMM: O[ph] = A @ B[ph] (+b), split-precision (hi/lo bf16, 3 MFMA).
// ---------------------------------------------------------------------------
__global__ __launch_bounds__(256, 2) void k_gemm(const float* __restrict__ A,
                                                 GemmArgsT g, int N)
{
    extern __shared__ unsigned short lds[];
    unsigned short* Ahi = lds;
    unsigned short* Alo = lds + 128 * KPAD;
    unsigned short* Bhi = lds + 2 * 128 * KPAD;
    unsigned short* Blo = lds + 3 * 128 * KPAD;
    const int tid  = threadIdx.x;
    const int row0 = blockIdx.x * 128;
    const int nrows = min(128, N - row0);
    const int ph   = blockIdx.y;
    const int w    = tid >> 6, lane = tid & 63;
    const int lrow = lane & 15, kgrp = lane >> 4;

    const float* bp = g.b[ph];
    f32x4 acc[2][8];
    #pragma unroll
    for (int tc = 0; tc < 8; ++tc) {
        const float bv = bp ? bp[tc * 16 + lrow] : 0.f;
        acc[0][tc] = f32x4{bv, bv, bv, bv};
        acc[1][tc] = f32x4{bv, bv, bv, bv};
    }

    const unsigned short* __restrict__ Wh = g.Whi[ph];
    const unsigned short* __restrict__ Wl = g.Wlo[ph];

    for (int ch = 0; ch < 2; ++ch) {
        __syncthreads();
        #pragma unroll
        for (int it = 0; it < 8; ++it) {
            const int idx = tid + 256 * it;
            const int r = idx >> 4, kq = (idx & 15) * 4;
            f4 v = {0.f, 0.f, 0.f, 0.f};
            if (r < nrows) v = *(const f4*)&A[(size_t)(row0 + r) * HID + ch * 64 + kq];
            ushort4 h, l;
            split2(v[0], h.x, l.x); split2(v[1], h.y, l.y);
            split2(v[2], h.z, l.z); split2(v[3], h.w, l.w);
            *(ushort4*)&Ahi[r * KPAD + kq] = h;
            *(ushort4*)&Alo[r * KPAD + kq] = l;
        }
        #pragma unroll
        for (int it = 0; it < 4; ++it) {
            const int idx = tid + 256 * it;
            const int c = idx >> 3, k8 = (idx & 7) * 8;
            *(uint4*)&Bhi[c * KPAD + k8] = *(const uint4*)&Wh[(size_t)c * HID + ch * 64 + k8];
            *(uint4*)&Blo[c * KPAD + k8] = *(const uint4*)&Wl[(size_t)c * HID + ch * 64 + k8];
        }
        __syncthreads();

        #pragma unroll
        for (int ks = 0; ks < 2; ++ks) {
            const int ko = ks * 32 + kgrp * 8;
            bf16x8 ah[2], al[2], bh[8], bl[8];
            #pragma unroll
            for (int tr = 0; tr < 2; ++tr) {
                const int rr = w * 32 + tr * 16 + lrow;
                ah[tr] = *(const bf16x8*)&Ahi[rr * KPAD + ko];
                al[tr] = *(const bf16x8*)&Alo[rr * KPAD + ko];
            }
            #pragma unroll
            for (int tc = 0; tc < 8; ++tc) {
                const int cc = tc * 16 + lrow;
                bh[tc] = *(const bf16x8*)&Bhi[cc * KPAD + ko];
                bl[tc] = *(const bf16x8*)&Blo[cc * KPAD + ko];
            }
            #pragma unroll
            for (int tr = 0; tr < 2; ++tr)
                #pragma unroll
                for (int tc = 0; tc < 8; ++tc) {
                    acc[tr][tc] = __builtin_amdgcn_mfma_f32_16x16x32_bf16(ah[tr], bh[tc], acc[tr][tc], 0, 0, 0);
                    acc[tr][tc] = __builtin_amdgcn_mfma_f32_16x16x32_bf16(al[tr], bh[tc], acc[tr][tc], 0, 0, 0);
                    acc[tr][tc] = __builtin_amdgcn_mfma_f32_16x16x32_bf16(ah[tr], bl[tc], acc[tr][tc], 0, 0, 0);
                }
        }
    }

    #pragma unroll
    for (int tr = 0; tr < 2; ++tr)
        #pragma unroll
        for (int j = 0; j < 4; ++j) {
            const int r = w * 32 + tr * 16 + kgrp * 4 + j;
            if (r < nrows) {
                if (g.of32[ph]) {
                    float* O = (float*)g.O[ph];
                    #pragma unroll
                    for (int tc = 0; tc < 8; ++tc)
                        O[(size_t)(row0 + r) * HID + tc * 16 + lrow] = acc[tr][tc][j];
                } else {
                    unsigned short* O = (unsigned short*)g.O[ph];
                    #pragma unroll
                    for (int tc = 0; tc < 8; ++tc)
                        O[(size_t)(row0 + r) * HID + tc * 16 + lrow] = f2bf(acc[tr][tc][j]);
                }
            }
        }
}

// ---------------------------------------------------------------------------
// k_final: out = LN(relu(Matt@WA + H@Wself + s@Wstr + biases) + H)
// ---------------------------------------------------------------------------
__global__ __launch_bounds__(256, 2) void k_final(
    const float* __restrict__ Matt, const float* __restrict__ H,
    const unsigned short* __restrict__ WAhi, const unsigned short* __restrict__ WAlo,
    const unsigned short* __restrict__ WShi, const unsigned short* __restrict__ WSlo,
    const float* __restrict__ Wstr,
    const float* __restrict__ bself, const float* __restrict__ bA,
    const float* __restrict__ bstr,
    const float* __restrict__ lng, const float* __restrict__ lnb,
    float* __restrict__ out, int N)
{
    extern __shared__ unsigned short lds[];
    unsigned short* Ahi = lds;
    unsigned short* Alo = lds + 128 * KPAD;
    unsigned short* Bhi = lds + 2 * 128 * KPAD;
    unsigned short* Blo = lds + 3 * 128 * KPAD;
    const int tid  = threadIdx.x;
    const int row0 = blockIdx.x * 128;
    const int nrows = min(128, N - row0);
    const int w    = tid >> 6, lane = tid & 63;
    const int lrow = lane & 15, kgrp = lane >> 4;

    f32x4 acc[2][8];
    float gl[8], bl_[8];
    #pragma unroll
    for (int tc = 0; tc < 8; ++tc) {
        const int c = tc * 16 + lrow;
        const float bv = bself[c] + bA[c] + bstr[c];
        acc[0][tc] = f32x4{bv, bv, bv, bv};
        acc[1][tc] = f32x4{bv, bv, bv, bv};
        gl[tc] = lng[c]; bl_[tc] = lnb[c];
    }

    for (int ph = 0; ph < 2; ++ph) {
        const float* __restrict__ Am = ph ? H : Matt;
        const unsigned short* __restrict__ Wh = ph ? WShi : WAhi;
        const unsigned short* __restrict__ Wl = ph ? WSlo : WAlo;
        for (int ch = 0; ch < 2; ++ch) {
            __syncthreads();
            #pragma unroll
            for (int it = 0; it < 8; ++it) {
                const int idx = tid + 256 * it;
                const int r = idx >> 4, kq = (idx & 15) * 4;
                f4 v = {0.f, 0.f, 0.f, 0.f};
                if (r < nrows) v = *(const f4*)&Am[(size_t)(row0 + r) * HID + ch * 64 + kq];
                ushort4 h, l;
                split2(v[0], h.x, l.x); split2(v[1], h.y, l.y);
                split2(v[2], h.z, l.z); split2(v[3], h.w, l.w);
                *(ushort4*)&Ahi[r * KPAD + kq] = h;
                *(ushort4*)&Alo[r * KPAD + kq] = l;
            }
            #pragma unroll
            for (int it = 0; it < 4; ++it) {
                const int idx = tid + 256 * it;
                const int c = idx >> 3, k8 = (idx & 7) * 8;
                *(uint4*)&Bhi[c * KPAD + k8] = *(const uint4*)&Wh[(size_t)c * HID + ch * 64 + k8];
                *(uint4*)&Blo[c * KPAD + k8] = *(const uint4*)&Wl[(size_t)c * HID + ch * 64 + k8];
            }
            __syncthreads();

            #pragma unroll
            for (int ks = 0; ks < 2; ++ks) {
                const int ko = ks * 32 + kgrp * 8;
                bf16x8 ah[2], al[2], bh[8], bl[8];
                #pragma unroll
                for (int tr = 0; tr < 2; ++tr) {
                    const int rr = w * 32 + tr * 16 + lrow;
                    ah[tr] = *(const bf16x8*)&Ahi[rr * KPAD + ko];
                    al[tr] = *(const bf16x8*)&Alo[rr * KPAD + ko];
                }
                #pragma unroll
                for (int tc = 0; tc < 8; ++tc) {
                    const int cc = tc * 16 + lrow;
                    bh[tc] = *(const bf16x8*)&Bhi[cc * KPAD + ko];
                    bl[tc] = *(const bf16x8*)&Blo[cc * KPAD + ko];
                }
                #pragma unroll
                for (int tr = 0; tr < 2; ++tr)
                    #pragma unroll
                    for (int tc = 0; tc < 8; ++tc) {
                        acc[tr][tc] = __builtin_amdgcn_mfma_f32_16x16x32_bf16(ah[tr], bh[tc], acc[tr][tc], 0, 0, 0);
                        acc[tr][tc] = __builtin_amdgcn_mfma_f32_16x16x32_bf16(al[tr], bh[tc], acc[tr][tc], 0, 0, 0);
                        acc[tr][tc] = __builtin_amdgcn_mfma_f32_16x16x32_bf16(ah[tr], bl[tc], acc[tr][tc], 0, 0, 0);
                    }
            }

            if (ph == 1 && ch == 0) {
                #pragma unroll
                for (int tr = 0; tr < 2; ++tr)
                    #pragma unroll
                    for (int j = 0; j < 4; ++j) {
                        const int rr = w * 32 + tr * 16 + kgrp * 4 + j;
                        float s[NSTR];
                        #pragma unroll
                        for (int k = 0; k < NSTR; ++k)
                            s[k] = bf2f(Ahi[rr * KPAD + k]) + bf2f(Alo[rr * KPAD + k]);
                        #pragma unroll
                        for (int tc = 0; tc < 8; ++tc) {
                            float a = 0.f;
                            #pragma unroll
                            for (int k = 0; k < NSTR; ++k)
                                a = fmaf(s[k], Wstr[k * HID + tc * 16 + lrow], a);
                            acc[tr][tc][j] += a;
                        }
                    }
            }
        }
    }

    #pragma unroll
    for (int tr = 0; tr < 2; ++tr)
        #pragma unroll
        for (int j = 0; j < 4; ++j) {
            const int r = w * 32 + tr * 16 + kgrp * 4 + j;
            const bool valid = r < nrows;
            const size_t rb = (size_t)(row0 + r) * HID;
            float v[8], s1 = 0.f, s2 = 0.f;
            #pragma unroll
            for (int tc = 0; tc < 8; ++tc) {
                float x = fmaxf(acc[tr][tc][j], 0.f);
                if (valid) x += H[rb + tc * 16 + lrow];
                v[tc] = x;
                s1 += x; s2 += x * x;
            }
            #pragma unroll
            for (int mk = 1; mk < 16; mk <<= 1) {
                s1 += __shfl_xor(s1, mk);
                s2 += __shfl_xor(s2, mk);
            }
            const float mean = s1 * (1.f / HID);
            const float var  = s2 * (1.f / HID) - mean * mean;
            const float rs   = rsqrtf(var + LN_EPS);
            if (valid) {
                #pragma unroll
                for (int tc = 0; tc < 8; ++tc)
                    out[rb + tc * 16 + lrow] = (v[tc] - mean) * rs * gl[tc] + bl_[tc];
            }
        }
}

// psi[n] = dot(H[n], f_def_w) + f_def_b
__global__ __launch_bounds__(256) void k_psi(
    const float* __restrict__ H, const float* __restrict__ fw, const float* __restrict__ fb,
    float* __restrict__ psi, int N)
{
    const int wid = threadIdx.x >> 6, lane = threadIdx.x & 63;
    const int n = blockIdx.x * 4 + wid;
    if (n >= N) return;
    const size_t o = (size_t)n * HID;
    float a = H[o + lane] * fw[lane] + H[o + 64 + lane] * fw[64 + lane];
    #pragma unroll
    for (int off = 32; off; off >>= 1) a += __shfl_down(a, off);
    if (lane == 0) psi[n] = a + fb[0];
}

// ---------------------------------------------------------------------------
// CSR build via two-level LDS counting sort — ZERO global atomics.
// Buckets of 256 nodes (NB buckets); chunks of CSR_CHUNK edges (NC blocks).
// ---------------------------------------------------------------------------
// S1: per-(chunk,bucket) counts for both keys in one launch (grid NC x 2)
__global__ __launch_bounds__(256) void k_csr_count(
    const int* __restrict__ etgt, const int* __restrict__ esrc,
    int* __restrict__ cnt_t, int* __restrict__ cnt_s,
    int NB, int NC, int E)
{
    __shared__ int cnt[256];
    const int which = blockIdx.y;
    const int* __restrict__ key = which ? esrc : etgt;
    int* __restrict__ outc = which ? cnt_s : cnt_t;
    const int tid = threadIdx.x;
    for (int i = tid; i < NB; i += 256) cnt[i] = 0;
    __syncthreads();
    const int e0 = blockIdx.x * CSR_CHUNK;
    const int e1 = min(e0 + CSR_CHUNK, E);
    for (int e = e0 + tid; e < e1; e += 256)
        atomicAdd(&cnt[key[e] >> 8], 1);
    __syncthreads();
    for (int k = tid; k < NB; k += 256)
        outc[(size_t)k * NC + blockIdx.x] = cnt[k];
}

// S2: flat exclusive scan of both count matrices (length L = NB*NC)
__global__ __launch_bounds__(1024) void k_csr_scan(
    const int* __restrict__ cnt_t, int* __restrict__ off_t,
    const int* __restrict__ cnt_s, int* __restrict__ off_s, int L)
{
    const int* __restrict__ cnt = blockIdx.x ? cnt_s : cnt_t;
    int* __restrict__ off = blockIdx.x ? off_s : off_t;
    __shared__ int warp_sums[16];
    __shared__ int carry_s;
    const int tid = threadIdx.x, lane = tid & 63, wid = tid >> 6;
    if (tid == 0) carry_s = 0;
    __syncthreads();
    for (int i0 = 0; i0 < L; i0 += 1024) {
        const int i = i0 + tid;
        const int v = (i < L) ? cnt[i] : 0;
        int x = v;
        #pragma unroll
        for (int d = 1; d < 64; d <<= 1) {
            const int y = __shfl_up(x, d);
            if (lane >= d) x += y;
        }
        if (lane == 63) warp_sums[wid] = x;
        __syncthreads();
        if (wid == 0) {
            int ws = (lane < 16) ? warp_sums[lane] : 0;
            #pragma unroll
            for (int d = 1; d < 16; d <<= 1) {
                const int y = __shfl_up(ws, d);
                if (lane >= d) ws += y;
            }
            if (lane < 16) warp_sums[lane] = ws;
        }
        __syncthreads();
        const int carry = carry_s;
        if (i < L) off[i] = carry + (wid ? warp_sums[wid - 1] : 0) + x - v;
        __syncthreads();
        if (tid == 1023) carry_s = carry + warp_sums[15];
        __syncthreads();
    }
    if (tid == 0) off[L] = carry_s;
}

// S3: scatter edge ids into bucket segments (LDS cursors, plain stores)
__global__ __launch_bounds__(256) void k_csr_bucket(
    const int* __restrict__ key, const int* __restrict__ off,
    int* __restrict__ ebuck, int NB, int NC, int E)
{
    __shared__ int cur[256];
    const int tid = threadIdx.x;
    for (int k = tid; k < NB; k += 256)
        cur[k] = off[(size_t)k * NC + blockIdx.x];
    __syncthreads();
    const int e0 = blockIdx.x * CSR_CHUNK;
    const int e1 = min(e0 + CSR_CHUNK, E);
    for (int e = e0 + tid; e < e1; e += 256) {
        const int p = atomicAdd(&cur[key[e] >> 8], 1);
        ebuck[p] = e;
    }
}

// S4: per-bucket finalize: local hist + block scan -> base[] and eid[]
__global__ __launch_bounds__(256) void k_csr_final(
    const int* __restrict__ key, const int* __restrict__ off,
    const int* __restrict__ ebuck,
    int* __restrict__ base, int* __restrict__ eid,
    int NB, int NC, int N, int E)
{
    __shared__ int cnt[256], excl[256], wsum[4];
    const int tid = threadIdx.x, lane = tid & 63, wv = tid >> 6;
    const int k = blockIdx.x;
    const int segb = off[(size_t)k * NC];
    const int sege = (k + 1 < NB) ? off[(size_t)(k + 1) * NC] : E;
    cnt[tid] = 0;
    __syncthreads();
    for (int i = segb + tid; i < sege; i += 256)
        atomicAdd(&cnt[key[ebuck[i]] & 255], 1);
    __syncthreads();
    // block exclusive scan of cnt -> excl
    {
        const int orig = cnt[tid];
        int x = orig;
        #pragma unroll
        for (int d = 1; d < 64; d <<= 1) {
            const int y = __shfl_up(x, d);
            if (lane >= d) x += y;
        }
        if (lane == 63) wsum[wv] = x;
        __syncthreads();
        if (tid == 0) {
            int a = 0;
            #pragma unroll
            for (int i = 0; i < 4; ++i) { const int t = wsum[i]; wsum[i] = a; a += t; }
        }
        __syncthreads();
        excl[tid] = x - orig + wsum[wv];
    }
    __syncthreads();
    const int node = k * 256 + tid;
    if (node < N) base[node] = segb + excl[tid];
    if (k == NB - 1 && tid == 0) base[N] = E;
    cnt[tid] = excl[tid];   // reuse as cursor
    __syncthreads();
    for (int i = segb + tid; i < sege; i += 256) {
        const int e = ebuck[i];
        const int r = atomicAdd(&cnt[key[e] & 255], 1);
        eid[segb + r] = e;
    }
}

// ---------------------------------------------------------------------------
// k_score: wave per TARGET node, 16-lane edge groups, single 256B gather/edge.
// score = Wt[tgt].hs + struct;  pair = Uf[tgt].hs -> pairv[eid] (plain store).
// ---------------------------------------------------------------------------
__global__ __launch_bounds__(256) void k_score(
    const int* __restrict__ eid_t, const int* __restrict__ base_t,
    const int* __restrict__ esrc,
    const float* __restrict__ Wt, const float* __restrict__ Uf,
    const unsigned short* __restrict__ HB,
    float* __restrict__ score, float* __restrict__ pairv,
    float* __restrict__ sumt_inv, int N)
{
    const int lane = threadIdx.x & 63, wv = threadIdx.x >> 6;
    const int t = blockIdx.x * 4 + wv;
    if (t >= N) return;
    const int b0 = base_t[t], deg = base_t[t + 1] - b0;
    if (deg == 0) { if (lane == 0) sumt_inv[t] = 0.f; return; }
    const int sub = lane & 15, grp = lane >> 4;
    const size_t to = (size_t)t * HID;

    float wt[8], u[8], htg[8];
    {
        const f4 w0 = *(const f4*)&Wt[to + sub * 8];
        const f4 w1 = *(const f4*)&Wt[to + sub * 8 + 4];
        wt[0] = w0[0]; wt[1] = w0[1]; wt[2] = w0[2]; wt[3] = w0[3];
        wt[4] = w1[0]; wt[5] = w1[1]; wt[6] = w1[2]; wt[7] = w1[3];
        const f4 u0 = *(const f4*)&Uf[to + sub * 8];
        const f4 u1 = *(const f4*)&Uf[to + sub * 8 + 4];
        u[0] = u0[0]; u[1] = u0[1]; u[2] = u0[2]; u[3] = u0[3];
        u[4] = u1[0]; u[5] = u1[1]; u[6] = u1[2]; u[7] = u1[3];
        unpack8(*(const uint4*)&HB[to + sub * 8], htg);
    }

    for (int j0 = 0; j0 < deg; j0 += 4) {
        const int jj = j0 + grp;
        const bool val = jj < deg;
        int eid = 0, src = 0;
        if (val) { eid = eid_t[b0 + jj]; src = esrc[eid]; }
        const size_t so = (size_t)src * HID;
        float hs[8];
        unpack8(*(const uint4*)&HB[so + sub * 8], hs);
        float ps = 0.f, pp = 0.f;
        #pragma unroll
        for (int d = 0; d < 8; ++d) {
            ps = fmaf(wt[d], hs[d], ps);
            pp = fmaf(u[d], hs[d], pp);
        }
        if (sub == 0) {
            #pragma unroll
            for (int d = 0; d < NSTR; ++d) ps = fmaf(htg[d], hs[d], ps);
        }
        #pragma unroll
        for (int mk = 1; mk < 16; mk <<= 1) {
            ps += __shfl_xor(ps, mk);
            pp += __shfl_xor(pp, mk);
        }
        if (sub == 0 && val) {
            score[b0 + jj] = ps;
            pairv[eid] = pp;
        }
    }

    float m = -1e30f;
    for (int i = lane; i < deg; i += 64) m = fmaxf(m, score[b0 + i]);
    #pragma unroll
    for (int mk = 1; mk < 64; mk <<= 1) m = fmaxf(m, __shfl_xor(m, mk));
    float psum = 0.f;
    for (int i = lane; i < deg; i += 64) {
        const float e = expf(score[b0 + i] - m);
        score[b0 + i] = e;
        psum += e;
    }
    #pragma unroll
    for (int mk = 1; mk < 64; mk <<= 1) psum += __shfl_xor(psum, mk);
    if (lane == 0) sumt_inv[t] = 1.f / psum;
}

// ---------------------------------------------------------------------------
// k_beta2: wave per SOURCE node, streaming (no atomics); fuses rho.
// ---------------------------------------------------------------------------
__global__ __launch_bounds__(256) void k_beta2(
    const int* __restrict__ base_s, const int* __restrict__ eid_s,
    const int* __restrict__ etgt,
    const float* __restrict__ pairv, const float* __restrict__ psi,
    float* __restrict__ rho1m, int N)
{
    const int lane = threadIdx.x & 63, wv = threadIdx.x >> 6;
    const int s = blockIdx.x * 4 + wv;
    if (s >= N) return;
    const int b0 = base_s[s], deg = base_s[s + 1] - b0;

    float m = -1e30f;
    for (int i = lane; i < deg; i += 64) m = fmaxf(m, pairv[eid_s[b0 + i]]);
    #pragma unroll
    for (int mk = 1; mk < 64; mk <<= 1) m = fmaxf(m, __shfl_xor(m, mk));

    float se = 0.f, sn = 0.f;
    for (int i = lane; i < deg; i += 64) {
        const int e = eid_s[b0 + i];
        const float ex = expf(pairv[e] - m);
        se += ex;
        sn += ex * expf(-psi[etgt[e]]);
    }
    #pragma unroll
    for (int mk = 1; mk < 64; mk <<= 1) {
        se += __shfl_xor(se, mk);
        sn += __shfl_xor(sn, mk);
    }
    if (lane == 0) {
        const float st = (deg > 0 && se > 0.f) ? sn / se : 0.f;
        const float d  = -logf(st + 1e-8f);
        rho1m[s] = 1.f - 1.f / (1.f + expf(-(GAMMA * (d - DELTA))));
    }
}

// ---------------------------------------------------------------------------
// k_matt: wave per TARGET, 16-lane edge groups; Hphi bf16 gather; out f32.
// ---------------------------------------------------------------------------
__global__ __launch_bounds__(256) void k_matt(
    const int* __restrict__ eid_t, const int* __restrict__ base_t,
    const int* __restrict__ esrc,
    const float* __restrict__ score, const float* __restrict__ sumt_inv,
    const float* __restrict__ rho1m,
    const unsigned short* __restrict__ HphiB,
    float* __restrict__ matt, int N)
{
    const int lane = threadIdx.x & 63, wv = threadIdx.x >> 6;
    const int t = blockIdx.x * 4 + wv;
    if (t >= N) return;
    const int b0 = base_t[t], deg = base_t[t + 1] - b0;
    const int sub = lane & 15, grp = lane >> 4;
    const size_t to = (size_t)t * HID;

    float acc[8];
    #pragma unroll
    for (int d = 0; d < 8; ++d) acc[d] = 0.f;
    const float inv = (deg > 0) ? sumt_inv[t] : 0.f;

    for (int j0 = 0; j0 < deg; j0 += 4) {
        const int jj = j0 + grp;
        const bool val = jj < deg;
        float c = 0.f;
        size_t so = 0;
        if (val) {
            const int eid = eid_t[b0 + jj];
            const int src = esrc[eid];
            c = score[b0 + jj] * inv * rho1m[src];
            so = (size_t)src * HID;
        }
        float hf[8];
        unpack8(*(const uint4*)&HphiB[so + sub * 8], hf);
        #pragma unroll
        for (int d = 0; d < 8; ++d) acc[d] = fmaf(c, hf[d], acc[d]);
    }
    #pragma unroll
    for (int d = 0; d < 8; ++d) {
        acc[d] += __shfl_xor(acc[d], 16);
        acc[d] += __shfl_xor(acc[d], 32);
    }
    if (grp == 0) {
        f4 o0, o1;
        #pragma unroll
        for (int d = 0; d < 4; ++d) { o0[d] = acc[d]; o1[d] = acc[d + 4]; }
        *(f4*)&matt[to + sub * 8]     = o0;
        *(f4*)&matt[to + sub * 8 + 4] = o1;
    }
}

extern "C" void kernel_launch(void* const* d_in, const int* in_sizes, int n_in,
                              void* d_out, int out_size, void* d_ws, size_t ws_size,
                              hipStream_t stream)
{
    const int*   eidx   = (const int*)  d_in[0];
    const float* H      = (const float*)d_in[1];
    const float* W_att  = (const float*)d_in[2];
    const float* phi_w  = (const float*)d_in[3];
    const float* phi_b  = (const float*)d_in[4];
    const float* W_p    = (const float*)d_in[5];
    const float* W_pp   = (const float*)d_in[6];
    const float* fdef_w = (const float*)d_in[7];
    const float* fdef_b = (const float*)d_in[8];
    const float* Wself  = (const float*)d_in[9];
    const float* bself  = (const float*)d_in[10];
    const float* WA     = (const float*)d_in[11];
    const float* bA     = (const float*)d_in[12];
    const float* Wstr   = (const float*)d_in[13];
    const float* bstr   = (const float*)d_in[14];
    const float* lng    = (const float*)d_in[15];
    const float* lnb    = (const float*)d_in[16];
    float* out = (float*)d_out;

    const int E = in_sizes[0] / 2;
    const int N = in_sizes[1] / HID;
    const int* esrc = eidx;
    const int* etgt = eidx + E;

    const int NB = (N + 255) >> 8;                      // node buckets
    const int NC = (E + CSR_CHUNK - 1) / CSR_CHUNK;     // edge chunks
    const int L  = NB * NC;

    // ---- workspace layout (~91 MB) ----
    char* w = (char*)d_ws;
    const size_t NHb  = (size_t)N * HID * sizeof(unsigned short);
    const size_t NH   = (size_t)N * HID * sizeof(float);
    const size_t Epad = (((size_t)E * sizeof(float)) + 255) & ~255ull;
    const size_t Npad = (((size_t)(N + 1) * sizeof(float)) + 255) & ~255ull;
    const size_t Lpad = (((size_t)(L + 1) * sizeof(int)) + 255) & ~255ull;

    float*          Wt    = (float*)w;          w += NH;   // matt aliases after k_score
    float*          Uf    = (float*)w;          w += NH;
    unsigned short* HB    = (unsigned short*)w; w += NHb;
    unsigned short* HphiB = (unsigned short*)w; w += NHb;
    float* score = (float*)w; w += Epad;  // CSR-tgt order
    float* pairv = (float*)w; w += Epad;  // edge-id order
    int*   eid_t = (int*)  w; w += Epad;
    int*   eid_s = (int*)  w; w += Epad;
    int*   ebuck = (int*)  w; w += Epad;  // shared between t/s passes
    int*   cnt_t = (int*)  w; w += Lpad;
    int*   off_t = (int*)  w; w += Lpad;
    int*   cnt_s = (int*)  w; w += Lpad;
    int*   off_s = (int*)  w; w += Lpad;
    int*   base_t   = (int*)  w; w += Npad;   // N+1
    int*   base_s   = (int*)  w; w += Npad;   // N+1
    float* sumt_inv = (float*)w; w += Npad;
    float* psi      = (float*)w; w += Npad;
    float* rho1m    = (float*)w; w += Npad;
    unsigned short* WT = (unsigned short*)w;  // 5 slots x 2 planes x 128x128
    w += 5 * 2 * HID * HID * sizeof(unsigned short);
    float* matt = Wt;   // alias: Wt dead after k_score

    const int nblk128 = (N + 127) / 128;
    const int nblkN4  = (N + 3) / 4;
    const size_t lds_mfma = 4 * 128 * KPAD * sizeof(unsigned short);  // 72 KB
    const size_t MSZ = (size_t)2 * HID * HID;

    PrepArgs pa;
    pa.W[0] = W_att; pa.tr[0] = 0;
    pa.W[1] = phi_w; pa.tr[1] = 1;
    pa.W[2] = WA;    pa.tr[2] = 1;
    pa.W[3] = Wself; pa.tr[3] = 1;
    k_prep<<<dim3(8, 4), 256, 0, stream>>>(pa, WT);
    k_m2<<<8, 256, 0, stream>>>(W_p, W_pp, WT + 4 * MSZ);

    k_cast<<<(N * HID / 8 + 255) / 256, 256, 0, stream>>>(H, HB, N * HID / 8);

    GemmArgsT g3;
    g3.Whi[0] = WT;            g3.Wlo[0] = WT + HID * HID;
    g3.Whi[1] = WT + 4 * MSZ;  g3.Wlo[1] = WT + 4 * MSZ + HID * HID;
    g3.Whi[2] = WT + 1 * MSZ;  g3.Wlo[2] = WT + 1 * MSZ + HID * HID;
    g3.b[0] = nullptr; g3.b[1] = nullptr; g3.b[2] = phi_b;
    g3.O[0] = Wt;    g3.of32[0] = 1;
    g3.O[1] = Uf;    g3.of32[1] = 1;
    g3.O[2] = HphiB; g3.of32[2] = 0;
    k_gemm<<<dim3(nblk128, 3), 256, lds_mfma, stream>>>(H, g3, N);

    k_psi<<<nblkN4, 256, 0, stream>>>(H, fdef_w, fdef_b, psi, N);

    // ---- CSR build (no global atomics) ----
    k_csr_count<<<dim3(NC, 2), 256, 0, stream>>>(etgt, esrc, cnt_t, cnt_s, NB, NC, E);
    k_csr_scan<<<2, 1024, 0, stream>>>(cnt_t, off_t, cnt_s, off_s, L);
    k_csr_bucket<<<NC, 256, 0, stream>>>(etgt, off_t, ebuck, NB, NC, E);
    k_csr_final<<<NB, 256, 0, stream>>>(etgt, off_t, ebuck, base_t, eid_t, NB, NC, N, E);
    k_csr_bucket<<<NC, 256, 0, stream>>>(esrc, off_s, ebuck, NB, NC, E);
    k_csr_final<<<NB, 256, 0, stream>>>(esrc, off_s, ebuck, base_s, eid_s, NB, NC, N, E);

    k_score<<<nblkN4, 256, 0, stream>>>(eid_t, base_t, esrc, Wt, Uf, HB,
                                        score, pairv, sumt_inv, N);
    k_beta2<<<nblkN4, 256, 0, stream>>>(base_s, eid_s, etgt, pairv, psi, rho1m, N);

    k_matt<<<nblkN4, 256, 0, stream>>>(eid_t, base_t, esrc, score, sumt_inv,
                                       rho1m, HphiB, matt, N);

    k_final<<<nblk128, 256, lds_mfma, stream>>>(matt, H,
                                                WT + 2 * MSZ, WT + 2 * MSZ + HID * HID,
                                                WT + 3 * MSZ, WT + 3 * MSZ + HID * HID,
                                                Wstr, bself, bA, bstr, lng, lnb, out, N);
}

// Round 12
// 368.574 us; speedup vs baseline: 1.2875x; 1.0061x over previous
//
#include <hip/hip_runtime.h>
#include <math.h>

#define HID 128
#define NSTR 6              // STRUCT-1
#define GAMMA 1.0f
#define DELTA 0.5f
#define LN_EPS 1e-5f
#define KPAD 72             // bf16 elems per LDS row (64 + 8 pad)
#define CSR_CHUNK 8192      // edges per block in CSR build

typedef __attribute__((ext_vector_type(4))) float f4;
typedef __attribute__((ext_vector_type(8))) short bf16x8;
typedef __attribute__((ext_vector_type(4))) float f32x4;

// f32 -> bf16 (round-to-nearest-even) and helpers
__device__ __forceinline__ unsigned short f2bf(float f) {
    unsigned u = __float_as_uint(f);
    unsigned r = u + 0x7FFFu + ((u >> 16) & 1u);
    return (unsigned short)(r >> 16);
}
__device__ __forceinline__ float bf2f(unsigned short h) {
    return __uint_as_float((unsigned)h << 16);
}
__device__ __forceinline__ void split2(float v, unsigned short& h, unsigned short& l) {
    h = f2bf(v);
    l = f2bf(v - bf2f(h));
}
__device__ __forceinline__ void bf2f2(unsigned u, float& lo, float& hi) {
    lo = __uint_as_float(u << 16);
    hi = __uint_as_float(u & 0xFFFF0000u);
}
__device__ __forceinline__ void unpack8(const uint4 u, float* f) {
    bf2f2(u.x, f[0], f[1]); bf2f2(u.y, f[2], f[3]);
    bf2f2(u.z, f[4], f[5]); bf2f2(u.w, f[6], f[7]);
}

// ---------------------------------------------------------------------------
// k_prep: split (optionally transpose) weight matrices into WT slots.
// slot m: [hi 128x128][lo 128x128] bf16, table[c][k].
// ---------------------------------------------------------------------------
struct PrepArgs { const float* W[2]; int tr[2]; };

__global__ __launch_bounds__(256) void k_prep(PrepArgs p, unsigned short* WT)
{
    __shared__ float T[128][17];
    const int m = blockIdx.y, c0 = blockIdx.x * 16;
    const int tid = threadIdx.x;
    const float* __restrict__ W = p.W[m];
    unsigned short* hi = WT + (size_t)m * 2 * HID * HID;
    unsigned short* lo = hi + HID * HID;
    if (p.tr[m]) {
        for (int idx = tid; idx < 2048; idx += 256) {
            const int k = idx >> 4, c = idx & 15;
            T[k][c] = W[k * HID + c0 + c];
        }
        __syncthreads();
        for (int idx = tid; idx < 2048; idx += 256) {
            const int c = idx >> 7, k = idx & 127;
            unsigned short h, l;
            split2(T[k][c], h, l);
            hi[(size_t)(c0 + c) * HID + k] = h;
            lo[(size_t)(c0 + c) * HID + k] = l;
        }
    } else {
        for (int idx = tid; idx < 2048; idx += 256) {
            const int c = idx >> 7, k = idx & 127;
            unsigned short h, l;
            split2(W[(size_t)(c0 + c) * HID + k], h, l);
            hi[(size_t)(c0 + c) * HID + k] = h;
            lo[(size_t)(c0 + c) * HID + k] = l;
        }
    }
}

// k_m2: M2 = W_p @ W_pp^T split into slot: tbl[c][k] = sum_j Wp[c][j]*Wpp[k][j]
__global__ __launch_bounds__(256) void k_m2(
    const float* __restrict__ Wp, const float* __restrict__ Wpp,
    unsigned short* __restrict__ slot)
{
    __shared__ float Bs[128][129];
    __shared__ float As[16][129];
    const int tid = threadIdx.x, c0 = blockIdx.x * 16;
    for (int idx = tid; idx < 128 * 128; idx += 256)
        Bs[idx >> 7][idx & 127] = Wpp[idx];
    for (int idx = tid; idx < 16 * 128; idx += 256)
        As[idx >> 7][idx & 127] = Wp[(size_t)(c0 + (idx >> 7)) * HID + (idx & 127)];
    __syncthreads();
    unsigned short* hi = slot;
    unsigned short* lo = slot + HID * HID;
    for (int it = 0; it < 8; ++it) {
        const int idx = tid + 256 * it;
        const int c = idx >> 7, k = idx & 127;
        float a = 0.f;
        #pragma unroll 4
        for (int j = 0; j < 128; ++j)
            a = fmaf(As[c][j], Bs[k][j], a);
        unsigned short h, l;
        split2(a, h, l);
        hi[(size_t)(c0 + c) * HID + k] = h;
        lo[(size_t)(c0 + c) * HID + k] = l;
    }
}

// ---------------------------------------------------------------------------
// k_g: G-table for agg@(phi_w@W_A): tbl[c][k] = sum_j phi_w[k][j]*W_A[j][c]
// Also pbA[c] = sum_j phi_b[j]*W_A[j][c].
// ---------------------------------------------------------------------------
__global__ __launch_bounds__(256) void k_g(
    const float* __restrict__ phiw, const float* __restrict__ WA,
    const float* __restrict__ phib,
    unsigned short* __restrict__ slot, float* __restrict__ pbA)
{
    __shared__ float Bs[128][129];   // phi_w rows
    __shared__ float As[16][129];    // W_A columns c0..c0+15
    const int tid = threadIdx.x, c0 = blockIdx.x * 16;
    for (int idx = tid; idx < 128 * 128; idx += 256)
        Bs[idx >> 7][idx & 127] = phiw[idx];
    for (int idx = tid; idx < 16 * 128; idx += 256) {
        const int c = idx >> 7, j = idx & 127;
        As[c][j] = WA[(size_t)j * HID + c0 + c];
    }
    __syncthreads();
    unsigned short* hi = slot;
    unsigned short* lo = slot + HID * HID;
    for (int it = 0; it < 8; ++it) {
        const int idx = tid + 256 * it;
        const int c = idx >> 7, k = idx & 127;
        float a = 0.f;
        #pragma unroll 4
        for (int j = 0; j < 128; ++j)
            a = fmaf(As[c][j], Bs[k][j], a);
        unsigned short h, l;
        split2(a, h, l);
        hi[(size_t)(c0 + c) * HID + k] = h;
        lo[(size_t)(c0 + c) * HID + k] = l;
    }
    if (tid < 16) {
        float a = 0.f;
        #pragma unroll 4
        for (int j = 0; j < 128; ++j)
            a = fmaf(phib[j], As[tid][j], a);
        pbA[c0 + tid] = a;
    }
}

// ---------------------------------------------------------------------------
// k_castpsi: HB = bf16(H) AND psi = H.f_def_w + f_def_b in one H pass.
// ---------------------------------------------------------------------------
__global__ __launch_bounds__(256) void k_castpsi(
    const float* __restrict__ H, const float* __restrict__ fw,
    const float* __restrict__ fb,
    unsigned short* __restrict__ HB, float* __restrict__ psi, int N)
{
    const int tid = threadIdx.x;
    const int row = blockIdx.x * 16 + (tid >> 4), sub = tid & 15;
    if (row >= N) return;
    const size_t o = (size_t)row * HID + sub * 8;
    const f4 v0 = *(const f4*)&H[o];
    const f4 v1 = *(const f4*)&H[o + 4];
    ushort4 a, b;
    a.x = f2bf(v0[0]); a.y = f2bf(v0[1]); a.z = f2bf(v0[2]); a.w = f2bf(v0[3]);
    b.x = f2bf(v1[0]); b.y = f2bf(v1[1]); b.z = f2bf(v1[2]); b.w = f2bf(v1[3]);
    *(ushort4*)&HB[o] = a;
    *(ushort4*)&HB[o + 4] = b;
    const f4 w0 = *(const f4*)&fw[sub * 8];
    const f4 w1 = *(const f4*)&fw[sub * 8 + 4];
    float s = v0[0]*w0[0] + v0[1]*w0[1] + v0[2]*w0[2] + v0[3]*w0[3]
            + v1[0]*w1[0] + v1[1]*w1[1] + v1[2]*w1[2] + v1[3]*w1[3];
    #pragma unroll
    for (int mk = 1; mk < 16; mk <<= 1) s += __shfl_xor(s, mk);
    if (sub == 0) psi[row] = s + fb[0];
}

struct GemmArgsT {
    const unsigned short* Whi[2];
    const unsigned short* Wlo[2];
    float*                O[2];
};

// ---------------------------------------------------------------------------
// MFMA GEMM: O[ph] = A @ B[ph], split-precision (hi/lo bf16, 3 MFMA), f32 out.
// ---------------------------------------------------------------------------
__global__ __launch_bounds__(256, 2) void k_gemm(const float* __restrict__ A,
                                                 GemmArgsT g, int N)
{
    extern __shared__ unsigned short lds[];
    unsigned short* Ahi = lds;
    unsigned short* Alo = lds + 128 * KPAD;
    unsigned short* Bhi = lds + 2 * 128 * KPAD;
    unsigned short* Blo = lds + 3 * 128 * KPAD;
    const int tid  = threadIdx.x;
    const int row0 = blockIdx.x * 128;
    const int nrows = min(128, N - row0);
    const int ph   = blockIdx.y;
    const int w    = tid >> 6, lane = tid & 63;
    const int lrow = lane & 15, kgrp = lane >> 4;

    f32x4 acc[2][8];
    #pragma unroll
    for (int tc = 0; tc < 8; ++tc) {
        acc[0][tc] = f32x4{0.f, 0.f, 0.f, 0.f};
        acc[1][tc] = f32x4{0.f, 0.f, 0.f, 0.f};
    }

    const unsigned short* __restrict__ Wh = g.Whi[ph];
    const unsigned short* __restrict__ Wl = g.Wlo[ph];

    for (int ch = 0; ch < 2; ++ch) {
        __syncthreads();
        #pragma unroll
        for (int it = 0; it < 8; ++it) {
            const int idx = tid + 256 * it;
            const int r = idx >> 4, kq = (idx & 15) * 4;
            f4 v = {0.f, 0.f, 0.f, 0.f};
            if (r < nrows) v = *(const f4*)&A[(size_t)(row0 + r) * HID + ch * 64 + kq];
            ushort4 h, l;
            split2(v[0], h.x, l.x); split2(v[1], h.y, l.y);
            split2(v[2], h.z, l.z); split2(v[3], h.w, l.w);
            *(ushort4*)&Ahi[r * KPAD + kq] = h;
            *(ushort4*)&Alo[r * KPAD + kq] = l;
        }
        #pragma unroll
        for (int it = 0; it < 4; ++it) {
            const int idx = tid + 256 * it;
            const int c = idx >> 3, k8 = (idx & 7) * 8;
            *(uint4*)&Bhi[c * KPAD + k8] = *(const uint4*)&Wh[(size_t)c * HID + ch * 64 + k8];
            *(uint4*)&Blo[c * KPAD + k8] = *(const uint4*)&Wl[(size_t)c * HID + ch * 64 + k8];
        }
        __syncthreads();

        #pragma unroll
        for (int ks = 0; ks < 2; ++ks) {
            const int ko = ks * 32 + kgrp * 8;
            bf16x8 ah[2], al[2], bh[8], bl[8];
            #pragma unroll
            for (int tr = 0; tr < 2; ++tr) {
                const int rr = w * 32 + tr * 16 + lrow;
                ah[tr] = *(const bf16x8*)&Ahi[rr * KPAD + ko];
                al[tr] = *(const bf16x8*)&Alo[rr * KPAD + ko];
            }
            #pragma unroll
            for (int tc = 0; tc < 8; ++tc) {
                const int cc = tc * 16 + lrow;
                bh[tc] = *(const bf16x8*)&Bhi[cc * KPAD + ko];
                bl[tc] = *(const bf16x8*)&Blo[cc * KPAD + ko];
            }
            #pragma unroll
            for (int tr = 0; tr < 2; ++tr)
                #pragma unroll
                for (int tc = 0; tc < 8; ++tc) {
                    acc[tr][tc] = __builtin_amdgcn_mfma_f32_16x16x32_bf16(ah[tr], bh[tc], acc[tr][tc], 0, 0, 0);
                    acc[tr][tc] = __builtin_amdgcn_mfma_f32_16x16x32_bf16(al[tr], bh[tc], acc[tr][tc], 0, 0, 0);
                    acc[tr][tc] = __builtin_amdgcn_mfma_f32_16x16x32_bf16(ah[tr], bl[tc], acc[tr][tc], 0, 0, 0);
                }
        }
    }

    float* __restrict__ O = g.O[ph];
    #pragma unroll
    for (int tr = 0; tr < 2; ++tr)
        #pragma unroll
        for (int j = 0; j < 4; ++j) {
            const int r = w * 32 + tr * 16 + kgrp * 4 + j;
            if (r < nrows) {
                #pragma unroll
                for (int tc = 0; tc < 8; ++tc)
                    O[(size_t)(row0 + r) * HID + tc * 16 + lrow] = acc[tr][tc][j];
            }
        }
}

// ---------------------------------------------------------------------------
// k_final: out = LN(relu(agg@G + sig*pbA + H@Wself + s@Wstr + biases) + H)
// ---------------------------------------------------------------------------
__global__ __launch_bounds__(256, 2) void k_final(
    const float* __restrict__ Agg, const float* __restrict__ H,
    const float* __restrict__ sig, const float* __restrict__ pbA,
    const unsigned short* __restrict__ Ghi, const unsigned short* __restrict__ Glo,
    const unsigned short* __restrict__ WShi, const unsigned short* __restrict__ WSlo,
    const float* __restrict__ Wstr,
    const float* __restrict__ bself, const float* __restrict__ bA,
    const float* __restrict__ bstr,
    const float* __restrict__ lng, const float* __restrict__ lnb,
    float* __restrict__ out, int N)
{
    extern __shared__ unsigned short lds[];
    unsigned short* Ahi = lds;
    unsigned short* Alo = lds + 128 * KPAD;
    unsigned short* Bhi = lds + 2 * 128 * KPAD;
    unsigned short* Blo = lds + 3 * 128 * KPAD;
    const int tid  = threadIdx.x;
    const int row0 = blockIdx.x * 128;
    const int nrows = min(128, N - row0);
    const int w    = tid >> 6, lane = tid & 63;
    const int lrow = lane & 15, kgrp = lane >> 4;

    f32x4 acc[2][8];
    float gl[8], bl_[8], pb[8];
    #pragma unroll
    for (int tc = 0; tc < 8; ++tc) {
        const int c = tc * 16 + lrow;
        const float bv = bself[c] + bA[c] + bstr[c];
        acc[0][tc] = f32x4{bv, bv, bv, bv};
        acc[1][tc] = f32x4{bv, bv, bv, bv};
        gl[tc] = lng[c]; bl_[tc] = lnb[c]; pb[tc] = pbA[c];
    }

    for (int ph = 0; ph < 2; ++ph) {
        const float* __restrict__ Am = ph ? H : Agg;
        const unsigned short* __restrict__ Wh = ph ? WShi : Ghi;
        const unsigned short* __restrict__ Wl = ph ? WSlo : Glo;
        for (int ch = 0; ch < 2; ++ch) {
            __syncthreads();
            #pragma unroll
            for (int it = 0; it < 8; ++it) {
                const int idx = tid + 256 * it;
                const int r = idx >> 4, kq = (idx & 15) * 4;
                f4 v = {0.f, 0.f, 0.f, 0.f};
                if (r < nrows) v = *(const f4*)&Am[(size_t)(row0 + r) * HID + ch * 64 + kq];
                ushort4 h, l;
                split2(v[0], h.x, l.x); split2(v[1], h.y, l.y);
                split2(v[2], h.z, l.z); split2(v[3], h.w, l.w);
                *(ushort4*)&Ahi[r * KPAD + kq] = h;
                *(ushort4*)&Alo[r * KPAD + kq] = l;
            }
            #pragma unroll
            for (int it = 0; it < 4; ++it) {
                const int idx = tid + 256 * it;
                const int c = idx >> 3, k8 = (idx & 7) * 8;
                *(uint4*)&Bhi[c * KPAD + k8] = *(const uint4*)&Wh[(size_t)c * HID + ch * 64 + k8];
                *(uint4*)&Blo[c * KPAD + k8] = *(const uint4*)&Wl[(size_t)c * HID + ch * 64 + k8];
            }
            __syncthreads();

            #pragma unroll
            for (int ks = 0; ks < 2; ++ks) {
                const int ko = ks * 32 + kgrp * 8;
                bf16x8 ah[2], al[2], bh[8], bl[8];
                #pragma unroll
                for (int tr = 0; tr < 2; ++tr) {
                    const int rr = w * 32 + tr * 16 + lrow;
                    ah[tr] = *(const bf16x8*)&Ahi[rr * KPAD + ko];
                    al[tr] = *(const bf16x8*)&Alo[rr * KPAD + ko];
                }
                #pragma unroll
                for (int tc = 0; tc < 8; ++tc) {
                    const int cc = tc * 16 + lrow;
                    bh[tc] = *(const bf16x8*)&Bhi[cc * KPAD + ko];
                    bl[tc] = *(const bf16x8*)&Blo[cc * KPAD + ko];
                }
                #pragma unroll
                for (int tr = 0; tr < 2; ++tr)
                    #pragma unroll
                    for (int tc = 0; tc < 8; ++tc) {
                        acc[tr][tc] = __builtin_amdgcn_mfma_f32_16x16x32_bf16(ah[tr], bh[tc], acc[tr][tc], 0, 0, 0);
                        acc[tr][tc] = __builtin_amdgcn_mfma_f32_16x16x32_bf16(al[tr], bh[tc], acc[tr][tc], 0, 0, 0);
                        acc[tr][tc] = __builtin_amdgcn_mfma_f32_16x16x32_bf16(ah[tr], bl[tc], acc[tr][tc], 0, 0, 0);
                    }
            }

            if (ph == 1 && ch == 0) {
                #pragma unroll
                for (int tr = 0; tr < 2; ++tr)
                    #pragma unroll
                    for (int j = 0; j < 4; ++j) {
                        const int rr = w * 32 + tr * 16 + kgrp * 4 + j;
                        float s[NSTR];
                        #pragma unroll
                        for (int k = 0; k < NSTR; ++k)
                            s[k] = bf2f(Ahi[rr * KPAD + k]) + bf2f(Alo[rr * KPAD + k]);
                        #pragma unroll
                        for (int tc = 0; tc < 8; ++tc) {
                            float a = 0.f;
                            #pragma unroll
                            for (int k = 0; k < NSTR; ++k)
                                a = fmaf(s[k], Wstr[k * HID + tc * 16 + lrow], a);
                            acc[tr][tc][j] += a;
                        }
                    }
            }
        }
    }

    #pragma unroll
    for (int tr = 0; tr < 2; ++tr)
        #pragma unroll
        for (int j = 0; j < 4; ++j) {
            const int r = w * 32 + tr * 16 + kgrp * 4 + j;
            const bool valid = r < nrows;
            const size_t rb = (size_t)(row0 + r) * HID;
            const float sg = valid ? sig[row0 + r] : 0.f;
            float v[8], s1 = 0.f, s2 = 0.f;
            #pragma unroll
            for (int tc = 0; tc < 8; ++tc) {
                float x = fmaxf(acc[tr][tc][j] + sg * pb[tc], 0.f);
                if (valid) x += H[rb + tc * 16 + lrow];
                v[tc] = x;
                s1 += x; s2 += x * x;
            }
            #pragma unroll
            for (int mk = 1; mk < 16; mk <<= 1) {
                s1 += __shfl_xor(s1, mk);
                s2 += __shfl_xor(s2, mk);
            }
            const float mean = s1 * (1.f / HID);
            const float var  = s2 * (1.f / HID) - mean * mean;
            const float rs   = rsqrtf(var + LN_EPS);
            if (valid) {
                #pragma unroll
                for (int tc = 0; tc < 8; ++tc)
                    out[rb + tc * 16 + lrow] = (v[tc] - mean) * rs * gl[tc] + bl_[tc];
            }
        }
}

// ---------------------------------------------------------------------------
// CSR build via two-level LDS counting sort — ZERO global atomics.
// ---------------------------------------------------------------------------
__global__ __launch_bounds__(256) void k_csr_count(
    const int* __restrict__ etgt, const int* __restrict__ esrc,
    int* __restrict__ cnt_t, int* __restrict__ cnt_s,
    int NB, int NC, int E)
{
    __shared__ int cnt[256];
    const int which = blockIdx.y;
    const int* __restrict__ key = which ? esrc : etgt;
    int* __restrict__ outc = which ? cnt_s : cnt_t;
    const int tid = threadIdx.x;
    for (int i = tid; i < NB; i += 256) cnt[i] = 0;
    __syncthreads();
    const int e0 = blockIdx.x * CSR_CHUNK;
    const int e1 = min(e0 + CSR_CHUNK, E);
    for (int e = e0 + tid; e < e1; e += 256)
        atomicAdd(&cnt[key[e] >> 8], 1);
    __syncthreads();
    for (int k = tid; k < NB; k += 256)
        outc[(size_t)k * NC + blockIdx.x] = cnt[k];
}

__global__ __launch_bounds__(1024) void k_csr_scan(
    const int* __restrict__ cnt_t, int* __restrict__ off_t,
    const int* __restrict__ cnt_s, int* __restrict__ off_s, int L)
{
    const int* __restrict__ cnt = blockIdx.x ? cnt_s : cnt_t;
    int* __restrict__ off = blockIdx.x ? off_s : off_t;
    __shared__ int warp_sums[16];
    __shared__ int carry_s;
    const int tid = threadIdx.x, lane = tid & 63, wid = tid >> 6;
    if (tid == 0) carry_s = 0;
    __syncthreads();
    for (int i0 = 0; i0 < L; i0 += 1024) {
        const int i = i0 + tid;
        const int v = (i < L) ? cnt[i] : 0;
        int x = v;
        #pragma unroll
        for (int d = 1; d < 64; d <<= 1) {
            const int y = __shfl_up(x, d);
            if (lane >= d) x += y;
        }
        if (lane == 63) warp_sums[wid] = x;
        __syncthreads();
        if (wid == 0) {
            int ws = (lane < 16) ? warp_sums[lane] : 0;
            #pragma unroll
            for (int d = 1; d < 16; d <<= 1) {
                const int y = __shfl_up(ws, d);
                if (lane >= d) ws += y;
            }
            if (lane < 16) warp_sums[lane] = ws;
        }
        __syncthreads();
        const int carry = carry_s;
        if (i < L) off[i] = carry + (wid ? warp_sums[wid - 1] : 0) + x - v;
        __syncthreads();
        if (tid == 1023) carry_s = carry + warp_sums[15];
        __syncthreads();
    }
    if (tid == 0) off[L] = carry_s;
}

__global__ __launch_bounds__(256) void k_csr_bucket(
    const int* __restrict__ etgt, const int* __restrict__ esrc,
    const int* __restrict__ off_t, const int* __restrict__ off_s,
    int* __restrict__ ebuck_t, int* __restrict__ ebuck_s,
    int NB, int NC, int E)
{
    __shared__ int cur[256];
    const int which = blockIdx.y;
    const int* __restrict__ key = which ? esrc : etgt;
    const int* __restrict__ off = which ? off_s : off_t;
    int* __restrict__ ebuck = which ? ebuck_s : ebuck_t;
    const int tid = threadIdx.x;
    for (int k = tid; k < NB; k += 256)
        cur[k] = off[(size_t)k * NC + blockIdx.x];
    __syncthreads();
    const int e0 = blockIdx.x * CSR_CHUNK;
    const int e1 = min(e0 + CSR_CHUNK, E);
    for (int e = e0 + tid; e < e1; e += 256) {
        const int p = atomicAdd(&cur[key[e] >> 8], 1);
        ebuck[p] = e;
    }
}

__global__ __launch_bounds__(256) void k_csr_final(
    const int* __restrict__ etgt, const int* __restrict__ esrc,
    const int* __restrict__ off_t, const int* __restrict__ off_s,
    const int* __restrict__ ebuck_t, const int* __restrict__ ebuck_s,
    int* __restrict__ base_t, int* __restrict__ base_s,
    int* __restrict__ eid_t, int* __restrict__ eid_s,
    int NB, int NC, int N, int E)
{
    __shared__ int cnt[256], excl[256], wsum[4];
    const int which = blockIdx.y;
    const int* __restrict__ key   = which ? esrc : etgt;
    const int* __restrict__ off   = which ? off_s : off_t;
    const int* __restrict__ ebuck = which ? ebuck_s : ebuck_t;
    int* __restrict__ base = which ? base_s : base_t;
    int* __restrict__ eid  = which ? eid_s : eid_t;
    const int tid = threadIdx.x, lane = tid & 63, wv = tid >> 6;
    const int k = blockIdx.x;
    const int segb = off[(size_t)k * NC];
    const int sege = (k + 1 < NB) ? off[(size_t)(k + 1) * NC] : E;
    cnt[tid] = 0;
    __syncthreads();
    for (int i = segb + tid; i < sege; i += 256)
        atomicAdd(&cnt[key[ebuck[i]] & 255], 1);
    __syncthreads();
    {
        const int orig = cnt[tid];
        int x = orig;
        #pragma unroll
        for (int d = 1; d < 64; d <<= 1) {
            const int y = __shfl_up(x, d);
            if (lane >= d) x += y;
        }
        if (lane == 63) wsum[wv] = x;
        __syncthreads();
        if (tid == 0) {
            int a = 0;
            #pragma unroll
            for (int i = 0; i < 4; ++i) { const int t = wsum[i]; wsum[i] = a; a += t; }
        }
        __syncthreads();
        excl[tid] = x - orig + wsum[wv];
    }
    __syncthreads();
    const int node = k * 256 + tid;
    if (node < N) base[node] = segb + excl[tid];
    if (k == NB - 1 && tid == 0) base[N] = E;
    cnt[tid] = excl[tid];
    __syncthreads();
    for (int i = segb + tid; i < sege; i += 256) {
        const int e = ebuck[i];
        const int r = atomicAdd(&cnt[key[e] & 255], 1);
        eid[segb + r] = e;
    }
}

// ---------------------------------------------------------------------------
// k_score: wave per TARGET, 16-lane groups, 8 edges in flight (unroll 2).
// ---------------------------------------------------------------------------
__global__ __launch_bounds__(256) void k_score(
    const int* __restrict__ eid_t, const int* __restrict__ base_t,
    const int* __restrict__ esrc,
    const float* __restrict__ Wt, const float* __restrict__ Uf,
    const unsigned short* __restrict__ HB,
    float* __restrict__ score, float* __restrict__ pairv,
    float* __restrict__ sumt_inv, int N)
{
    const int lane = threadIdx.x & 63, wv = threadIdx.x >> 6;
    const int t = blockIdx.x * 4 + wv;
    if (t >= N) return;
    const int b0 = base_t[t], deg = base_t[t + 1] - b0;
    if (deg == 0) { if (lane == 0) sumt_inv[t] = 0.f; return; }
    const int sub = lane & 15, grp = lane >> 4;
    const size_t to = (size_t)t * HID;

    float wt[8], u[8], htg[8];
    {
        const f4 w0 = *(const f4*)&Wt[to + sub * 8];
        const f4 w1 = *(const f4*)&Wt[to + sub * 8 + 4];
        wt[0] = w0[0]; wt[1] = w0[1]; wt[2] = w0[2]; wt[3] = w0[3];
        wt[4] = w1[0]; wt[5] = w1[1]; wt[6] = w1[2]; wt[7] = w1[3];
        const f4 u0 = *(const f4*)&Uf[to + sub * 8];
        const f4 u1 = *(const f4*)&Uf[to + sub * 8 + 4];
        u[0] = u0[0]; u[1] = u0[1]; u[2] = u0[2]; u[3] = u0[3];
        u[4] = u1[0]; u[5] = u1[1]; u[6] = u1[2]; u[7] = u1[3];
        unpack8(*(const uint4*)&HB[to + sub * 8], htg);
    }

    for (int j0 = 0; j0 < deg; j0 += 8) {
        const int jA = j0 + grp, jB = j0 + 4 + grp;
        const bool vA = jA < deg, vB = jB < deg;
        int eA = 0, sA = 0, eB = 0, sB = 0;
        if (vA) { eA = eid_t[b0 + jA]; sA = esrc[eA]; }
        if (vB) { eB = eid_t[b0 + jB]; sB = esrc[eB]; }
        const uint4 rA = *(const uint4*)&HB[(size_t)sA * HID + sub * 8];
        const uint4 rB = *(const uint4*)&HB[(size_t)sB * HID + sub * 8];
        float hA[8], hB[8];
        unpack8(rA, hA); unpack8(rB, hB);
        float psA = 0.f, ppA = 0.f, psB = 0.f, ppB = 0.f;
        #pragma unroll
        for (int d = 0; d < 8; ++d) {
            psA = fmaf(wt[d], hA[d], psA);
            ppA = fmaf(u[d], hA[d], ppA);
            psB = fmaf(wt[d], hB[d], psB);
            ppB = fmaf(u[d], hB[d], ppB);
        }
        if (sub == 0) {
            #pragma unroll
            for (int d = 0; d < NSTR; ++d) {
                psA = fmaf(htg[d], hA[d], psA);
                psB = fmaf(htg[d], hB[d], psB);
            }
        }
        #pragma unroll
        for (int mk = 1; mk < 16; mk <<= 1) {
            psA += __shfl_xor(psA, mk);
            ppA += __shfl_xor(ppA, mk);
            psB += __shfl_xor(psB, mk);
            ppB += __shfl_xor(ppB, mk);
        }
        if (sub == 0) {
            if (vA) { score[b0 + jA] = psA; pairv[eA] = ppA; }
            if (vB) { score[b0 + jB] = psB; pairv[eB] = ppB; }
        }
    }

    float m = -1e30f;
    for (int i = lane; i < deg; i += 64) m = fmaxf(m, score[b0 + i]);
    #pragma unroll
    for (int mk = 1; mk < 64; mk <<= 1) m = fmaxf(m, __shfl_xor(m, mk));
    float psum = 0.f;
    for (int i = lane; i < deg; i += 64) {
        const float e = expf(score[b0 + i] - m);
        score[b0 + i] = e;
        psum += e;
    }
    #pragma unroll
    for (int mk = 1; mk < 64; mk <<= 1) psum += __shfl_xor(psum, mk);
    if (lane == 0) sumt_inv[t] = 1.f / psum;
}

// ---------------------------------------------------------------------------
// k_beta2: wave per SOURCE node, streaming; fuses rho.
// ---------------------------------------------------------------------------
__global__ __launch_bounds__(256) void k_beta2(
    const int* __restrict__ base_s, const int* __restrict__ eid_s,
    const int* __restrict__ etgt,
    const float* __restrict__ pairv, const float* __restrict__ psi,
    float* __restrict__ rho1m, int N)
{
    const int lane = threadIdx.x & 63, wv = threadIdx.x >> 6;
    const int s = blockIdx.x * 4 + wv;
    if (s >= N) return;
    const int b0 = base_s[s], deg = base_s[s + 1] - b0;

    float m = -1e30f;
    for (int i = lane; i < deg; i += 64) m = fmaxf(m, pairv[eid_s[b0 + i]]);
    #pragma unroll
    for (int mk = 1; mk < 64; mk <<= 1) m = fmaxf(m, __shfl_xor(m, mk));

    float se = 0.f, sn = 0.f;
    for (int i = lane; i < deg; i += 64) {
        const int e = eid_s[b0 + i];
        const float ex = expf(pairv[e] - m);
        se += ex;
        sn += ex * expf(-psi[etgt[e]]);
    }
    #pragma unroll
    for (int mk = 1; mk < 64; mk <<= 1) {
        se += __shfl_xor(se, mk);
        sn += __shfl_xor(sn, mk);
    }
    if (lane == 0) {
        const float st = (deg > 0 && se > 0.f) ? sn / se : 0.f;
        const float d  = -logf(st + 1e-8f);
        rho1m[s] = 1.f - 1.f / (1.f + expf(-(GAMMA * (d - DELTA))));
    }
}

// ---------------------------------------------------------------------------
// k_matt: wave per TARGET, 8 edges in flight; gathers HB (shared with score).
// agg[t] = sum_e c_e * H_bf[src];  sig[t] = sum_e c_e.
// ---------------------------------------------------------------------------
__global__ __launch_bounds__(256) void k_matt(
    const int* __restrict__ eid_t, const int* __restrict__ base_t,
    const int* __restrict__ esrc,
    const float* __restrict__ score, const float* __restrict__ sumt_inv,
    const float* __restrict__ rho1m,
    const unsigned short* __restrict__ HB,
    float* __restrict__ agg, float* __restrict__ sig, int N)
{
    const int lane = threadIdx.x & 63, wv = threadIdx.x >> 6;
    const int t = blockIdx.x * 4 + wv;
    if (t >= N) return;
    const int b0 = base_t[t], deg = base_t[t + 1] - b0;
    const int sub = lane & 15, grp = lane >> 4;
    const size_t to = (size_t)t * HID;

    float acc[8];
    #pragma unroll
    for (int d = 0; d < 8; ++d) acc[d] = 0.f;
    float csum = 0.f;
    const float inv = (deg > 0) ? sumt_inv[t] : 0.f;

    for (int j0 = 0; j0 < deg; j0 += 8) {
        const int jA = j0 + grp, jB = j0 + 4 + grp;
        const bool vA = jA < deg, vB = jB < deg;
        float cA = 0.f, cB = 0.f;
        size_t soA = 0, soB = 0;
        if (vA) {
            const int e = eid_t[b0 + jA];
            const int s = esrc[e];
            cA = score[b0 + jA] * inv * rho1m[s];
            soA = (size_t)s * HID;
        }
        if (vB) {
            const int e = eid_t[b0 + jB];
            const int s = esrc[e];
            cB = score[b0 + jB] * inv * rho1m[s];
            soB = (size_t)s * HID;
        }
        const uint4 rA = *(const uint4*)&HB[soA + sub * 8];
        const uint4 rB = *(const uint4*)&HB[soB + sub * 8];
        float hA[8], hB[8];
        unpack8(rA, hA); unpack8(rB, hB);
        #pragma unroll
        for (int d = 0; d < 8; ++d) {
            acc[d] = fmaf(cA, hA[d], acc[d]);
            acc[d] = fmaf(cB, hB[d], acc[d]);
        }
        if (sub == 0) csum += cA + cB;
    }
    #pragma unroll
    for (int d = 0; d < 8; ++d) {
        acc[d] += __shfl_xor(acc[d], 16);
        acc[d] += __shfl_xor(acc[d], 32);
    }
    csum += __shfl_xor(csum, 16);
    csum += __shfl_xor(csum, 32);
    if (grp == 0) {
        f4 o0, o1;
        #pragma unroll
        for (int d = 0; d < 4; ++d) { o0[d] = acc[d]; o1[d] = acc[d + 4]; }
        *(f4*)&agg[to + sub * 8]     = o0;
        *(f4*)&agg[to + sub * 8 + 4] = o1;
        if (sub == 0) sig[t] = csum;
    }
}

extern "C" void kernel_launch(void* const* d_in, const int* in_sizes, int n_in,
                              void* d_out, int out_size, void* d_ws, size_t ws_size,
                              hipStream_t stream)
{
    const int*   eidx   = (const int*)  d_in[0];
    const float* H      = (const float*)d_in[1];
    const float* W_att  = (const float*)d_in[2];
    const float* phi_w  = (const float*)d_in[3];
    const float* phi_b  = (const float*)d_in[4];
    const float* W_p    = (const float*)d_in[5];
    const float* W_pp   = (const float*)d_in[6];
    const float* fdef_w = (const float*)d_in[7];
    const float* fdef_b = (const float*)d_in[8];
    const float* Wself  = (const float*)d_in[9];
    const float* bself  = (const float*)d_in[10];
    const float* WA     = (const float*)d_in[11];
    const float* bA     = (const float*)d_in[12];
    const float* Wstr   = (const float*)d_in[13];
    const float* bstr   = (const float*)d_in[14];
    const float* lng    = (const float*)d_in[15];
    const float* lnb    = (const float*)d_in[16];
    float* out = (float*)d_out;

    const int E = in_sizes[0] / 2;
    const int N = in_sizes[1] / HID;
    const int* esrc = eidx;
    const int* etgt = eidx + E;

    const int NB = (N + 255) >> 8;
    const int NC = (E + CSR_CHUNK - 1) / CSR_CHUNK;
    const int L  = NB * NC;

    // ---- workspace layout (~84 MB) ----
    char* w = (char*)d_ws;
    const size_t NHb  = (size_t)N * HID * sizeof(unsigned short);
    const size_t NH   = (size_t)N * HID * sizeof(float);
    const size_t Epad = (((size_t)E * sizeof(float)) + 255) & ~255ull;
    const size_t Npad = (((size_t)(N + 1) * sizeof(float)) + 255) & ~255ull;
    const size_t Lpad = (((size_t)(L + 1) * sizeof(int)) + 255) & ~255ull;

    float*          Wt    = (float*)w;          w += NH;   // agg aliases after k_score
    float*          Uf    = (float*)w;          w += NH;
    unsigned short* HB    = (unsigned short*)w; w += NHb;
    float* score   = (float*)w; w += Epad;  // CSR-tgt order
    float* pairv   = (float*)w; w += Epad;  // edge-id order
    int*   eid_t   = (int*)  w; w += Epad;
    int*   eid_s   = (int*)  w; w += Epad;
    int*   ebuck_t = (int*)  w; w += Epad;
    int*   ebuck_s = (int*)  w; w += Epad;
    int*   cnt_t = (int*)w; w += Lpad;
    int*   off_t = (int*)w; w += Lpad;
    int*   cnt_s = (int*)w; w += Lpad;
    int*   off_s = (int*)w; w += Lpad;
    int*   base_t   = (int*)  w; w += Npad;   // N+1
    int*   base_s   = (int*)  w; w += Npad;   // N+1
    float* sumt_inv = (float*)w; w += Npad;
    float* psi      = (float*)w; w += Npad;
    float* rho1m    = (float*)w; w += Npad;
    float* sig      = (float*)w; w += Npad;
    float* pbA      = (float*)w; w += 512;   // 128 floats (BUGFIX: was 256 B -> stomped WT slot 0)
    unsigned short* WT = (unsigned short*)w;  // 4 slots x 2 planes x 128x128
    w += 4 * 2 * HID * HID * sizeof(unsigned short);
    float* agg = Wt;   // alias: Wt dead after k_score

    const int nblk128 = (N + 127) / 128;
    const int nblkN4  = (N + 3) / 4;
    const size_t lds_mfma = 4 * 128 * KPAD * sizeof(unsigned short);  // 72 KB
    const size_t MSZ = (size_t)2 * HID * HID;

    // slots: 0 = W_att(nat), 1 = Wself(T), 2 = M2, 3 = G
    PrepArgs pa;
    pa.W[0] = W_att; pa.tr[0] = 0;
    pa.W[1] = Wself; pa.tr[1] = 1;
    k_prep<<<dim3(8, 2), 256, 0, stream>>>(pa, WT);
    k_m2<<<8, 256, 0, stream>>>(W_p, W_pp, WT + 2 * MSZ);
    k_g<<<8, 256, 0, stream>>>(phi_w, WA, phi_b, WT + 3 * MSZ, pbA);

    k_castpsi<<<(N + 15) / 16, 256, 0, stream>>>(H, fdef_w, fdef_b, HB, psi, N);

    GemmArgsT g2;
    g2.Whi[0] = WT;           g2.Wlo[0] = WT + HID * HID;             // W_att
    g2.Whi[1] = WT + 2 * MSZ; g2.Wlo[1] = WT + 2 * MSZ + HID * HID;   // M2
    g2.O[0] = Wt;
    g2.O[1] = Uf;
    k_gemm<<<dim3(nblk128, 2), 256, lds_mfma, stream>>>(H, g2, N);

    // ---- CSR build (no global atomics) ----
    k_csr_count<<<dim3(NC, 2), 256, 0, stream>>>(etgt, esrc, cnt_t, cnt_s, NB, NC, E);
    k_csr_scan<<<2, 1024, 0, stream>>>(cnt_t, off_t, cnt_s, off_s, L);
    k_csr_bucket<<<dim3(NC, 2), 256, 0, stream>>>(etgt, esrc, off_t, off_s,
                                                  ebuck_t, ebuck_s, NB, NC, E);
    k_csr_final<<<dim3(NB, 2), 256, 0, stream>>>(etgt, esrc, off_t, off_s,
                                                 ebuck_t, ebuck_s, base_t, base_s,
                                                 eid_t, eid_s, NB, NC, N, E);

    k_score<<<nblkN4, 256, 0, stream>>>(eid_t, base_t, esrc, Wt, Uf, HB,
                                        score, pairv, sumt_inv, N);
    k_beta2<<<nblkN4, 256, 0, stream>>>(base_s, eid_s, etgt, pairv, psi, rho1m, N);

    k_matt<<<nblkN4, 256, 0, stream>>>(eid_t, base_t, esrc, score, sumt_inv,
                                       rho1m, HB, agg, sig, N);

    k_final<<<nblk128, 256, lds_mfma, stream>>>(agg, H, sig, pbA,
                                                WT + 3 * MSZ, WT + 3 * MSZ + HID * HID,
                                                WT + 1 * MSZ, WT + 1 * MSZ + HID * HID,
                                                Wstr, bself, bA, bstr, lng, lnb, out, N);
}

// Round 13
// 348.055 us; speedup vs baseline: 1.3634x; 1.0590x over previous
//
#include <hip/hip_runtime.h>
#include <math.h>

#define HID 128
#define NSTR 6              // STRUCT-1
#define GAMMA 1.0f
#define DELTA 0.5f
#define LN_EPS 1e-5f
#define KPAD 72             // bf16 elems per LDS row (64 + 8 pad)
#define CSR_CHUNK 8192      // edges per block in CSR build

typedef __attribute__((ext_vector_type(4))) float f4;
typedef __attribute__((ext_vector_type(8))) short bf16x8;
typedef __attribute__((ext_vector_type(4))) float f32x4;

// f32 -> bf16 (round-to-nearest-even) and helpers
__device__ __forceinline__ unsigned short f2bf(float f) {
    unsigned u = __float_as_uint(f);
    unsigned r = u + 0x7FFFu + ((u >> 16) & 1u);
    return (unsigned short)(r >> 16);
}
__device__ __forceinline__ float bf2f(unsigned short h) {
    return __uint_as_float((unsigned)h << 16);
}
__device__ __forceinline__ void split2(float v, unsigned short& h, unsigned short& l) {
    h = f2bf(v);
    l = f2bf(v - bf2f(h));
}
__device__ __forceinline__ void bf2f2(unsigned u, float& lo, float& hi) {
    lo = __uint_as_float(u << 16);
    hi = __uint_as_float(u & 0xFFFF0000u);
}
__device__ __forceinline__ void unpack8(const uint4 u, float* f) {
    bf2f2(u.x, f[0], f[1]); bf2f2(u.y, f[2], f[3]);
    bf2f2(u.z, f[4], f[5]); bf2f2(u.w, f[6], f[7]);
}

// ---------------------------------------------------------------------------
// k_prep: split (optionally transpose) weight matrices into WT slots.
// slot m: [hi 128x128][lo 128x128] bf16, table[c][k].
// ---------------------------------------------------------------------------
struct PrepArgs { const float* W[2]; int tr[2]; };

__global__ __launch_bounds__(256) void k_prep(PrepArgs p, unsigned short* WT)
{
    __shared__ float T[128][17];
    const int m = blockIdx.y, c0 = blockIdx.x * 16;
    const int tid = threadIdx.x;
    const float* __restrict__ W = p.W[m];
    unsigned short* hi = WT + (size_t)m * 2 * HID * HID;
    unsigned short* lo = hi + HID * HID;
    if (p.tr[m]) {
        for (int idx = tid; idx < 2048; idx += 256) {
            const int k = idx >> 4, c = idx & 15;
            T[k][c] = W[k * HID + c0 + c];
        }
        __syncthreads();
        for (int idx = tid; idx < 2048; idx += 256) {
            const int c = idx >> 7, k = idx & 127;
            unsigned short h, l;
            split2(T[k][c], h, l);
            hi[(size_t)(c0 + c) * HID + k] = h;
            lo[(size_t)(c0 + c) * HID + k] = l;
        }
    } else {
        for (int idx = tid; idx < 2048; idx += 256) {
            const int c = idx >> 7, k = idx & 127;
            unsigned short h, l;
            split2(W[(size_t)(c0 + c) * HID + k], h, l);
            hi[(size_t)(c0 + c) * HID + k] = h;
            lo[(size_t)(c0 + c) * HID + k] = l;
        }
    }
}

// k_m2: M2 = W_p @ W_pp^T split into slot: tbl[c][k] = sum_j Wp[c][j]*Wpp[k][j]
__global__ __launch_bounds__(256) void k_m2(
    const float* __restrict__ Wp, const float* __restrict__ Wpp,
    unsigned short* __restrict__ slot)
{
    __shared__ float Bs[128][129];
    __shared__ float As[16][129];
    const int tid = threadIdx.x, c0 = blockIdx.x * 16;
    for (int idx = tid; idx < 128 * 128; idx += 256)
        Bs[idx >> 7][idx & 127] = Wpp[idx];
    for (int idx = tid; idx < 16 * 128; idx += 256)
        As[idx >> 7][idx & 127] = Wp[(size_t)(c0 + (idx >> 7)) * HID + (idx & 127)];
    __syncthreads();
    unsigned short* hi = slot;
    unsigned short* lo = slot + HID * HID;
    for (int it = 0; it < 8; ++it) {
        const int idx = tid + 256 * it;
        const int c = idx >> 7, k = idx & 127;
        float a = 0.f;
        #pragma unroll 4
        for (int j = 0; j < 128; ++j)
            a = fmaf(As[c][j], Bs[k][j], a);
        unsigned short h, l;
        split2(a, h, l);
        hi[(size_t)(c0 + c) * HID + k] = h;
        lo[(size_t)(c0 + c) * HID + k] = l;
    }
}

// ---------------------------------------------------------------------------
// k_g: G-table for agg@(phi_w@W_A): tbl[c][k] = sum_j phi_w[k][j]*W_A[j][c]
// Also pbA[c] = sum_j phi_b[j]*W_A[j][c].
// ---------------------------------------------------------------------------
__global__ __launch_bounds__(256) void k_g(
    const float* __restrict__ phiw, const float* __restrict__ WA,
    const float* __restrict__ phib,
    unsigned short* __restrict__ slot, float* __restrict__ pbA)
{
    __shared__ float Bs[128][129];   // phi_w rows
    __shared__ float As[16][129];    // W_A columns c0..c0+15
    const int tid = threadIdx.x, c0 = blockIdx.x * 16;
    for (int idx = tid; idx < 128 * 128; idx += 256)
        Bs[idx >> 7][idx & 127] = phiw[idx];
    for (int idx = tid; idx < 16 * 128; idx += 256) {
        const int c = idx >> 7, j = idx & 127;
        As[c][j] = WA[(size_t)j * HID + c0 + c];
    }
    __syncthreads();
    unsigned short* hi = slot;
    unsigned short* lo = slot + HID * HID;
    for (int it = 0; it < 8; ++it) {
        const int idx = tid + 256 * it;
        const int c = idx >> 7, k = idx & 127;
        float a = 0.f;
        #pragma unroll 4
        for (int j = 0; j < 128; ++j)
            a = fmaf(As[c][j], Bs[k][j], a);
        unsigned short h, l;
        split2(a, h, l);
        hi[(size_t)(c0 + c) * HID + k] = h;
        lo[(size_t)(c0 + c) * HID + k] = l;
    }
    if (tid < 16) {
        float a = 0.f;
        #pragma unroll 4
        for (int j = 0; j < 128; ++j)
            a = fmaf(phib[j], As[tid][j], a);
        pbA[c0 + tid] = a;
    }
}

// ---------------------------------------------------------------------------
// k_castpsi: HB = bf16(H) AND psi = H.f_def_w + f_def_b in one H pass.
// ---------------------------------------------------------------------------
__global__ __launch_bounds__(256) void k_castpsi(
    const float* __restrict__ H, const float* __restrict__ fw,
    const float* __restrict__ fb,
    unsigned short* __restrict__ HB, float* __restrict__ psi, int N)
{
    const int tid = threadIdx.x;
    const int row = blockIdx.x * 16 + (tid >> 4), sub = tid & 15;
    if (row >= N) return;
    const size_t o = (size_t)row * HID + sub * 8;
    const f4 v0 = *(const f4*)&H[o];
    const f4 v1 = *(const f4*)&H[o + 4];
    ushort4 a, b;
    a.x = f2bf(v0[0]); a.y = f2bf(v0[1]); a.z = f2bf(v0[2]); a.w = f2bf(v0[3]);
    b.x = f2bf(v1[0]); b.y = f2bf(v1[1]); b.z = f2bf(v1[2]); b.w = f2bf(v1[3]);
    *(ushort4*)&HB[o] = a;
    *(ushort4*)&HB[o + 4] = b;
    const f4 w0 = *(const f4*)&fw[sub * 8];
    const f4 w1 = *(const f4*)&fw[sub * 8 + 4];
    float s = v0[0]*w0[0] + v0[1]*w0[1] + v0[2]*w0[2] + v0[3]*w0[3]
            + v1[0]*w1[0] + v1[1]*w1[1] + v1[2]*w1[2] + v1[3]*w1[3];
    #pragma unroll
    for (int mk = 1; mk < 16; mk <<= 1) s += __shfl_xor(s, mk);
    if (sub == 0) psi[row] = s + fb[0];
}

struct GemmArgsT {
    const unsigned short* Whi[2];
    const unsigned short* Wlo[2];
    void*                 O[2];
    int                   of32[2];
};

// ---------------------------------------------------------------------------
// MFMA GEMM: O[ph] = A @ B[ph], split-precision (hi/lo bf16, 3 MFMA).
// Output f32 or bf16 per of32 flag.
// ---------------------------------------------------------------------------
__global__ __launch_bounds__(256, 2) void k_gemm(const float* __restrict__ A,
                                                 GemmArgsT g, int N)
{
    extern __shared__ unsigned short lds[];
    unsigned short* Ahi = lds;
    unsigned short* Alo = lds + 128 * KPAD;
    unsigned short* Bhi = lds + 2 * 128 * KPAD;
    unsigned short* Blo = lds + 3 * 128 * KPAD;
    const int tid  = threadIdx.x;
    const int row0 = blockIdx.x * 128;
    const int nrows = min(128, N - row0);
    const int ph   = blockIdx.y;
    const int w    = tid >> 6, lane = tid & 63;
    const int lrow = lane & 15, kgrp = lane >> 4;

    f32x4 acc[2][8];
    #pragma unroll
    for (int tc = 0; tc < 8; ++tc) {
        acc[0][tc] = f32x4{0.f, 0.f, 0.f, 0.f};
        acc[1][tc] = f32x4{0.f, 0.f, 0.f, 0.f};
    }

    const unsigned short* __restrict__ Wh = g.Whi[ph];
    const unsigned short* __restrict__ Wl = g.Wlo[ph];

    for (int ch = 0; ch < 2; ++ch) {
        __syncthreads();
        #pragma unroll
        for (int it = 0; it < 8; ++it) {
            const int idx = tid + 256 * it;
            const int r = idx >> 4, kq = (idx & 15) * 4;
            f4 v = {0.f, 0.f, 0.f, 0.f};
            if (r < nrows) v = *(const f4*)&A[(size_t)(row0 + r) * HID + ch * 64 + kq];
            ushort4 h, l;
            split2(v[0], h.x, l.x); split2(v[1], h.y, l.y);
            split2(v[2], h.z, l.z); split2(v[3], h.w, l.w);
            *(ushort4*)&Ahi[r * KPAD + kq] = h;
            *(ushort4*)&Alo[r * KPAD + kq] = l;
        }
        #pragma unroll
        for (int it = 0; it < 4; ++it) {
            const int idx = tid + 256 * it;
            const int c = idx >> 3, k8 = (idx & 7) * 8;
            *(uint4*)&Bhi[c * KPAD + k8] = *(const uint4*)&Wh[(size_t)c * HID + ch * 64 + k8];
            *(uint4*)&Blo[c * KPAD + k8] = *(const uint4*)&Wl[(size_t)c * HID + ch * 64 + k8];
        }
        __syncthreads();

        #pragma unroll
        for (int ks = 0; ks < 2; ++ks) {
            const int ko = ks * 32 + kgrp * 8;
            bf16x8 ah[2], al[2], bh[8], bl[8];
            #pragma unroll
            for (int tr = 0; tr < 2; ++tr) {
                const int rr = w * 32 + tr * 16 + lrow;
                ah[tr] = *(const bf16x8*)&Ahi[rr * KPAD + ko];
                al[tr] = *(const bf16x8*)&Alo[rr * KPAD + ko];
            }
            #pragma unroll
            for (int tc = 0; tc < 8; ++tc) {
                const int cc = tc * 16 + lrow;
                bh[tc] = *(const bf16x8*)&Bhi[cc * KPAD + ko];
                bl[tc] = *(const bf16x8*)&Blo[cc * KPAD + ko];
            }
            #pragma unroll
            for (int tr = 0; tr < 2; ++tr)
                #pragma unroll
                for (int tc = 0; tc < 8; ++tc) {
                    acc[tr][tc] = __builtin_amdgcn_mfma_f32_16x16x32_bf16(ah[tr], bh[tc], acc[tr][tc], 0, 0, 0);
                    acc[tr][tc] = __builtin_amdgcn_mfma_f32_16x16x32_bf16(al[tr], bh[tc], acc[tr][tc], 0, 0, 0);
                    acc[tr][tc] = __builtin_amdgcn_mfma_f32_16x16x32_bf16(ah[tr], bl[tc], acc[tr][tc], 0, 0, 0);
                }
        }
    }

    #pragma unroll
    for (int tr = 0; tr < 2; ++tr)
        #pragma unroll
        for (int j = 0; j < 4; ++j) {
            const int r = w * 32 + tr * 16 + kgrp * 4 + j;
            if (r < nrows) {
                if (g.of32[ph]) {
                    float* O = (float*)g.O[ph];
                    #pragma unroll
                    for (int tc = 0; tc < 8; ++tc)
                        O[(size_t)(row0 + r) * HID + tc * 16 + lrow] = acc[tr][tc][j];
                } else {
                    unsigned short* O = (unsigned short*)g.O[ph];
                    #pragma unroll
                    for (int tc = 0; tc < 8; ++tc)
                        O[(size_t)(row0 + r) * HID + tc * 16 + lrow] = f2bf(acc[tr][tc][j]);
                }
            }
        }
}

// ---------------------------------------------------------------------------
// k_final: out = LN(relu(agg@G + sig*pbA + H@Wself + s@Wstr + biases) + H)
// ---------------------------------------------------------------------------
__global__ __launch_bounds__(256, 2) void k_final(
    const float* __restrict__ Agg, const float* __restrict__ H,
    const float* __restrict__ sig, const float* __restrict__ pbA,
    const unsigned short* __restrict__ Ghi, const unsigned short* __restrict__ Glo,
    const unsigned short* __restrict__ WShi, const unsigned short* __restrict__ WSlo,
    const float* __restrict__ Wstr,
    const float* __restrict__ bself, const float* __restrict__ bA,
    const float* __restrict__ bstr,
    const float* __restrict__ lng, const float* __restrict__ lnb,
    float* __restrict__ out, int N)
{
    extern __shared__ unsigned short lds[];
    unsigned short* Ahi = lds;
    unsigned short* Alo = lds + 128 * KPAD;
    unsigned short* Bhi = lds + 2 * 128 * KPAD;
    unsigned short* Blo = lds + 3 * 128 * KPAD;
    const int tid  = threadIdx.x;
    const int row0 = blockIdx.x * 128;
    const int nrows = min(128, N - row0);
    const int w    = tid >> 6, lane = tid & 63;
    const int lrow = lane & 15, kgrp = lane >> 4;

    f32x4 acc[2][8];
    float gl[8], bl_[8], pb[8];
    #pragma unroll
    for (int tc = 0; tc < 8; ++tc) {
        const int c = tc * 16 + lrow;
        const float bv = bself[c] + bA[c] + bstr[c];
        acc[0][tc] = f32x4{bv, bv, bv, bv};
        acc[1][tc] = f32x4{bv, bv, bv, bv};
        gl[tc] = lng[c]; bl_[tc] = lnb[c]; pb[tc] = pbA[c];
    }

    for (int ph = 0; ph < 2; ++ph) {
        const float* __restrict__ Am = ph ? H : Agg;
        const unsigned short* __restrict__ Wh = ph ? WShi : Ghi;
        const unsigned short* __restrict__ Wl = ph ? WSlo : Glo;
        for (int ch = 0; ch < 2; ++ch) {
            __syncthreads();
            #pragma unroll
            for (int it = 0; it < 8; ++it) {
                const int idx = tid + 256 * it;
                const int r = idx >> 4, kq = (idx & 15) * 4;
                f4 v = {0.f, 0.f, 0.f, 0.f};
                if (r < nrows) v = *(const f4*)&Am[(size_t)(row0 + r) * HID + ch * 64 + kq];
                ushort4 h, l;
                split2(v[0], h.x, l.x); split2(v[1], h.y, l.y);
                split2(v[2], h.z, l.z); split2(v[3], h.w, l.w);
                *(ushort4*)&Ahi[r * KPAD + kq] = h;
                *(ushort4*)&Alo[r * KPAD + kq] = l;
            }
            #pragma unroll
            for (int it = 0; it < 4; ++it) {
                const int idx = tid + 256 * it;
                const int c = idx >> 3, k8 = (idx & 7) * 8;
                *(uint4*)&Bhi[c * KPAD + k8] = *(const uint4*)&Wh[(size_t)c * HID + ch * 64 + k8];
                *(uint4*)&Blo[c * KPAD + k8] = *(const uint4*)&Wl[(size_t)c * HID + ch * 64 + k8];
            }
            __syncthreads();

            #pragma unroll
            for (int ks = 0; ks < 2; ++ks) {
                const int ko = ks * 32 + kgrp * 8;
                bf16x8 ah[2], al[2], bh[8], bl[8];
                #pragma unroll
                for (int tr = 0; tr < 2; ++tr) {
                    const int rr = w * 32 + tr * 16 + lrow;
                    ah[tr] = *(const bf16x8*)&Ahi[rr * KPAD + ko];
                    al[tr] = *(const bf16x8*)&Alo[rr * KPAD + ko];
                }
                #pragma unroll
                for (int tc = 0; tc < 8; ++tc) {
                    const int cc = tc * 16 + lrow;
                    bh[tc] = *(const bf16x8*)&Bhi[cc * KPAD + ko];
                    bl[tc] = *(const bf16x8*)&Blo[cc * KPAD + ko];
                }
                #pragma unroll
                for (int tr = 0; tr < 2; ++tr)
                    #pragma unroll
                    for (int tc = 0; tc < 8; ++tc) {
                        acc[tr][tc] = __builtin_amdgcn_mfma_f32_16x16x32_bf16(ah[tr], bh[tc], acc[tr][tc], 0, 0, 0);
                        acc[tr][tc] = __builtin_amdgcn_mfma_f32_16x16x32_bf16(al[tr], bh[tc], acc[tr][tc], 0, 0, 0);
                        acc[tr][tc] = __builtin_amdgcn_mfma_f32_16x16x32_bf16(ah[tr], bl[tc], acc[tr][tc], 0, 0, 0);
                    }
            }

            if (ph == 1 && ch == 0) {
                #pragma unroll
                for (int tr = 0; tr < 2; ++tr)
                    #pragma unroll
                    for (int j = 0; j < 4; ++j) {
                        const int rr = w * 32 + tr * 16 + kgrp * 4 + j;
                        float s[NSTR];
                        #pragma unroll
                        for (int k = 0; k < NSTR; ++k)
                            s[k] = bf2f(Ahi[rr * KPAD + k]) + bf2f(Alo[rr * KPAD + k]);
                        #pragma unroll
                        for (int tc = 0; tc < 8; ++tc) {
                            float a = 0.f;
                            #pragma unroll
                            for (int k = 0; k < NSTR; ++k)
                                a = fmaf(s[k], Wstr[k * HID + tc * 16 + lrow], a);
                            acc[tr][tc][j] += a;
                        }
                    }
            }
        }
    }

    #pragma unroll
    for (int tr = 0; tr < 2; ++tr)
        #pragma unroll
        for (int j = 0; j < 4; ++j) {
            const int r = w * 32 + tr * 16 + kgrp * 4 + j;
            const bool valid = r < nrows;
            const size_t rb = (size_t)(row0 + r) * HID;
            const float sg = valid ? sig[row0 + r] : 0.f;
            float v[8], s1 = 0.f, s2 = 0.f;
            #pragma unroll
            for (int tc = 0; tc < 8; ++tc) {
                float x = fmaxf(acc[tr][tc][j] + sg * pb[tc], 0.f);
                if (valid) x += H[rb + tc * 16 + lrow];
                v[tc] = x;
                s1 += x; s2 += x * x;
            }
            #pragma unroll
            for (int mk = 1; mk < 16; mk <<= 1) {
                s1 += __shfl_xor(s1, mk);
                s2 += __shfl_xor(s2, mk);
            }
            const float mean = s1 * (1.f / HID);
            const float var  = s2 * (1.f / HID) - mean * mean;
            const float rs   = rsqrtf(var + LN_EPS);
            if (valid) {
                #pragma unroll
                for (int tc = 0; tc < 8; ++tc)
                    out[rb + tc * 16 + lrow] = (v[tc] - mean) * rs * gl[tc] + bl_[tc];
            }
        }
}

// ---------------------------------------------------------------------------
// CSR build via two-level LDS counting sort — ZERO global atomics.
// ---------------------------------------------------------------------------
__global__ __launch_bounds__(256) void k_csr_count(
    const int* __restrict__ etgt, const int* __restrict__ esrc,
    int* __restrict__ cnt_t, int* __restrict__ cnt_s,
    int NB, int NC, int E)
{
    __shared__ int cnt[256];
    const int which = blockIdx.y;
    const int* __restrict__ key = which ? esrc : etgt;
    int* __restrict__ outc = which ? cnt_s : cnt_t;
    const int tid = threadIdx.x;
    for (int i = tid; i < NB; i += 256) cnt[i] = 0;
    __syncthreads();
    const int e0 = blockIdx.x * CSR_CHUNK;
    const int e1 = min(e0 + CSR_CHUNK, E);
    for (int e = e0 + tid; e < e1; e += 256)
        atomicAdd(&cnt[key[e] >> 8], 1);
    __syncthreads();
    for (int k = tid; k < NB; k += 256)
        outc[(size_t)k * NC + blockIdx.x] = cnt[k];
}

__global__ __launch_bounds__(1024) void k_csr_scan(
    const int* __restrict__ cnt_t, int* __restrict__ off_t,
    const int* __restrict__ cnt_s, int* __restrict__ off_s, int L)
{
    const int* __restrict__ cnt = blockIdx.x ? cnt_s : cnt_t;
    int* __restrict__ off = blockIdx.x ? off_s : off_t;
    __shared__ int warp_sums[16];
    __shared__ int carry_s;
    const int tid = threadIdx.x, lane = tid & 63, wid = tid >> 6;
    if (tid == 0) carry_s = 0;
    __syncthreads();
    for (int i0 = 0; i0 < L; i0 += 1024) {
        const int i = i0 + tid;
        const int v = (i < L) ? cnt[i] : 0;
        int x = v;
        #pragma unroll
        for (int d = 1; d < 64; d <<= 1) {
            const int y = __shfl_up(x, d);
            if (lane >= d) x += y;
        }
        if (lane == 63) warp_sums[wid] = x;
        __syncthreads();
        if (wid == 0) {
            int ws = (lane < 16) ? warp_sums[lane] : 0;
            #pragma unroll
            for (int d = 1; d < 16; d <<= 1) {
                const int y = __shfl_up(ws, d);
                if (lane >= d) ws += y;
            }
            if (lane < 16) warp_sums[lane] = ws;
        }
        __syncthreads();
        const int carry = carry_s;
        if (i < L) off[i] = carry + (wid ? warp_sums[wid - 1] : 0) + x - v;
        __syncthreads();
        if (tid == 1023) carry_s = carry + warp_sums[15];
        __syncthreads();
    }
    if (tid == 0) off[L] = carry_s;
}

__global__ __launch_bounds__(256) void k_csr_bucket(
    const int* __restrict__ etgt, const int* __restrict__ esrc,
    const int* __restrict__ off_t, const int* __restrict__ off_s,
    int* __restrict__ ebuck_t, int* __restrict__ ebuck_s,
    int NB, int NC, int E)
{
    __shared__ int cur[256];
    const int which = blockIdx.y;
    const int* __restrict__ key = which ? esrc : etgt;
    const int* __restrict__ off = which ? off_s : off_t;
    int* __restrict__ ebuck = which ? ebuck_s : ebuck_t;
    const int tid = threadIdx.x;
    for (int k = tid; k < NB; k += 256)
        cur[k] = off[(size_t)k * NC + blockIdx.x];
    __syncthreads();
    const int e0 = blockIdx.x * CSR_CHUNK;
    const int e1 = min(e0 + CSR_CHUNK, E);
    for (int e = e0 + tid; e < e1; e += 256) {
        const int p = atomicAdd(&cur[key[e] >> 8], 1);
        ebuck[p] = e;
    }
}

__global__ __launch_bounds__(256) void k_csr_final(
    const int* __restrict__ etgt, const int* __restrict__ esrc,
    const int* __restrict__ off_t, const int* __restrict__ off_s,
    const int* __restrict__ ebuck_t, const int* __restrict__ ebuck_s,
    int* __restrict__ base_t, int* __restrict__ base_s,
    int* __restrict__ eid_t, int* __restrict__ eid_s,
    int NB, int NC, int N, int E)
{
    __shared__ int cnt[256], excl[256], wsum[4];
    const int which = blockIdx.y;
    const int* __restrict__ key   = which ? esrc : etgt;
    const int* __restrict__ off   = which ? off_s : off_t;
    const int* __restrict__ ebuck = which ? ebuck_s : ebuck_t;
    int* __restrict__ base = which ? base_s : base_t;
    int* __restrict__ eid  = which ? eid_s : eid_t;
    const int tid = threadIdx.x, lane = tid & 63, wv = tid >> 6;
    const int k = blockIdx.x;
    const int segb = off[(size_t)k * NC];
    const int sege = (k + 1 < NB) ? off[(size_t)(k + 1) * NC] : E;
    cnt[tid] = 0;
    __syncthreads();
    for (int i = segb + tid; i < sege; i += 256)
        atomicAdd(&cnt[key[ebuck[i]] & 255], 1);
    __syncthreads();
    {
        const int orig = cnt[tid];
        int x = orig;
        #pragma unroll
        for (int d = 1; d < 64; d <<= 1) {
            const int y = __shfl_up(x, d);
            if (lane >= d) x += y;
        }
        if (lane == 63) wsum[wv] = x;
        __syncthreads();
        if (tid == 0) {
            int a = 0;
            #pragma unroll
            for (int i = 0; i < 4; ++i) { const int t = wsum[i]; wsum[i] = a; a += t; }
        }
        __syncthreads();
        excl[tid] = x - orig + wsum[wv];
    }
    __syncthreads();
    const int node = k * 256 + tid;
    if (node < N) base[node] = segb + excl[tid];
    if (k == NB - 1 && tid == 0) base[N] = E;
    cnt[tid] = excl[tid];
    __syncthreads();
    for (int i = segb + tid; i < sege; i += 256) {
        const int e = ebuck[i];
        const int r = atomicAdd(&cnt[key[e] & 255], 1);
        eid[segb + r] = e;
    }
}

// ---------------------------------------------------------------------------
// k_score: wave per TARGET, 16-lane groups, single edge per group per iter
// (round-10 structure: 28 VGPR, high occupancy). UB is bf16.
// ---------------------------------------------------------------------------
__global__ __launch_bounds__(256) void k_score(
    const int* __restrict__ eid_t, const int* __restrict__ base_t,
    const int* __restrict__ esrc,
    const float* __restrict__ Wt, const unsigned short* __restrict__ UB,
    const unsigned short* __restrict__ HB,
    float* __restrict__ score, float* __restrict__ pairv,
    float* __restrict__ sumt_inv, int N)
{
    const int lane = threadIdx.x & 63, wv = threadIdx.x >> 6;
    const int t = blockIdx.x * 4 + wv;
    if (t >= N) return;
    const int b0 = base_t[t], deg = base_t[t + 1] - b0;
    if (deg == 0) { if (lane == 0) sumt_inv[t] = 0.f; return; }
    const int sub = lane & 15, grp = lane >> 4;
    const size_t to = (size_t)t * HID;

    float wt[8], u[8], htg[8];
    {
        const f4 w0 = *(const f4*)&Wt[to + sub * 8];
        const f4 w1 = *(const f4*)&Wt[to + sub * 8 + 4];
        wt[0] = w0[0]; wt[1] = w0[1]; wt[2] = w0[2]; wt[3] = w0[3];
        wt[4] = w1[0]; wt[5] = w1[1]; wt[6] = w1[2]; wt[7] = w1[3];
        unpack8(*(const uint4*)&UB[to + sub * 8], u);
        unpack8(*(const uint4*)&HB[to + sub * 8], htg);
    }

    for (int j0 = 0; j0 < deg; j0 += 4) {
        const int jj = j0 + grp;
        const bool val = jj < deg;
        int eid = 0, src = 0;
        if (val) { eid = eid_t[b0 + jj]; src = esrc[eid]; }
        const size_t so = (size_t)src * HID;
        float hs[8];
        unpack8(*(const uint4*)&HB[so + sub * 8], hs);
        float ps = 0.f, pp = 0.f;
        #pragma unroll
        for (int d = 0; d < 8; ++d) {
            ps = fmaf(wt[d], hs[d], ps);
            pp = fmaf(u[d], hs[d], pp);
        }
        if (sub == 0) {
            #pragma unroll
            for (int d = 0; d < NSTR; ++d) ps = fmaf(htg[d], hs[d], ps);
        }
        #pragma unroll
        for (int mk = 1; mk < 16; mk <<= 1) {
            ps += __shfl_xor(ps, mk);
            pp += __shfl_xor(pp, mk);
        }
        if (sub == 0 && val) {
            score[b0 + jj] = ps;
            pairv[eid] = pp;
        }
    }

    float m = -1e30f;
    for (int i = lane; i < deg; i += 64) m = fmaxf(m, score[b0 + i]);
    #pragma unroll
    for (int mk = 1; mk < 64; mk <<= 1) m = fmaxf(m, __shfl_xor(m, mk));
    float psum = 0.f;
    for (int i = lane; i < deg; i += 64) {
        const float e = expf(score[b0 + i] - m);
        score[b0 + i] = e;
        psum += e;
    }
    #pragma unroll
    for (int mk = 1; mk < 64; mk <<= 1) psum += __shfl_xor(psum, mk);
    if (lane == 0) sumt_inv[t] = 1.f / psum;
}

// ---------------------------------------------------------------------------
// k_beta2: wave per SOURCE node, streaming; fuses rho.
// ---------------------------------------------------------------------------
__global__ __launch_bounds__(256) void k_beta2(
    const int* __restrict__ base_s, const int* __restrict__ eid_s,
    const int* __restrict__ etgt,
    const float* __restrict__ pairv, const float* __restrict__ psi,
    float* __restrict__ rho1m, int N)
{
    const int lane = threadIdx.x & 63, wv = threadIdx.x >> 6;
    const int s = blockIdx.x * 4 + wv;
    if (s >= N) return;
    const int b0 = base_s[s], deg = base_s[s + 1] - b0;

    float m = -1e30f;
    for (int i = lane; i < deg; i += 64) m = fmaxf(m, pairv[eid_s[b0 + i]]);
    #pragma unroll
    for (int mk = 1; mk < 64; mk <<= 1) m = fmaxf(m, __shfl_xor(m, mk));

    float se = 0.f, sn = 0.f;
    for (int i = lane; i < deg; i += 64) {
        const int e = eid_s[b0 + i];
        const float ex = expf(pairv[e] - m);
        se += ex;
        sn += ex * expf(-psi[etgt[e]]);
    }
    #pragma unroll
    for (int mk = 1; mk < 64; mk <<= 1) {
        se += __shfl_xor(se, mk);
        sn += __shfl_xor(sn, mk);
    }
    if (lane == 0) {
        const float st = (deg > 0 && se > 0.f) ? sn / se : 0.f;
        const float d  = -logf(st + 1e-8f);
        rho1m[s] = 1.f - 1.f / (1.f + expf(-(GAMMA * (d - DELTA))));
    }
}

// ---------------------------------------------------------------------------
// k_matt: wave per TARGET, 8 edges in flight; gathers HB (warm from k_score).
// agg[t] = sum_e c_e * H_bf[src];  sig[t] = sum_e c_e.
// ---------------------------------------------------------------------------
__global__ __launch_bounds__(256) void k_matt(
    const int* __restrict__ eid_t, const int* __restrict__ base_t,
    const int* __restrict__ esrc,
    const float* __restrict__ score, const float* __restrict__ sumt_inv,
    const float* __restrict__ rho1m,
    const unsigned short* __restrict__ HB,
    float* __restrict__ agg, float* __restrict__ sig, int N)
{
    const int lane = threadIdx.x & 63, wv = threadIdx.x >> 6;
    const int t = blockIdx.x * 4 + wv;
    if (t >= N) return;
    const int b0 = base_t[t], deg = base_t[t + 1] - b0;
    const int sub = lane & 15, grp = lane >> 4;
    const size_t to = (size_t)t * HID;

    float acc[8];
    #pragma unroll
    for (int d = 0; d < 8; ++d) acc[d] = 0.f;
    float csum = 0.f;
    const float inv = (deg > 0) ? sumt_inv[t] : 0.f;

    for (int j0 = 0; j0 < deg; j0 += 8) {
        const int jA = j0 + grp, jB = j0 + 4 + grp;
        const bool vA = jA < deg, vB = jB < deg;
        float cA = 0.f, cB = 0.f;
        size_t soA = 0, soB = 0;
        if (vA) {
            const int e = eid_t[b0 + jA];
            const int s = esrc[e];
            cA = score[b0 + jA] * inv * rho1m[s];
            soA = (size_t)s * HID;
        }
        if (vB) {
            const int e = eid_t[b0 + jB];
            const int s = esrc[e];
            cB = score[b0 + jB] * inv * rho1m[s];
            soB = (size_t)s * HID;
        }
        const uint4 rA = *(const uint4*)&HB[soA + sub * 8];
        const uint4 rB = *(const uint4*)&HB[soB + sub * 8];
        float hA[8], hB[8];
        unpack8(rA, hA); unpack8(rB, hB);
        #pragma unroll
        for (int d = 0; d < 8; ++d) {
            acc[d] = fmaf(cA, hA[d], acc[d]);
            acc[d] = fmaf(cB, hB[d], acc[d]);
        }
        if (sub == 0) csum += cA + cB;
    }
    #pragma unroll
    for (int d = 0; d < 8; ++d) {
        acc[d] += __shfl_xor(acc[d], 16);
        acc[d] += __shfl_xor(acc[d], 32);
    }
    csum += __shfl_xor(csum, 16);
    csum += __shfl_xor(csum, 32);
    if (grp == 0) {
        f4 o0, o1;
        #pragma unroll
        for (int d = 0; d < 4; ++d) { o0[d] = acc[d]; o1[d] = acc[d + 4]; }
        *(f4*)&agg[to + sub * 8]     = o0;
        *(f4*)&agg[to + sub * 8 + 4] = o1;
        if (sub == 0) sig[t] = csum;
    }
}

extern "C" void kernel_launch(void* const* d_in, const int* in_sizes, int n_in,
                              void* d_out, int out_size, void* d_ws, size_t ws_size,
                              hipStream_t stream)
{
    const int*   eidx   = (const int*)  d_in[0];
    const float* H      = (const float*)d_in[1];
    const float* W_att  = (const float*)d_in[2];
    const float* phi_w  = (const float*)d_in[3];
    const float* phi_b  = (const float*)d_in[4];
    const float* W_p    = (const float*)d_in[5];
    const float* W_pp   = (const float*)d_in[6];
    const float* fdef_w = (const float*)d_in[7];
    const float* fdef_b = (const float*)d_in[8];
    const float* Wself  = (const float*)d_in[9];
    const float* bself  = (const float*)d_in[10];
    const float* WA     = (const float*)d_in[11];
    const float* bA     = (const float*)d_in[12];
    const float* Wstr   = (const float*)d_in[13];
    const float* bstr   = (const float*)d_in[14];
    const float* lng    = (const float*)d_in[15];
    const float* lnb    = (const float*)d_in[16];
    float* out = (float*)d_out;

    const int E = in_sizes[0] / 2;
    const int N = in_sizes[1] / HID;
    const int* esrc = eidx;
    const int* etgt = eidx + E;

    const int NB = (N + 255) >> 8;
    const int NC = (E + CSR_CHUNK - 1) / CSR_CHUNK;
    const int L  = NB * NC;

    // ---- workspace layout (~72 MB) ----
    char* w = (char*)d_ws;
    const size_t NHb  = (size_t)N * HID * sizeof(unsigned short);
    const size_t NH   = (size_t)N * HID * sizeof(float);
    const size_t Epad = (((size_t)E * sizeof(float)) + 255) & ~255ull;
    const size_t Npad = (((size_t)(N + 1) * sizeof(float)) + 255) & ~255ull;
    const size_t Lpad = (((size_t)(L + 1) * sizeof(int)) + 255) & ~255ull;

    float*          Wt    = (float*)w;          w += NH;   // agg aliases after k_score
    unsigned short* UB    = (unsigned short*)w; w += NHb;
    unsigned short* HB    = (unsigned short*)w; w += NHb;
    float* score   = (float*)w; w += Epad;  // CSR-tgt order
    float* pairv   = (float*)w; w += Epad;  // edge-id order
    int*   eid_t   = (int*)  w; w += Epad;
    int*   eid_s   = (int*)  w; w += Epad;
    int*   ebuck_t = (int*)  w; w += Epad;
    int*   ebuck_s = (int*)  w; w += Epad;
    int*   cnt_t = (int*)w; w += Lpad;
    int*   off_t = (int*)w; w += Lpad;
    int*   cnt_s = (int*)w; w += Lpad;
    int*   off_s = (int*)w; w += Lpad;
    int*   base_t   = (int*)  w; w += Npad;   // N+1
    int*   base_s   = (int*)  w; w += Npad;   // N+1
    float* sumt_inv = (float*)w; w += Npad;
    float* psi      = (float*)w; w += Npad;
    float* rho1m    = (float*)w; w += Npad;
    float* sig      = (float*)w; w += Npad;
    float* pbA      = (float*)w; w += 512;   // 128 floats
    unsigned short* WT = (unsigned short*)w;  // 4 slots x 2 planes x 128x128
    w += 4 * 2 * HID * HID * sizeof(unsigned short);
    float* agg = Wt;   // alias: Wt dead after k_score

    const int nblk128 = (N + 127) / 128;
    const int nblkN4  = (N + 3) / 4;
    const size_t lds_mfma = 4 * 128 * KPAD * sizeof(unsigned short);  // 72 KB
    const size_t MSZ = (size_t)2 * HID * HID;

    // slots: 0 = W_att(nat), 1 = Wself(T), 2 = M2, 3 = G
    PrepArgs pa;
    pa.W[0] = W_att; pa.tr[0] = 0;
    pa.W[1] = Wself; pa.tr[1] = 1;
    k_prep<<<dim3(8, 2), 256, 0, stream>>>(pa, WT);
    k_m2<<<8, 256, 0, stream>>>(W_p, W_pp, WT + 2 * MSZ);
    k_g<<<8, 256, 0, stream>>>(phi_w, WA, phi_b, WT + 3 * MSZ, pbA);

    k_castpsi<<<(N + 15) / 16, 256, 0, stream>>>(H, fdef_w, fdef_b, HB, psi, N);

    GemmArgsT g2;
    g2.Whi[0] = WT;           g2.Wlo[0] = WT + HID * HID;             // W_att
    g2.Whi[1] = WT + 2 * MSZ; g2.Wlo[1] = WT + 2 * MSZ + HID * HID;   // M2
    g2.O[0] = Wt;  g2.of32[0] = 1;
    g2.O[1] = UB;  g2.of32[1] = 0;
    k_gemm<<<dim3(nblk128, 2), 256, lds_mfma, stream>>>(H, g2, N);

    // ---- CSR build (no global atomics) ----
    k_csr_count<<<dim3(NC, 2), 256, 0, stream>>>(etgt, esrc, cnt_t, cnt_s, NB, NC, E);
    k_csr_scan<<<2, 1024, 0, stream>>>(cnt_t, off_t, cnt_s, off_s, L);
    k_csr_bucket<<<dim3(NC, 2), 256, 0, stream>>>(etgt, esrc, off_t, off_s,
                                                  ebuck_t, ebuck_s, NB, NC, E);
    k_csr_final<<<dim3(NB, 2), 256, 0, stream>>>(etgt, esrc, off_t, off_s,
                                                 ebuck_t, ebuck_s, base_t, base_s,
                                                 eid_t, eid_s, NB, NC, N, E);

    k_score<<<nblkN4, 256, 0, stream>>>(eid_t, base_t, esrc, Wt, UB, HB,
                                        score, pairv, sumt_inv, N);
    k_beta2<<<nblkN4, 256, 0, stream>>>(base_s, eid_s, etgt, pairv, psi, rho1m, N);

    k_matt<<<nblkN4, 256, 0, stream>>>(eid_t, base_t, esrc, score, sumt_inv,
                                       rho1m, HB, agg, sig, N);

    k_final<<<nblk128, 256, lds_mfma, stream>>>(agg, H, sig, pbA,
                                                WT + 3 * MSZ, WT + 3 * MSZ + HID * HID,
                                                WT + 1 * MSZ, WT + 1 * MSZ + HID * HID,
                                                Wstr, bself, bA, bstr, lng, lnb, out, N);
}

// Round 14
// 318.821 us; speedup vs baseline: 1.4885x; 1.0917x over previous
//
#include <hip/hip_runtime.h>
#include <math.h>

#define HID 128
#define NSTR 6              // STRUCT-1
#define GAMMA 1.0f
#define DELTA 0.5f
#define LN_EPS 1e-5f
#define KPAD 72             // bf16 elems per LDS row (64 + 8 pad)
#define CSR_CHUNK 8192      // edges per block in CSR build

typedef __attribute__((ext_vector_type(4))) float f4;
typedef __attribute__((ext_vector_type(8))) short bf16x8;
typedef __attribute__((ext_vector_type(4))) float f32x4;

// f32 -> bf16 (round-to-nearest-even) and helpers
__device__ __forceinline__ unsigned short f2bf(float f) {
    unsigned u = __float_as_uint(f);
    unsigned r = u + 0x7FFFu + ((u >> 16) & 1u);
    return (unsigned short)(r >> 16);
}
__device__ __forceinline__ float bf2f(unsigned short h) {
    return __uint_as_float((unsigned)h << 16);
}
__device__ __forceinline__ void split2(float v, unsigned short& h, unsigned short& l) {
    h = f2bf(v);
    l = f2bf(v - bf2f(h));
}
__device__ __forceinline__ void bf2f2(unsigned u, float& lo, float& hi) {
    lo = __uint_as_float(u << 16);
    hi = __uint_as_float(u & 0xFFFF0000u);
}
__device__ __forceinline__ void unpack8(const uint4 u, float* f) {
    bf2f2(u.x, f[0], f[1]); bf2f2(u.y, f[2], f[3]);
    bf2f2(u.z, f[4], f[5]); bf2f2(u.w, f[6], f[7]);
}

// ---------------------------------------------------------------------------
// k_prep_all: all weight-table prep in ONE launch, grid (8, 4).
// mode 0: slot0 = W_att natural (tbl[c][k] = W[c][k], for H @ W_att^T)
// mode 1: slot1 = Wself transposed (tbl[c][k] = W[k][c], for H @ Wself)
// mode 2: slot2 = M2 = W_p @ W_pp^T (tbl[c][k] = sum_j Wp[c][j]*Wpp[k][j])
// mode 3: slot3 = G  (tbl[c][k] = sum_j phiw[k][j]*WA[j][c]) + pbA[c]
// ---------------------------------------------------------------------------
__global__ __launch_bounds__(256) void k_prep_all(
    const float* __restrict__ W_att, const float* __restrict__ Wself,
    const float* __restrict__ Wp,    const float* __restrict__ Wpp,
    const float* __restrict__ phiw,  const float* __restrict__ WA,
    const float* __restrict__ phib,
    unsigned short* __restrict__ WT, float* __restrict__ pbA)
{
    __shared__ float Bs[128][129];
    __shared__ float As[16][129];
    const int mode = blockIdx.y, c0 = blockIdx.x * 16;
    const int tid = threadIdx.x;
    const size_t MSZ = (size_t)2 * HID * HID;
    unsigned short* hi = WT + (size_t)mode * MSZ;
    unsigned short* lo = hi + HID * HID;

    if (mode == 0) {
        for (int idx = tid; idx < 2048; idx += 256) {
            const int c = idx >> 7, k = idx & 127;
            unsigned short h, l;
            split2(W_att[(size_t)(c0 + c) * HID + k], h, l);
            hi[(size_t)(c0 + c) * HID + k] = h;
            lo[(size_t)(c0 + c) * HID + k] = l;
        }
    } else if (mode == 1) {
        // transpose via LDS (reuse As rows as a 128x17-ish scratch: use Bs)
        for (int idx = tid; idx < 2048; idx += 256) {
            const int k = idx >> 4, c = idx & 15;
            Bs[k][c] = Wself[k * HID + c0 + c];
        }
        __syncthreads();
        for (int idx = tid; idx < 2048; idx += 256) {
            const int c = idx >> 7, k = idx & 127;
            unsigned short h, l;
            split2(Bs[k][c], h, l);
            hi[(size_t)(c0 + c) * HID + k] = h;
            lo[(size_t)(c0 + c) * HID + k] = l;
        }
    } else if (mode == 2) {
        for (int idx = tid; idx < 128 * 128; idx += 256)
            Bs[idx >> 7][idx & 127] = Wpp[idx];
        for (int idx = tid; idx < 16 * 128; idx += 256)
            As[idx >> 7][idx & 127] = Wp[(size_t)(c0 + (idx >> 7)) * HID + (idx & 127)];
        __syncthreads();
        for (int it = 0; it < 8; ++it) {
            const int idx = tid + 256 * it;
            const int c = idx >> 7, k = idx & 127;
            float a = 0.f;
            #pragma unroll 4
            for (int j = 0; j < 128; ++j)
                a = fmaf(As[c][j], Bs[k][j], a);
            unsigned short h, l;
            split2(a, h, l);
            hi[(size_t)(c0 + c) * HID + k] = h;
            lo[(size_t)(c0 + c) * HID + k] = l;
        }
    } else {
        for (int idx = tid; idx < 128 * 128; idx += 256)
            Bs[idx >> 7][idx & 127] = phiw[idx];
        for (int idx = tid; idx < 16 * 128; idx += 256) {
            const int c = idx >> 7, j = idx & 127;
            As[c][j] = WA[(size_t)j * HID + c0 + c];
        }
        __syncthreads();
        for (int it = 0; it < 8; ++it) {
            const int idx = tid + 256 * it;
            const int c = idx >> 7, k = idx & 127;
            float a = 0.f;
            #pragma unroll 4
            for (int j = 0; j < 128; ++j)
                a = fmaf(As[c][j], Bs[k][j], a);
            unsigned short h, l;
            split2(a, h, l);
            hi[(size_t)(c0 + c) * HID + k] = h;
            lo[(size_t)(c0 + c) * HID + k] = l;
        }
        if (tid < 16) {
            float a = 0.f;
            #pragma unroll 4
            for (int j = 0; j < 128; ++j)
                a = fmaf(phib[j], As[tid][j], a);
            pbA[c0 + tid] = a;
        }
    }
}

// ---------------------------------------------------------------------------
// k_castpsi: HB = bf16(H) AND psi = H.f_def_w + f_def_b in one H pass.
// ---------------------------------------------------------------------------
__global__ __launch_bounds__(256) void k_castpsi(
    const float* __restrict__ H, const float* __restrict__ fw,
    const float* __restrict__ fb,
    unsigned short* __restrict__ HB, float* __restrict__ psi, int N)
{
    const int tid = threadIdx.x;
    const int row = blockIdx.x * 16 + (tid >> 4), sub = tid & 15;
    if (row >= N) return;
    const size_t o = (size_t)row * HID + sub * 8;
    const f4 v0 = *(const f4*)&H[o];
    const f4 v1 = *(const f4*)&H[o + 4];
    ushort4 a, b;
    a.x = f2bf(v0[0]); a.y = f2bf(v0[1]); a.z = f2bf(v0[2]); a.w = f2bf(v0[3]);
    b.x = f2bf(v1[0]); b.y = f2bf(v1[1]); b.z = f2bf(v1[2]); b.w = f2bf(v1[3]);
    *(ushort4*)&HB[o] = a;
    *(ushort4*)&HB[o + 4] = b;
    const f4 w0 = *(const f4*)&fw[sub * 8];
    const f4 w1 = *(const f4*)&fw[sub * 8 + 4];
    float s = v0[0]*w0[0] + v0[1]*w0[1] + v0[2]*w0[2] + v0[3]*w0[3]
            + v1[0]*w1[0] + v1[1]*w1[1] + v1[2]*w1[2] + v1[3]*w1[3];
    #pragma unroll
    for (int mk = 1; mk < 16; mk <<= 1) s += __shfl_xor(s, mk);
    if (sub == 0) psi[row] = s + fb[0];
}

struct GemmArgsT {
    const unsigned short* Whi[2];
    const unsigned short* Wlo[2];
    void*                 O[2];
    int                   of32[2];
};

// ---------------------------------------------------------------------------
// MFMA GEMM: O[ph] = A @ B[ph], split-precision (hi/lo bf16, 3 MFMA).
// Output f32 or bf16 per of32 flag.
// ---------------------------------------------------------------------------
__global__ __launch_bounds__(256, 2) void k_gemm(const float* __restrict__ A,
                                                 GemmArgsT g, int N)
{
    extern __shared__ unsigned short lds[];
    unsigned short* Ahi = lds;
    unsigned short* Alo = lds + 128 * KPAD;
    unsigned short* Bhi = lds + 2 * 128 * KPAD;
    unsigned short* Blo = lds + 3 * 128 * KPAD;
    const int tid  = threadIdx.x;
    const int row0 = blockIdx.x * 128;
    const int nrows = min(128, N - row0);
    const int ph   = blockIdx.y;
    const int w    = tid >> 6, lane = tid & 63;
    const int lrow = lane & 15, kgrp = lane >> 4;

    f32x4 acc[2][8];
    #pragma unroll
    for (int tc = 0; tc < 8; ++tc) {
        acc[0][tc] = f32x4{0.f, 0.f, 0.f, 0.f};
        acc[1][tc] = f32x4{0.f, 0.f, 0.f, 0.f};
    }

    const unsigned short* __restrict__ Wh = g.Whi[ph];
    const unsigned short* __restrict__ Wl = g.Wlo[ph];

    for (int ch = 0; ch < 2; ++ch) {
        __syncthreads();
        #pragma unroll
        for (int it = 0; it < 8; ++it) {
            const int idx = tid + 256 * it;
            const int r = idx >> 4, kq = (idx & 15) * 4;
            f4 v = {0.f, 0.f, 0.f, 0.f};
            if (r < nrows) v = *(const f4*)&A[(size_t)(row0 + r) * HID + ch * 64 + kq];
            ushort4 h, l;
            split2(v[0], h.x, l.x); split2(v[1], h.y, l.y);
            split2(v[2], h.z, l.z); split2(v[3], h.w, l.w);
            *(ushort4*)&Ahi[r * KPAD + kq] = h;
            *(ushort4*)&Alo[r * KPAD + kq] = l;
        }
        #pragma unroll
        for (int it = 0; it < 4; ++it) {
            const int idx = tid + 256 * it;
            const int c = idx >> 3, k8 = (idx & 7) * 8;
            *(uint4*)&Bhi[c * KPAD + k8] = *(const uint4*)&Wh[(size_t)c * HID + ch * 64 + k8];
            *(uint4*)&Blo[c * KPAD + k8] = *(const uint4*)&Wl[(size_t)c * HID + ch * 64 + k8];
        }
        __syncthreads();

        #pragma unroll
        for (int ks = 0; ks < 2; ++ks) {
            const int ko = ks * 32 + kgrp * 8;
            bf16x8 ah[2], al[2], bh[8], bl[8];
            #pragma unroll
            for (int tr = 0; tr < 2; ++tr) {
                const int rr = w * 32 + tr * 16 + lrow;
                ah[tr] = *(const bf16x8*)&Ahi[rr * KPAD + ko];
                al[tr] = *(const bf16x8*)&Alo[rr * KPAD + ko];
            }
            #pragma unroll
            for (int tc = 0; tc < 8; ++tc) {
                const int cc = tc * 16 + lrow;
                bh[tc] = *(const bf16x8*)&Bhi[cc * KPAD + ko];
                bl[tc] = *(const bf16x8*)&Blo[cc * KPAD + ko];
            }
            #pragma unroll
            for (int tr = 0; tr < 2; ++tr)
                #pragma unroll
                for (int tc = 0; tc < 8; ++tc) {
                    acc[tr][tc] = __builtin_amdgcn_mfma_f32_16x16x32_bf16(ah[tr], bh[tc], acc[tr][tc], 0, 0, 0);
                    acc[tr][tc] = __builtin_amdgcn_mfma_f32_16x16x32_bf16(al[tr], bh[tc], acc[tr][tc], 0, 0, 0);
                    acc[tr][tc] = __builtin_amdgcn_mfma_f32_16x16x32_bf16(ah[tr], bl[tc], acc[tr][tc], 0, 0, 0);
                }
        }
    }

    #pragma unroll
    for (int tr = 0; tr < 2; ++tr)
        #pragma unroll
        for (int j = 0; j < 4; ++j) {
            const int r = w * 32 + tr * 16 + kgrp * 4 + j;
            if (r < nrows) {
                if (g.of32[ph]) {
                    float* O = (float*)g.O[ph];
                    #pragma unroll
                    for (int tc = 0; tc < 8; ++tc)
                        O[(size_t)(row0 + r) * HID + tc * 16 + lrow] = acc[tr][tc][j];
                } else {
                    unsigned short* O = (unsigned short*)g.O[ph];
                    #pragma unroll
                    for (int tc = 0; tc < 8; ++tc)
                        O[(size_t)(row0 + r) * HID + tc * 16 + lrow] = f2bf(acc[tr][tc][j]);
                }
            }
        }
}

// ---------------------------------------------------------------------------
// k_final: out = LN(relu(agg@G + sig*pbA + H@Wself + s@Wstr + biases) + H)
// ---------------------------------------------------------------------------
__global__ __launch_bounds__(256, 2) void k_final(
    const float* __restrict__ Agg, const float* __restrict__ H,
    const float* __restrict__ sig, const float* __restrict__ pbA,
    const unsigned short* __restrict__ Ghi, const unsigned short* __restrict__ Glo,
    const unsigned short* __restrict__ WShi, const unsigned short* __restrict__ WSlo,
    const float* __restrict__ Wstr,
    const float* __restrict__ bself, const float* __restrict__ bA,
    const float* __restrict__ bstr,
    const float* __restrict__ lng, const float* __restrict__ lnb,
    float* __restrict__ out, int N)
{
    extern __shared__ unsigned short lds[];
    unsigned short* Ahi = lds;
    unsigned short* Alo = lds + 128 * KPAD;
    unsigned short* Bhi = lds + 2 * 128 * KPAD;
    unsigned short* Blo = lds + 3 * 128 * KPAD;
    const int tid  = threadIdx.x;
    const int row0 = blockIdx.x * 128;
    const int nrows = min(128, N - row0);
    const int w    = tid >> 6, lane = tid & 63;
    const int lrow = lane & 15, kgrp = lane >> 4;

    f32x4 acc[2][8];
    float gl[8], bl_[8], pb[8];
    #pragma unroll
    for (int tc = 0; tc < 8; ++tc) {
        const int c = tc * 16 + lrow;
        const float bv = bself[c] + bA[c] + bstr[c];
        acc[0][tc] = f32x4{bv, bv, bv, bv};
        acc[1][tc] = f32x4{bv, bv, bv, bv};
        gl[tc] = lng[c]; bl_[tc] = lnb[c]; pb[tc] = pbA[c];
    }

    for (int ph = 0; ph < 2; ++ph) {
        const float* __restrict__ Am = ph ? H : Agg;
        const unsigned short* __restrict__ Wh = ph ? WShi : Ghi;
        const unsigned short* __restrict__ Wl = ph ? WSlo : Glo;
        for (int ch = 0; ch < 2; ++ch) {
            __syncthreads();
            #pragma unroll
            for (int it = 0; it < 8; ++it) {
                const int idx = tid + 256 * it;
                const int r = idx >> 4, kq = (idx & 15) * 4;
                f4 v = {0.f, 0.f, 0.f, 0.f};
                if (r < nrows) v = *(const f4*)&Am[(size_t)(row0 + r) * HID + ch * 64 + kq];
                ushort4 h, l;
                split2(v[0], h.x, l.x); split2(v[1], h.y, l.y);
                split2(v[2], h.z, l.z); split2(v[3], h.w, l.w);
                *(ushort4*)&Ahi[r * KPAD + kq] = h;
                *(ushort4*)&Alo[r * KPAD + kq] = l;
            }
            #pragma unroll
            for (int it = 0; it < 4; ++it) {
                const int idx = tid + 256 * it;
                const int c = idx >> 3, k8 = (idx & 7) * 8;
                *(uint4*)&Bhi[c * KPAD + k8] = *(const uint4*)&Wh[(size_t)c * HID + ch * 64 + k8];
                *(uint4*)&Blo[c * KPAD + k8] = *(const uint4*)&Wl[(size_t)c * HID + ch * 64 + k8];
            }
            __syncthreads();

            #pragma unroll
            for (int ks = 0; ks < 2; ++ks) {
                const int ko = ks * 32 + kgrp * 8;
                bf16x8 ah[2], al[2], bh[8], bl[8];
                #pragma unroll
                for (int tr = 0; tr < 2; ++tr) {
                    const int rr = w * 32 + tr * 16 + lrow;
                    ah[tr] = *(const bf16x8*)&Ahi[rr * KPAD + ko];
                    al[tr] = *(const bf16x8*)&Alo[rr * KPAD + ko];
                }
                #pragma unroll
                for (int tc = 0; tc < 8; ++tc) {
                    const int cc = tc * 16 + lrow;
                    bh[tc] = *(const bf16x8*)&Bhi[cc * KPAD + ko];
                    bl[tc] = *(const bf16x8*)&Blo[cc * KPAD + ko];
                }
                #pragma unroll
                for (int tr = 0; tr < 2; ++tr)
                    #pragma unroll
                    for (int tc = 0; tc < 8; ++tc) {
                        acc[tr][tc] = __builtin_amdgcn_mfma_f32_16x16x32_bf16(ah[tr], bh[tc], acc[tr][tc], 0, 0, 0);
                        acc[tr][tc] = __builtin_amdgcn_mfma_f32_16x16x32_bf16(al[tr], bh[tc], acc[tr][tc], 0, 0, 0);
                        acc[tr][tc] = __builtin_amdgcn_mfma_f32_16x16x32_bf16(ah[tr], bl[tc], acc[tr][tc], 0, 0, 0);
                    }
            }

            if (ph == 1 && ch == 0) {
                #pragma unroll
                for (int tr = 0; tr < 2; ++tr)
                    #pragma unroll
                    for (int j = 0; j < 4; ++j) {
                        const int rr = w * 32 + tr * 16 + kgrp * 4 + j;
                        float s[NSTR];
                        #pragma unroll
                        for (int k = 0; k < NSTR; ++k)
                            s[k] = bf2f(Ahi[rr * KPAD + k]) + bf2f(Alo[rr * KPAD + k]);
                        #pragma unroll
                        for (int tc = 0; tc < 8; ++tc) {
                            float a = 0.f;
                            #pragma unroll
                            for (int k = 0; k < NSTR; ++k)
                                a = fmaf(s[k], Wstr[k * HID + tc * 16 + lrow], a);
                            acc[tr][tc][j] += a;
                        }
                    }
            }
        }
    }

    #pragma unroll
    for (int tr = 0; tr < 2; ++tr)
        #pragma unroll
        for (int j = 0; j < 4; ++j) {
            const int r = w * 32 + tr * 16 + kgrp * 4 + j;
            const bool valid = r < nrows;
            const size_t rb = (size_t)(row0 + r) * HID;
            const float sg = valid ? sig[row0 + r] : 0.f;
            float v[8], s1 = 0.f, s2 = 0.f;
            #pragma unroll
            for (int tc = 0; tc < 8; ++tc) {
                float x = fmaxf(acc[tr][tc][j] + sg * pb[tc], 0.f);
                if (valid) x += H[rb + tc * 16 + lrow];
                v[tc] = x;
                s1 += x; s2 += x * x;
            }
            #pragma unroll
            for (int mk = 1; mk < 16; mk <<= 1) {
                s1 += __shfl_xor(s1, mk);
                s2 += __shfl_xor(s2, mk);
            }
            const float mean = s1 * (1.f / HID);
            const float var  = s2 * (1.f / HID) - mean * mean;
            const float rs   = rsqrtf(var + LN_EPS);
            if (valid) {
                #pragma unroll
                for (int tc = 0; tc < 8; ++tc)
                    out[rb + tc * 16 + lrow] = (v[tc] - mean) * rs * gl[tc] + bl_[tc];
            }
        }
}

// ---------------------------------------------------------------------------
// CSR build via two-level LDS counting sort — ZERO global atomics.
// ---------------------------------------------------------------------------
__global__ __launch_bounds__(256) void k_csr_count(
    const int* __restrict__ etgt, const int* __restrict__ esrc,
    int* __restrict__ cnt_t, int* __restrict__ cnt_s,
    int NB, int NC, int E)
{
    __shared__ int cnt[256];
    const int which = blockIdx.y;
    const int* __restrict__ key = which ? esrc : etgt;
    int* __restrict__ outc = which ? cnt_s : cnt_t;
    const int tid = threadIdx.x;
    for (int i = tid; i < NB; i += 256) cnt[i] = 0;
    __syncthreads();
    const int e0 = blockIdx.x * CSR_CHUNK;
    const int e1 = min(e0 + CSR_CHUNK, E);
    for (int e = e0 + tid; e < e1; e += 256)
        atomicAdd(&cnt[key[e] >> 8], 1);
    __syncthreads();
    for (int k = tid; k < NB; k += 256)
        outc[(size_t)k * NC + blockIdx.x] = cnt[k];
}

__global__ __launch_bounds__(1024) void k_csr_scan(
    const int* __restrict__ cnt_t, int* __restrict__ off_t,
    const int* __restrict__ cnt_s, int* __restrict__ off_s, int L)
{
    const int* __restrict__ cnt = blockIdx.x ? cnt_s : cnt_t;
    int* __restrict__ off = blockIdx.x ? off_s : off_t;
    __shared__ int warp_sums[16];
    __shared__ int carry_s;
    const int tid = threadIdx.x, lane = tid & 63, wid = tid >> 6;
    if (tid == 0) carry_s = 0;
    __syncthreads();
    for (int i0 = 0; i0 < L; i0 += 1024) {
        const int i = i0 + tid;
        const int v = (i < L) ? cnt[i] : 0;
        int x = v;
        #pragma unroll
        for (int d = 1; d < 64; d <<= 1) {
            const int y = __shfl_up(x, d);
            if (lane >= d) x += y;
        }
        if (lane == 63) warp_sums[wid] = x;
        __syncthreads();
        if (wid == 0) {
            int ws = (lane < 16) ? warp_sums[lane] : 0;
            #pragma unroll
            for (int d = 1; d < 16; d <<= 1) {
                const int y = __shfl_up(ws, d);
                if (lane >= d) ws += y;
            }
            if (lane < 16) warp_sums[lane] = ws;
        }
        __syncthreads();
        const int carry = carry_s;
        if (i < L) off[i] = carry + (wid ? warp_sums[wid - 1] : 0) + x - v;
        __syncthreads();
        if (tid == 1023) carry_s = carry + warp_sums[15];
        __syncthreads();
    }
    if (tid == 0) off[L] = carry_s;
}

__global__ __launch_bounds__(256) void k_csr_bucket(
    const int* __restrict__ etgt, const int* __restrict__ esrc,
    const int* __restrict__ off_t, const int* __restrict__ off_s,
    int* __restrict__ ebuck_t, int* __restrict__ ebuck_s,
    int NB, int NC, int E)
{
    __shared__ int cur[256];
    const int which = blockIdx.y;
    const int* __restrict__ key = which ? esrc : etgt;
    const int* __restrict__ off = which ? off_s : off_t;
    int* __restrict__ ebuck = which ? ebuck_s : ebuck_t;
    const int tid = threadIdx.x;
    for (int k = tid; k < NB; k += 256)
        cur[k] = off[(size_t)k * NC + blockIdx.x];
    __syncthreads();
    const int e0 = blockIdx.x * CSR_CHUNK;
    const int e1 = min(e0 + CSR_CHUNK, E);
    for (int e = e0 + tid; e < e1; e += 256) {
        const int p = atomicAdd(&cur[key[e] >> 8], 1);
        ebuck[p] = e;
    }
}

__global__ __launch_bounds__(256) void k_csr_final(
    const int* __restrict__ etgt, const int* __restrict__ esrc,
    const int* __restrict__ off_t, const int* __restrict__ off_s,
    const int* __restrict__ ebuck_t, const int* __restrict__ ebuck_s,
    int* __restrict__ base_t, int* __restrict__ base_s,
    int* __restrict__ eid_t, int* __restrict__ eid_s,
    int NB, int NC, int N, int E)
{
    __shared__ int cnt[256], excl[256], wsum[4];
    const int which = blockIdx.y;
    const int* __restrict__ key   = which ? esrc : etgt;
    const int* __restrict__ off   = which ? off_s : off_t;
    const int* __restrict__ ebuck = which ? ebuck_s : ebuck_t;
    int* __restrict__ base = which ? base_s : base_t;
    int* __restrict__ eid  = which ? eid_s : eid_t;
    const int tid = threadIdx.x, lane = tid & 63, wv = tid >> 6;
    const int k = blockIdx.x;
    const int segb = off[(size_t)k * NC];
    const int sege = (k + 1 < NB) ? off[(size_t)(k + 1) * NC] : E;
    cnt[tid] = 0;
    __syncthreads();
    for (int i = segb + tid; i < sege; i += 256)
        atomicAdd(&cnt[key[ebuck[i]] & 255], 1);
    __syncthreads();
    {
        const int orig = cnt[tid];
        int x = orig;
        #pragma unroll
        for (int d = 1; d < 64; d <<= 1) {
            const int y = __shfl_up(x, d);
            if (lane >= d) x += y;
        }
        if (lane == 63) wsum[wv] = x;
        __syncthreads();
        if (tid == 0) {
            int a = 0;
            #pragma unroll
            for (int i = 0; i < 4; ++i) { const int t = wsum[i]; wsum[i] = a; a += t; }
        }
        __syncthreads();
        excl[tid] = x - orig + wsum[wv];
    }
    __syncthreads();
    const int node = k * 256 + tid;
    if (node < N) base[node] = segb + excl[tid];
    if (k == NB - 1 && tid == 0) base[N] = E;
    cnt[tid] = excl[tid];
    __syncthreads();
    for (int i = segb + tid; i < sege; i += 256) {
        const int e = ebuck[i];
        const int r = atomicAdd(&cnt[key[e] & 255], 1);
        eid[segb + r] = e;
    }
}

// ---------------------------------------------------------------------------
// k_score: wave per TARGET, 16-lane groups, single edge per group per iter,
// with INDEX software pipelining (next (eid,src) prefetched during current
// gather+dot) — shortens the 3-deep dependent-load chain at +2 VGPRs.
// ---------------------------------------------------------------------------
__global__ __launch_bounds__(256) void k_score(
    const int* __restrict__ eid_t, const int* __restrict__ base_t,
    const int* __restrict__ esrc,
    const float* __restrict__ Wt, const unsigned short* __restrict__ UB,
    const unsigned short* __restrict__ HB,
    float* __restrict__ score, float* __restrict__ pairv,
    float* __restrict__ sumt_inv, int N)
{
    const int lane = threadIdx.x & 63, wv = threadIdx.x >> 6;
    const int t = blockIdx.x * 4 + wv;
    if (t >= N) return;
    const int b0 = base_t[t], deg = base_t[t + 1] - b0;
    if (deg == 0) { if (lane == 0) sumt_inv[t] = 0.f; return; }
    const int sub = lane & 15, grp = lane >> 4;
    const size_t to = (size_t)t * HID;

    float wt[8], u[8], htg[8];
    {
        const f4 w0 = *(const f4*)&Wt[to + sub * 8];
        const f4 w1 = *(const f4*)&Wt[to + sub * 8 + 4];
        wt[0] = w0[0]; wt[1] = w0[1]; wt[2] = w0[2]; wt[3] = w0[3];
        wt[4] = w1[0]; wt[5] = w1[1]; wt[6] = w1[2]; wt[7] = w1[3];
        unpack8(*(const uint4*)&UB[to + sub * 8], u);
        unpack8(*(const uint4*)&HB[to + sub * 8], htg);
    }

    // prologue: prefetch first edge's indices
    bool valN = grp < deg;
    int eidN = 0, srcN = 0;
    if (valN) { eidN = eid_t[b0 + grp]; srcN = esrc[eidN]; }

    for (int j0 = 0; j0 < deg; j0 += 4) {
        const bool val = valN;
        const int eid = eidN, src = srcN;
        // issue current gather ASAP
        const uint4 raw = *(const uint4*)&HB[(size_t)src * HID + sub * 8];
        // prefetch next iteration's indices (independent of raw)
        const int jn = j0 + 4 + grp;
        valN = jn < deg;
        eidN = 0; srcN = 0;
        if (valN) { eidN = eid_t[b0 + jn]; srcN = esrc[eidN]; }

        float hs[8];
        unpack8(raw, hs);
        float ps = 0.f, pp = 0.f;
        #pragma unroll
        for (int d = 0; d < 8; ++d) {
            ps = fmaf(wt[d], hs[d], ps);
            pp = fmaf(u[d], hs[d], pp);
        }
        if (sub == 0) {
            #pragma unroll
            for (int d = 0; d < NSTR; ++d) ps = fmaf(htg[d], hs[d], ps);
        }
        #pragma unroll
        for (int mk = 1; mk < 16; mk <<= 1) {
            ps += __shfl_xor(ps, mk);
            pp += __shfl_xor(pp, mk);
        }
        if (sub == 0 && val) {
            score[b0 + j0 + grp] = ps;
            pairv[eid] = pp;
        }
    }

    float m = -1e30f;
    for (int i = lane; i < deg; i += 64) m = fmaxf(m, score[b0 + i]);
    #pragma unroll
    for (int mk = 1; mk < 64; mk <<= 1) m = fmaxf(m, __shfl_xor(m, mk));
    float psum = 0.f;
    for (int i = lane; i < deg; i += 64) {
        const float e = expf(score[b0 + i] - m);
        score[b0 + i] = e;
        psum += e;
    }
    #pragma unroll
    for (int mk = 1; mk < 64; mk <<= 1) psum += __shfl_xor(psum, mk);
    if (lane == 0) sumt_inv[t] = 1.f / psum;
}

// ---------------------------------------------------------------------------
// k_beta2: wave per SOURCE node, streaming; fuses rho.
// ---------------------------------------------------------------------------
__global__ __launch_bounds__(256) void k_beta2(
    const int* __restrict__ base_s, const int* __restrict__ eid_s,
    const int* __restrict__ etgt,
    const float* __restrict__ pairv, const float* __restrict__ psi,
    float* __restrict__ rho1m, int N)
{
    const int lane = threadIdx.x & 63, wv = threadIdx.x >> 6;
    const int s = blockIdx.x * 4 + wv;
    if (s >= N) return;
    const int b0 = base_s[s], deg = base_s[s + 1] - b0;

    float m = -1e30f;
    for (int i = lane; i < deg; i += 64) m = fmaxf(m, pairv[eid_s[b0 + i]]);
    #pragma unroll
    for (int mk = 1; mk < 64; mk <<= 1) m = fmaxf(m, __shfl_xor(m, mk));

    float se = 0.f, sn = 0.f;
    for (int i = lane; i < deg; i += 64) {
        const int e = eid_s[b0 + i];
        const float ex = expf(pairv[e] - m);
        se += ex;
        sn += ex * expf(-psi[etgt[e]]);
    }
    #pragma unroll
    for (int mk = 1; mk < 64; mk <<= 1) {
        se += __shfl_xor(se, mk);
        sn += __shfl_xor(sn, mk);
    }
    if (lane == 0) {
        const float st = (deg > 0 && se > 0.f) ? sn / se : 0.f;
        const float d  = -logf(st + 1e-8f);
        rho1m[s] = 1.f - 1.f / (1.f + expf(-(GAMMA * (d - DELTA))));
    }
}

// ---------------------------------------------------------------------------
// k_matt: wave per TARGET, 8 edges in flight; gathers HB (warm from k_score).
// agg[t] = sum_e c_e * H_bf[src];  sig[t] = sum_e c_e.
// ---------------------------------------------------------------------------
__global__ __launch_bounds__(256) void k_matt(
    const int* __restrict__ eid_t, const int* __restrict__ base_t,
    const int* __restrict__ esrc,
    const float* __restrict__ score, const float* __restrict__ sumt_inv,
    const float* __restrict__ rho1m,
    const unsigned short* __restrict__ HB,
    float* __restrict__ agg, float* __restrict__ sig, int N)
{
    const int lane = threadIdx.x & 63, wv = threadIdx.x >> 6;
    const int t = blockIdx.x * 4 + wv;
    if (t >= N) return;
    const int b0 = base_t[t], deg = base_t[t + 1] - b0;
    const int sub = lane & 15, grp = lane >> 4;
    const size_t to = (size_t)t * HID;

    float acc[8];
    #pragma unroll
    for (int d = 0; d < 8; ++d) acc[d] = 0.f;
    float csum = 0.f;
    const float inv = (deg > 0) ? sumt_inv[t] : 0.f;

    for (int j0 = 0; j0 < deg; j0 += 8) {
        const int jA = j0 + grp, jB = j0 + 4 + grp;
        const bool vA = jA < deg, vB = jB < deg;
        float cA = 0.f, cB = 0.f;
        size_t soA = 0, soB = 0;
        if (vA) {
            const int e = eid_t[b0 + jA];
            const int s = esrc[e];
            cA = score[b0 + jA] * inv * rho1m[s];
            soA = (size_t)s * HID;
        }
        if (vB) {
            const int e = eid_t[b0 + jB];
            const int s = esrc[e];
            cB = score[b0 + jB] * inv * rho1m[s];
            soB = (size_t)s * HID;
        }
        const uint4 rA = *(const uint4*)&HB[soA + sub * 8];
        const uint4 rB = *(const uint4*)&HB[soB + sub * 8];
        float hA[8], hB[8];
        unpack8(rA, hA); unpack8(rB, hB);
        #pragma unroll
        for (int d = 0; d < 8; ++d) {
            acc[d] = fmaf(cA, hA[d], acc[d]);
            acc[d] = fmaf(cB, hB[d], acc[d]);
        }
        if (sub == 0) csum += cA + cB;
    }
    #pragma unroll
    for (int d = 0; d < 8; ++d) {
        acc[d] += __shfl_xor(acc[d], 16);
        acc[d] += __shfl_xor(acc[d], 32);
    }
    csum += __shfl_xor(csum, 16);
    csum += __shfl_xor(csum, 32);
    if (grp == 0) {
        f4 o0, o1;
        #pragma unroll
        for (int d = 0; d < 4; ++d) { o0[d] = acc[d]; o1[d] = acc[d + 4]; }
        *(f4*)&agg[to + sub * 8]     = o0;
        *(f4*)&agg[to + sub * 8 + 4] = o1;
        if (sub == 0) sig[t] = csum;
    }
}

extern "C" void kernel_launch(void* const* d_in, const int* in_sizes, int n_in,
                              void* d_out, int out_size, void* d_ws, size_t ws_size,
                              hipStream_t stream)
{
    const int*   eidx   = (const int*)  d_in[0];
    const float* H      = (const float*)d_in[1];
    const float* W_att  = (const float*)d_in[2];
    const float* phi_w  = (const float*)d_in[3];
    const float* phi_b  = (const float*)d_in[4];
    const float* W_p    = (const float*)d_in[5];
    const float* W_pp   = (const float*)d_in[6];
    const float* fdef_w = (const float*)d_in[7];
    const float* fdef_b = (const float*)d_in[8];
    const float* Wself  = (const float*)d_in[9];
    const float* bself  = (const float*)d_in[10];
    const float* WA     = (const float*)d_in[11];
    const float* bA     = (const float*)d_in[12];
    const float* Wstr   = (const float*)d_in[13];
    const float* bstr   = (const float*)d_in[14];
    const float* lng    = (const float*)d_in[15];
    const float* lnb    = (const float*)d_in[16];
    float* out = (float*)d_out;

    const int E = in_sizes[0] / 2;
    const int N = in_sizes[1] / HID;
    const int* esrc = eidx;
    const int* etgt = eidx + E;

    const int NB = (N + 255) >> 8;
    const int NC = (E + CSR_CHUNK - 1) / CSR_CHUNK;
    const int L  = NB * NC;

    // ---- workspace layout (~72 MB) ----
    char* w = (char*)d_ws;
    const size_t NHb  = (size_t)N * HID * sizeof(unsigned short);
    const size_t NH   = (size_t)N * HID * sizeof(float);
    const size_t Epad = (((size_t)E * sizeof(float)) + 255) & ~255ull;
    const size_t Npad = (((size_t)(N + 1) * sizeof(float)) + 255) & ~255ull;
    const size_t Lpad = (((size_t)(L + 1) * sizeof(int)) + 255) & ~255ull;

    float*          Wt    = (float*)w;          w += NH;   // agg aliases after k_score
    unsigned short* UB    = (unsigned short*)w; w += NHb;
    unsigned short* HB    = (unsigned short*)w; w += NHb;
    float* score   = (float*)w; w += Epad;  // CSR-tgt order
    float* pairv   = (float*)w; w += Epad;  // edge-id order
    int*   eid_t   = (int*)  w; w += Epad;
    int*   eid_s   = (int*)  w; w += Epad;
    int*   ebuck_t = (int*)  w; w += Epad;
    int*   ebuck_s = (int*)  w; w += Epad;
    int*   cnt_t = (int*)w; w += Lpad;
    int*   off_t = (int*)w; w += Lpad;
    int*   cnt_s = (int*)w; w += Lpad;
    int*   off_s = (int*)w; w += Lpad;
    int*   base_t   = (int*)  w; w += Npad;   // N+1
    int*   base_s   = (int*)  w; w += Npad;   // N+1
    float* sumt_inv = (float*)w; w += Npad;
    float* psi      = (float*)w; w += Npad;
    float* rho1m    = (float*)w; w += Npad;
    float* sig      = (float*)w; w += Npad;
    float* pbA      = (float*)w; w += 512;   // 128 floats
    unsigned short* WT = (unsigned short*)w;  // 4 slots x 2 planes x 128x128
    w += 4 * 2 * HID * HID * sizeof(unsigned short);
    float* agg = Wt;   // alias: Wt dead after k_score

    const int nblk128 = (N + 127) / 128;
    const int nblkN4  = (N + 3) / 4;
    const size_t lds_mfma = 4 * 128 * KPAD * sizeof(unsigned short);  // 72 KB
    const size_t MSZ = (size_t)2 * HID * HID;

    // slots: 0 = W_att(nat), 1 = Wself(T), 2 = M2, 3 = G  — one launch
    k_prep_all<<<dim3(8, 4), 256, 0, stream>>>(W_att, Wself, W_p, W_pp,
                                               phi_w, WA, phi_b, WT, pbA);

    k_castpsi<<<(N + 15) / 16, 256, 0, stream>>>(H, fdef_w, fdef_b, HB, psi, N);

    GemmArgsT g2;
    g2.Whi[0] = WT;           g2.Wlo[0] = WT + HID * HID;             // W_att
    g2.Whi[1] = WT + 2 * MSZ; g2.Wlo[1] = WT + 2 * MSZ + HID * HID;   // M2
    g2.O[0] = Wt;  g2.of32[0] = 1;
    g2.O[1] = UB;  g2.of32[1] = 0;
    k_gemm<<<dim3(nblk128, 2), 256, lds_mfma, stream>>>(H, g2, N);

    // ---- CSR build (no global atomics) ----
    k_csr_count<<<dim3(NC, 2), 256, 0, stream>>>(etgt, esrc, cnt_t, cnt_s, NB, NC, E);
    k_csr_scan<<<2, 1024, 0, stream>>>(cnt_t, off_t, cnt_s, off_s, L);
    k_csr_bucket<<<dim3(NC, 2), 256, 0, stream>>>(etgt, esrc, off_t, off_s,
                                                  ebuck_t, ebuck_s, NB, NC, E);
    k_csr_final<<<dim3(NB, 2), 256, 0, stream>>>(etgt, esrc, off_t, off_s,
                                                 ebuck_t, ebuck_s, base_t, base_s,
                                                 eid_t, eid_s, NB, NC, N, E);

    k_score<<<nblkN4, 256, 0, stream>>>(eid_t, base_t, esrc, Wt, UB, HB,
                                        score, pairv, sumt_inv, N);
    k_beta2<<<nblkN4, 256, 0, stream>>>(base_s, eid_s, etgt, pairv, psi, rho1m, N);

    k_matt<<<nblkN4, 256, 0, stream>>>(eid_t, base_t, esrc, score, sumt_inv,
                                       rho1m, HB, agg, sig, N);

    k_final<<<nblk128, 256, lds_mfma, stream>>>(agg, H, sig, pbA,
                                                WT + 3 * MSZ, WT + 3 * MSZ + HID * HID,
                                                WT + 1 * MSZ, WT + 1 * MSZ + HID * HID,
                                                Wstr, bself, bA, bstr, lng, lnb, out, N);
}

// Round 15
// 305.274 us; speedup vs baseline: 1.5545x; 1.0444x over previous
//
#include <hip/hip_runtime.h>
#include <math.h>

#define HID 128
#define NSTR 6              // STRUCT-1
#define GAMMA 1.0f
#define DELTA 0.5f
#define LN_EPS 1e-5f
#define KPAD 72             // bf16 elems per LDS row (64 + 8 pad)
#define CSR_CHUNK 8192      // edges per block in CSR build

typedef __attribute__((ext_vector_type(4))) float f4;
typedef __attribute__((ext_vector_type(8))) short bf16x8;
typedef __attribute__((ext_vector_type(4))) float f32x4;

// f32 -> bf16 (round-to-nearest-even) and helpers
__device__ __forceinline__ unsigned short f2bf(float f) {
    unsigned u = __float_as_uint(f);
    unsigned r = u + 0x7FFFu + ((u >> 16) & 1u);
    return (unsigned short)(r >> 16);
}
__device__ __forceinline__ float bf2f(unsigned short h) {
    return __uint_as_float((unsigned)h << 16);
}
__device__ __forceinline__ void split2(float v, unsigned short& h, unsigned short& l) {
    h = f2bf(v);
    l = f2bf(v - bf2f(h));
}
__device__ __forceinline__ void bf2f2(unsigned u, float& lo, float& hi) {
    lo = __uint_as_float(u << 16);
    hi = __uint_as_float(u & 0xFFFF0000u);
}
__device__ __forceinline__ void unpack8(const uint4 u, float* f) {
    bf2f2(u.x, f[0], f[1]); bf2f2(u.y, f[2], f[3]);
    bf2f2(u.z, f[4], f[5]); bf2f2(u.w, f[6], f[7]);
}

// ---------------------------------------------------------------------------
// k_prep_all: all weight-table prep in ONE launch, grid (8, 4).
// mode 0: slot0 = W_att natural; mode 1: slot1 = Wself^T;
// mode 2: slot2 = M2 = W_p @ W_pp^T; mode 3: slot3 = G (+ pbA).
// ---------------------------------------------------------------------------
__global__ __launch_bounds__(256) void k_prep_all(
    const float* __restrict__ W_att, const float* __restrict__ Wself,
    const float* __restrict__ Wp,    const float* __restrict__ Wpp,
    const float* __restrict__ phiw,  const float* __restrict__ WA,
    const float* __restrict__ phib,
    unsigned short* __restrict__ WT, float* __restrict__ pbA)
{
    __shared__ float Bs[128][129];
    __shared__ float As[16][129];
    const int mode = blockIdx.y, c0 = blockIdx.x * 16;
    const int tid = threadIdx.x;
    const size_t MSZ = (size_t)2 * HID * HID;
    unsigned short* hi = WT + (size_t)mode * MSZ;
    unsigned short* lo = hi + HID * HID;

    if (mode == 0) {
        for (int idx = tid; idx < 2048; idx += 256) {
            const int c = idx >> 7, k = idx & 127;
            unsigned short h, l;
            split2(W_att[(size_t)(c0 + c) * HID + k], h, l);
            hi[(size_t)(c0 + c) * HID + k] = h;
            lo[(size_t)(c0 + c) * HID + k] = l;
        }
    } else if (mode == 1) {
        for (int idx = tid; idx < 2048; idx += 256) {
            const int k = idx >> 4, c = idx & 15;
            Bs[k][c] = Wself[k * HID + c0 + c];
        }
        __syncthreads();
        for (int idx = tid; idx < 2048; idx += 256) {
            const int c = idx >> 7, k = idx & 127;
            unsigned short h, l;
            split2(Bs[k][c], h, l);
            hi[(size_t)(c0 + c) * HID + k] = h;
            lo[(size_t)(c0 + c) * HID + k] = l;
        }
    } else if (mode == 2) {
        for (int idx = tid; idx < 128 * 128; idx += 256)
            Bs[idx >> 7][idx & 127] = Wpp[idx];
        for (int idx = tid; idx < 16 * 128; idx += 256)
            As[idx >> 7][idx & 127] = Wp[(size_t)(c0 + (idx >> 7)) * HID + (idx & 127)];
        __syncthreads();
        for (int it = 0; it < 8; ++it) {
            const int idx = tid + 256 * it;
            const int c = idx >> 7, k = idx & 127;
            float a = 0.f;
            #pragma unroll 4
            for (int j = 0; j < 128; ++j)
                a = fmaf(As[c][j], Bs[k][j], a);
            unsigned short h, l;
            split2(a, h, l);
            hi[(size_t)(c0 + c) * HID + k] = h;
            lo[(size_t)(c0 + c) * HID + k] = l;
        }
    } else {
        for (int idx = tid; idx < 128 * 128; idx += 256)
            Bs[idx >> 7][idx & 127] = phiw[idx];
        for (int idx = tid; idx < 16 * 128; idx += 256) {
            const int c = idx >> 7, j = idx & 127;
            As[c][j] = WA[(size_t)j * HID + c0 + c];
        }
        __syncthreads();
        for (int it = 0; it < 8; ++it) {
            const int idx = tid + 256 * it;
            const int c = idx >> 7, k = idx & 127;
            float a = 0.f;
            #pragma unroll 4
            for (int j = 0; j < 128; ++j)
                a = fmaf(As[c][j], Bs[k][j], a);
            unsigned short h, l;
            split2(a, h, l);
            hi[(size_t)(c0 + c) * HID + k] = h;
            lo[(size_t)(c0 + c) * HID + k] = l;
        }
        if (tid < 16) {
            float a = 0.f;
            #pragma unroll 4
            for (int j = 0; j < 128; ++j)
                a = fmaf(phib[j], As[tid][j], a);
            pbA[c0 + tid] = a;
        }
    }
}

// ---------------------------------------------------------------------------
// k_castpsi: HB = bf16(H) AND psi = H.f_def_w + f_def_b in one H pass.
// ---------------------------------------------------------------------------
__global__ __launch_bounds__(256) void k_castpsi(
    const float* __restrict__ H, const float* __restrict__ fw,
    const float* __restrict__ fb,
    unsigned short* __restrict__ HB, float* __restrict__ psi, int N)
{
    const int tid = threadIdx.x;
    const int row = blockIdx.x * 16 + (tid >> 4), sub = tid & 15;
    if (row >= N) return;
    const size_t o = (size_t)row * HID + sub * 8;
    const f4 v0 = *(const f4*)&H[o];
    const f4 v1 = *(const f4*)&H[o + 4];
    ushort4 a, b;
    a.x = f2bf(v0[0]); a.y = f2bf(v0[1]); a.z = f2bf(v0[2]); a.w = f2bf(v0[3]);
    b.x = f2bf(v1[0]); b.y = f2bf(v1[1]); b.z = f2bf(v1[2]); b.w = f2bf(v1[3]);
    *(ushort4*)&HB[o] = a;
    *(ushort4*)&HB[o + 4] = b;
    const f4 w0 = *(const f4*)&fw[sub * 8];
    const f4 w1 = *(const f4*)&fw[sub * 8 + 4];
    float s = v0[0]*w0[0] + v0[1]*w0[1] + v0[2]*w0[2] + v0[3]*w0[3]
            + v1[0]*w1[0] + v1[1]*w1[1] + v1[2]*w1[2] + v1[3]*w1[3];
    #pragma unroll
    for (int mk = 1; mk < 16; mk <<= 1) s += __shfl_xor(s, mk);
    if (sub == 0) psi[row] = s + fb[0];
}

struct GemmArgsT {
    const unsigned short* Whi[2];
    const unsigned short* Wlo[2];
    void*                 O[2];
    int                   of32[2];
};

// ---------------------------------------------------------------------------
// MFMA GEMM: O[ph] = A @ B[ph], split-precision (hi/lo bf16, 3 MFMA).
// ---------------------------------------------------------------------------
__global__ __launch_bounds__(256, 2) void k_gemm(const float* __restrict__ A,
                                                 GemmArgsT g, int N)
{
    extern __shared__ unsigned short lds[];
    unsigned short* Ahi = lds;
    unsigned short* Alo = lds + 128 * KPAD;
    unsigned short* Bhi = lds + 2 * 128 * KPAD;
    unsigned short* Blo = lds + 3 * 128 * KPAD;
    const int tid  = threadIdx.x;
    const int row0 = blockIdx.x * 128;
    const int nrows = min(128, N - row0);
    const int ph   = blockIdx.y;
    const int w    = tid >> 6, lane = tid & 63;
    const int lrow = lane & 15, kgrp = lane >> 4;

    f32x4 acc[2][8];
    #pragma unroll
    for (int tc = 0; tc < 8; ++tc) {
        acc[0][tc] = f32x4{0.f, 0.f, 0.f, 0.f};
        acc[1][tc] = f32x4{0.f, 0.f, 0.f, 0.f};
    }

    const unsigned short* __restrict__ Wh = g.Whi[ph];
    const unsigned short* __restrict__ Wl = g.Wlo[ph];

    for (int ch = 0; ch < 2; ++ch) {
        __syncthreads();
        #pragma unroll
        for (int it = 0; it < 8; ++it) {
            const int idx = tid + 256 * it;
            const int r = idx >> 4, kq = (idx & 15) * 4;
            f4 v = {0.f, 0.f, 0.f, 0.f};
            if (r < nrows) v = *(const f4*)&A[(size_t)(row0 + r) * HID + ch * 64 + kq];
            ushort4 h, l;
            split2(v[0], h.x, l.x); split2(v[1], h.y, l.y);
            split2(v[2], h.z, l.z); split2(v[3], h.w, l.w);
            *(ushort4*)&Ahi[r * KPAD + kq] = h;
            *(ushort4*)&Alo[r * KPAD + kq] = l;
        }
        #pragma unroll
        for (int it = 0; it < 4; ++it) {
            const int idx = tid + 256 * it;
            const int c = idx >> 3, k8 = (idx & 7) * 8;
            *(uint4*)&Bhi[c * KPAD + k8] = *(const uint4*)&Wh[(size_t)c * HID + ch * 64 + k8];
            *(uint4*)&Blo[c * KPAD + k8] = *(const uint4*)&Wl[(size_t)c * HID + ch * 64 + k8];
        }
        __syncthreads();

        #pragma unroll
        for (int ks = 0; ks < 2; ++ks) {
            const int ko = ks * 32 + kgrp * 8;
            bf16x8 ah[2], al[2], bh[8], bl[8];
            #pragma unroll
            for (int tr = 0; tr < 2; ++tr) {
                const int rr = w * 32 + tr * 16 + lrow;
                ah[tr] = *(const bf16x8*)&Ahi[rr * KPAD + ko];
                al[tr] = *(const bf16x8*)&Alo[rr * KPAD + ko];
            }
            #pragma unroll
            for (int tc = 0; tc < 8; ++tc) {
                const int cc = tc * 16 + lrow;
                bh[tc] = *(const bf16x8*)&Bhi[cc * KPAD + ko];
                bl[tc] = *(const bf16x8*)&Blo[cc * KPAD + ko];
            }
            #pragma unroll
            for (int tr = 0; tr < 2; ++tr)
                #pragma unroll
                for (int tc = 0; tc < 8; ++tc) {
                    acc[tr][tc] = __builtin_amdgcn_mfma_f32_16x16x32_bf16(ah[tr], bh[tc], acc[tr][tc], 0, 0, 0);
                    acc[tr][tc] = __builtin_amdgcn_mfma_f32_16x16x32_bf16(al[tr], bh[tc], acc[tr][tc], 0, 0, 0);
                    acc[tr][tc] = __builtin_amdgcn_mfma_f32_16x16x32_bf16(ah[tr], bl[tc], acc[tr][tc], 0, 0, 0);
                }
        }
    }

    #pragma unroll
    for (int tr = 0; tr < 2; ++tr)
        #pragma unroll
        for (int j = 0; j < 4; ++j) {
            const int r = w * 32 + tr * 16 + kgrp * 4 + j;
            if (r < nrows) {
                if (g.of32[ph]) {
                    float* O = (float*)g.O[ph];
                    #pragma unroll
                    for (int tc = 0; tc < 8; ++tc)
                        O[(size_t)(row0 + r) * HID + tc * 16 + lrow] = acc[tr][tc][j];
                } else {
                    unsigned short* O = (unsigned short*)g.O[ph];
                    #pragma unroll
                    for (int tc = 0; tc < 8; ++tc)
                        O[(size_t)(row0 + r) * HID + tc * 16 + lrow] = f2bf(acc[tr][tc][j]);
                }
            }
        }
}

// ---------------------------------------------------------------------------
// k_final: out = LN(relu(agg@G + sig*pbA + H@Wself + s@Wstr + biases) + H)
// ---------------------------------------------------------------------------
__global__ __launch_bounds__(256, 2) void k_final(
    const float* __restrict__ Agg, const float* __restrict__ H,
    const float* __restrict__ sig, const float* __restrict__ pbA,
    const unsigned short* __restrict__ Ghi, const unsigned short* __restrict__ Glo,
    const unsigned short* __restrict__ WShi, const unsigned short* __restrict__ WSlo,
    const float* __restrict__ Wstr,
    const float* __restrict__ bself, const float* __restrict__ bA,
    const float* __restrict__ bstr,
    const float* __restrict__ lng, const float* __restrict__ lnb,
    float* __restrict__ out, int N)
{
    extern __shared__ unsigned short lds[];
    unsigned short* Ahi = lds;
    unsigned short* Alo = lds + 128 * KPAD;
    unsigned short* Bhi = lds + 2 * 128 * KPAD;
    unsigned short* Blo = lds + 3 * 128 * KPAD;
    const int tid  = threadIdx.x;
    const int row0 = blockIdx.x * 128;
    const int nrows = min(128, N - row0);
    const int w    = tid >> 6, lane = tid & 63;
    const int lrow = lane & 15, kgrp = lane >> 4;

    f32x4 acc[2][8];
    float gl[8], bl_[8], pb[8];
    #pragma unroll
    for (int tc = 0; tc < 8; ++tc) {
        const int c = tc * 16 + lrow;
        const float bv = bself[c] + bA[c] + bstr[c];
        acc[0][tc] = f32x4{bv, bv, bv, bv};
        acc[1][tc] = f32x4{bv, bv, bv, bv};
        gl[tc] = lng[c]; bl_[tc] = lnb[c]; pb[tc] = pbA[c];
    }

    for (int ph = 0; ph < 2; ++ph) {
        const float* __restrict__ Am = ph ? H : Agg;
        const unsigned short* __restrict__ Wh = ph ? WShi : Ghi;
        const unsigned short* __restrict__ Wl = ph ? WSlo : Glo;
        for (int ch = 0; ch < 2; ++ch) {
            __syncthreads();
            #pragma unroll
            for (int it = 0; it < 8; ++it) {
                const int idx = tid + 256 * it;
                const int r = idx >> 4, kq = (idx & 15) * 4;
                f4 v = {0.f, 0.f, 0.f, 0.f};
                if (r < nrows) v = *(const f4*)&Am[(size_t)(row0 + r) * HID + ch * 64 + kq];
                ushort4 h, l;
                split2(v[0], h.x, l.x); split2(v[1], h.y, l.y);
                split2(v[2], h.z, l.z); split2(v[3], h.w, l.w);
                *(ushort4*)&Ahi[r * KPAD + kq] = h;
                *(ushort4*)&Alo[r * KPAD + kq] = l;
            }
            #pragma unroll
            for (int it = 0; it < 4; ++it) {
                const int idx = tid + 256 * it;
                const int c = idx >> 3, k8 = (idx & 7) * 8;
                *(uint4*)&Bhi[c * KPAD + k8] = *(const uint4*)&Wh[(size_t)c * HID + ch * 64 + k8];
                *(uint4*)&Blo[c * KPAD + k8] = *(const uint4*)&Wl[(size_t)c * HID + ch * 64 + k8];
            }
            __syncthreads();

            #pragma unroll
            for (int ks = 0; ks < 2; ++ks) {
                const int ko = ks * 32 + kgrp * 8;
                bf16x8 ah[2], al[2], bh[8], bl[8];
                #pragma unroll
                for (int tr = 0; tr < 2; ++tr) {
                    const int rr = w * 32 + tr * 16 + lrow;
                    ah[tr] = *(const bf16x8*)&Ahi[rr * KPAD + ko];
                    al[tr] = *(const bf16x8*)&Alo[rr * KPAD + ko];
                }
                #pragma unroll
                for (int tc = 0; tc < 8; ++tc) {
                    const int cc = tc * 16 + lrow;
                    bh[tc] = *(const bf16x8*)&Bhi[cc * KPAD + ko];
                    bl[tc] = *(const bf16x8*)&Blo[cc * KPAD + ko];
                }
                #pragma unroll
                for (int tr = 0; tr < 2; ++tr)
                    #pragma unroll
                    for (int tc = 0; tc < 8; ++tc) {
                        acc[tr][tc] = __builtin_amdgcn_mfma_f32_16x16x32_bf16(ah[tr], bh[tc], acc[tr][tc], 0, 0, 0);
                        acc[tr][tc] = __builtin_amdgcn_mfma_f32_16x16x32_bf16(al[tr], bh[tc], acc[tr][tc], 0, 0, 0);
                        acc[tr][tc] = __builtin_amdgcn_mfma_f32_16x16x32_bf16(ah[tr], bl[tc], acc[tr][tc], 0, 0, 0);
                    }
            }

            if (ph == 1 && ch == 0) {
                #pragma unroll
                for (int tr = 0; tr < 2; ++tr)
                    #pragma unroll
                    for (int j = 0; j < 4; ++j) {
                        const int rr = w * 32 + tr * 16 + kgrp * 4 + j;
                        float s[NSTR];
                        #pragma unroll
                        for (int k = 0; k < NSTR; ++k)
                            s[k] = bf2f(Ahi[rr * KPAD + k]) + bf2f(Alo[rr * KPAD + k]);
                        #pragma unroll
                        for (int tc = 0; tc < 8; ++tc) {
                            float a = 0.f;
                            #pragma unroll
                            for (int k = 0; k < NSTR; ++k)
                                a = fmaf(s[k], Wstr[k * HID + tc * 16 + lrow], a);
                            acc[tr][tc][j] += a;
                        }
                    }
            }
        }
    }

    #pragma unroll
    for (int tr = 0; tr < 2; ++tr)
        #pragma unroll
        for (int j = 0; j < 4; ++j) {
            const int r = w * 32 + tr * 16 + kgrp * 4 + j;
            const bool valid = r < nrows;
            const size_t rb = (size_t)(row0 + r) * HID;
            const float sg = valid ? sig[row0 + r] : 0.f;
            float v[8], s1 = 0.f, s2 = 0.f;
            #pragma unroll
            for (int tc = 0; tc < 8; ++tc) {
                float x = fmaxf(acc[tr][tc][j] + sg * pb[tc], 0.f);
                if (valid) x += H[rb + tc * 16 + lrow];
                v[tc] = x;
                s1 += x; s2 += x * x;
            }
            #pragma unroll
            for (int mk = 1; mk < 16; mk <<= 1) {
                s1 += __shfl_xor(s1, mk);
                s2 += __shfl_xor(s2, mk);
            }
            const float mean = s1 * (1.f / HID);
            const float var  = s2 * (1.f / HID) - mean * mean;
            const float rs   = rsqrtf(var + LN_EPS);
            if (valid) {
                #pragma unroll
                for (int tc = 0; tc < 8; ++tc)
                    out[rb + tc * 16 + lrow] = (v[tc] - mean) * rs * gl[tc] + bl_[tc];
            }
        }
}

// ---------------------------------------------------------------------------
// CSR build via two-level LDS counting sort — ZERO global atomics.
// csr_final also denormalizes the companion endpoint into the CSR slot.
// ---------------------------------------------------------------------------
__global__ __launch_bounds__(256) void k_csr_count(
    const int* __restrict__ etgt, const int* __restrict__ esrc,
    int* __restrict__ cnt_t, int* __restrict__ cnt_s,
    int NB, int NC, int E)
{
    __shared__ int cnt[256];
    const int which = blockIdx.y;
    const int* __restrict__ key = which ? esrc : etgt;
    int* __restrict__ outc = which ? cnt_s : cnt_t;
    const int tid = threadIdx.x;
    for (int i = tid; i < NB; i += 256) cnt[i] = 0;
    __syncthreads();
    const int e0 = blockIdx.x * CSR_CHUNK;
    const int e1 = min(e0 + CSR_CHUNK, E);
    for (int e = e0 + tid; e < e1; e += 256)
        atomicAdd(&cnt[key[e] >> 8], 1);
    __syncthreads();
    for (int k = tid; k < NB; k += 256)
        outc[(size_t)k * NC + blockIdx.x] = cnt[k];
}

__global__ __launch_bounds__(1024) void k_csr_scan(
    const int* __restrict__ cnt_t, int* __restrict__ off_t,
    const int* __restrict__ cnt_s, int* __restrict__ off_s, int L)
{
    const int* __restrict__ cnt = blockIdx.x ? cnt_s : cnt_t;
    int* __restrict__ off = blockIdx.x ? off_s : off_t;
    __shared__ int warp_sums[16];
    __shared__ int carry_s;
    const int tid = threadIdx.x, lane = tid & 63, wid = tid >> 6;
    if (tid == 0) carry_s = 0;
    __syncthreads();
    for (int i0 = 0; i0 < L; i0 += 1024) {
        const int i = i0 + tid;
        const int v = (i < L) ? cnt[i] : 0;
        int x = v;
        #pragma unroll
        for (int d = 1; d < 64; d <<= 1) {
            const int y = __shfl_up(x, d);
            if (lane >= d) x += y;
        }
        if (lane == 63) warp_sums[wid] = x;
        __syncthreads();
        if (wid == 0) {
            int ws = (lane < 16) ? warp_sums[lane] : 0;
            #pragma unroll
            for (int d = 1; d < 16; d <<= 1) {
                const int y = __shfl_up(ws, d);
                if (lane >= d) ws += y;
            }
            if (lane < 16) warp_sums[lane] = ws;
        }
        __syncthreads();
        const int carry = carry_s;
        if (i < L) off[i] = carry + (wid ? warp_sums[wid - 1] : 0) + x - v;
        __syncthreads();
        if (tid == 1023) carry_s = carry + warp_sums[15];
        __syncthreads();
    }
    if (tid == 0) off[L] = carry_s;
}

__global__ __launch_bounds__(256) void k_csr_bucket(
    const int* __restrict__ etgt, const int* __restrict__ esrc,
    const int* __restrict__ off_t, const int* __restrict__ off_s,
    int* __restrict__ ebuck_t, int* __restrict__ ebuck_s,
    int NB, int NC, int E)
{
    __shared__ int cur[256];
    const int which = blockIdx.y;
    const int* __restrict__ key = which ? esrc : etgt;
    const int* __restrict__ off = which ? off_s : off_t;
    int* __restrict__ ebuck = which ? ebuck_s : ebuck_t;
    const int tid = threadIdx.x;
    for (int k = tid; k < NB; k += 256)
        cur[k] = off[(size_t)k * NC + blockIdx.x];
    __syncthreads();
    const int e0 = blockIdx.x * CSR_CHUNK;
    const int e1 = min(e0 + CSR_CHUNK, E);
    for (int e = e0 + tid; e < e1; e += 256) {
        const int p = atomicAdd(&cur[key[e] >> 8], 1);
        ebuck[p] = e;
    }
}

__global__ __launch_bounds__(256) void k_csr_final(
    const int* __restrict__ etgt, const int* __restrict__ esrc,
    const int* __restrict__ off_t, const int* __restrict__ off_s,
    const int* __restrict__ ebuck_t, const int* __restrict__ ebuck_s,
    int* __restrict__ base_t, int* __restrict__ base_s,
    int* __restrict__ eid_t, int* __restrict__ eid_s,
    int* __restrict__ src_t, int* __restrict__ tgt_s,
    int NB, int NC, int N, int E)
{
    __shared__ int cnt[256], excl[256], wsum[4];
    const int which = blockIdx.y;
    const int* __restrict__ key   = which ? esrc : etgt;
    const int* __restrict__ oth   = which ? etgt : esrc;
    const int* __restrict__ off   = which ? off_s : off_t;
    const int* __restrict__ ebuck = which ? ebuck_s : ebuck_t;
    int* __restrict__ base = which ? base_s : base_t;
    int* __restrict__ eid  = which ? eid_s : eid_t;
    int* __restrict__ aux  = which ? tgt_s : src_t;
    const int tid = threadIdx.x, lane = tid & 63, wv = tid >> 6;
    const int k = blockIdx.x;
    const int segb = off[(size_t)k * NC];
    const int sege = (k + 1 < NB) ? off[(size_t)(k + 1) * NC] : E;
    cnt[tid] = 0;
    __syncthreads();
    for (int i = segb + tid; i < sege; i += 256)
        atomicAdd(&cnt[key[ebuck[i]] & 255], 1);
    __syncthreads();
    {
        const int orig = cnt[tid];
        int x = orig;
        #pragma unroll
        for (int d = 1; d < 64; d <<= 1) {
            const int y = __shfl_up(x, d);
            if (lane >= d) x += y;
        }
        if (lane == 63) wsum[wv] = x;
        __syncthreads();
        if (tid == 0) {
            int a = 0;
            #pragma unroll
            for (int i = 0; i < 4; ++i) { const int t = wsum[i]; wsum[i] = a; a += t; }
        }
        __syncthreads();
        excl[tid] = x - orig + wsum[wv];
    }
    __syncthreads();
    const int node = k * 256 + tid;
    if (node < N) base[node] = segb + excl[tid];
    if (k == NB - 1 && tid == 0) base[N] = E;
    cnt[tid] = excl[tid];
    __syncthreads();
    for (int i = segb + tid; i < sege; i += 256) {
        const int e = ebuck[i];
        const int r = atomicAdd(&cnt[key[e] & 255], 1);
        eid[segb + r] = e;
        aux[segb + r] = oth[e];
    }
}

// ---------------------------------------------------------------------------
// k_score: wave per TARGET, 16-lane groups, src from contiguous src_t
// (2-deep chain: contig load -> gather), index prefetch.
// ---------------------------------------------------------------------------
__global__ __launch_bounds__(256) void k_score(
    const int* __restrict__ eid_t, const int* __restrict__ base_t,
    const int* __restrict__ src_t,
    const float* __restrict__ Wt, const unsigned short* __restrict__ UB,
    const unsigned short* __restrict__ HB,
    float* __restrict__ score, float* __restrict__ pairv,
    float* __restrict__ sumt_inv, int N)
{
    const int lane = threadIdx.x & 63, wv = threadIdx.x >> 6;
    const int t = blockIdx.x * 4 + wv;
    if (t >= N) return;
    const int b0 = base_t[t], deg = base_t[t + 1] - b0;
    if (deg == 0) { if (lane == 0) sumt_inv[t] = 0.f; return; }
    const int sub = lane & 15, grp = lane >> 4;
    const size_t to = (size_t)t * HID;

    float wt[8], u[8], htg[8];
    {
        const f4 w0 = *(const f4*)&Wt[to + sub * 8];
        const f4 w1 = *(const f4*)&Wt[to + sub * 8 + 4];
        wt[0] = w0[0]; wt[1] = w0[1]; wt[2] = w0[2]; wt[3] = w0[3];
        wt[4] = w1[0]; wt[5] = w1[1]; wt[6] = w1[2]; wt[7] = w1[3];
        unpack8(*(const uint4*)&UB[to + sub * 8], u);
        unpack8(*(const uint4*)&HB[to + sub * 8], htg);
    }

    // prologue: prefetch first edge's indices (both contiguous loads)
    bool valN = grp < deg;
    int eidN = 0, srcN = 0;
    if (valN) { eidN = eid_t[b0 + grp]; srcN = src_t[b0 + grp]; }

    for (int j0 = 0; j0 < deg; j0 += 4) {
        const bool val = valN;
        const int eid = eidN, src = srcN;
        const uint4 raw = *(const uint4*)&HB[(size_t)src * HID + sub * 8];
        const int jn = j0 + 4 + grp;
        valN = jn < deg;
        eidN = 0; srcN = 0;
        if (valN) { eidN = eid_t[b0 + jn]; srcN = src_t[b0 + jn]; }

        float hs[8];
        unpack8(raw, hs);
        float ps = 0.f, pp = 0.f;
        #pragma unroll
        for (int d = 0; d < 8; ++d) {
            ps = fmaf(wt[d], hs[d], ps);
            pp = fmaf(u[d], hs[d], pp);
        }
        if (sub == 0) {
            #pragma unroll
            for (int d = 0; d < NSTR; ++d) ps = fmaf(htg[d], hs[d], ps);
        }
        #pragma unroll
        for (int mk = 1; mk < 16; mk <<= 1) {
            ps += __shfl_xor(ps, mk);
            pp += __shfl_xor(pp, mk);
        }
        if (sub == 0 && val) {
            score[b0 + j0 + grp] = ps;
            pairv[eid] = pp;
        }
    }

    float m = -1e30f;
    for (int i = lane; i < deg; i += 64) m = fmaxf(m, score[b0 + i]);
    #pragma unroll
    for (int mk = 1; mk < 64; mk <<= 1) m = fmaxf(m, __shfl_xor(m, mk));
    float psum = 0.f;
    for (int i = lane; i < deg; i += 64) {
        const float e = expf(score[b0 + i] - m);
        score[b0 + i] = e;
        psum += e;
    }
    #pragma unroll
    for (int mk = 1; mk < 64; mk <<= 1) psum += __shfl_xor(psum, mk);
    if (lane == 0) sumt_inv[t] = 1.f / psum;
}

// ---------------------------------------------------------------------------
// k_beta2: wave per SOURCE node, streaming; fuses rho. tgt from tgt_s.
// ---------------------------------------------------------------------------
__global__ __launch_bounds__(256) void k_beta2(
    const int* __restrict__ base_s, const int* __restrict__ eid_s,
    const int* __restrict__ tgt_s,
    const float* __restrict__ pairv, const float* __restrict__ psi,
    float* __restrict__ rho1m, int N)
{
    const int lane = threadIdx.x & 63, wv = threadIdx.x >> 6;
    const int s = blockIdx.x * 4 + wv;
    if (s >= N) return;
    const int b0 = base_s[s], deg = base_s[s + 1] - b0;

    float m = -1e30f;
    for (int i = lane; i < deg; i += 64) m = fmaxf(m, pairv[eid_s[b0 + i]]);
    #pragma unroll
    for (int mk = 1; mk < 64; mk <<= 1) m = fmaxf(m, __shfl_xor(m, mk));

    float se = 0.f, sn = 0.f;
    for (int i = lane; i < deg; i += 64) {
        const float ex = expf(pairv[eid_s[b0 + i]] - m);
        se += ex;
        sn += ex * expf(-psi[tgt_s[b0 + i]]);
    }
    #pragma unroll
    for (int mk = 1; mk < 64; mk <<= 1) {
        se += __shfl_xor(se, mk);
        sn += __shfl_xor(sn, mk);
    }
    if (lane == 0) {
        const float st = (deg > 0 && se > 0.f) ? sn / se : 0.f;
        const float d  = -logf(st + 1e-8f);
        rho1m[s] = 1.f - 1.f / (1.f + expf(-(GAMMA * (d - DELTA))));
    }
}

// ---------------------------------------------------------------------------
// k_matt: wave per TARGET, 8 edges in flight; src from contiguous src_t
// (no eid/esrc loads at all); gathers HB (warm from k_score).
// ---------------------------------------------------------------------------
__global__ __launch_bounds__(256) void k_matt(
    const int* __restrict__ src_t, const int* __restrict__ base_t,
    const float* __restrict__ score, const float* __restrict__ sumt_inv,
    const float* __restrict__ rho1m,
    const unsigned short* __restrict__ HB,
    float* __restrict__ agg, float* __restrict__ sig, int N)
{
    const int lane = threadIdx.x & 63, wv = threadIdx.x >> 6;
    const int t = blockIdx.x * 4 + wv;
    if (t >= N) return;
    const int b0 = base_t[t], deg = base_t[t + 1] - b0;
    const int sub = lane & 15, grp = lane >> 4;
    const size_t to = (size_t)t * HID;

    float acc[8];
    #pragma unroll
    for (int d = 0; d < 8; ++d) acc[d] = 0.f;
    float csum = 0.f;
    const float inv = (deg > 0) ? sumt_inv[t] : 0.f;

    for (int j0 = 0; j0 < deg; j0 += 8) {
        const int jA = j0 + grp, jB = j0 + 4 + grp;
        const bool vA = jA < deg, vB = jB < deg;
        float cA = 0.f, cB = 0.f;
        size_t soA = 0, soB = 0;
        if (vA) {
            const int s = src_t[b0 + jA];
            cA = score[b0 + jA] * inv * rho1m[s];
            soA = (size_t)s * HID;
        }
        if (vB) {
            const int s = src_t[b0 + jB];
            cB = score[b0 + jB] * inv * rho1m[s];
            soB = (size_t)s * HID;
        }
        const uint4 rA = *(const uint4*)&HB[soA + sub * 8];
        const uint4 rB = *(const uint4*)&HB[soB + sub * 8];
        float hA[8], hB[8];
        unpack8(rA, hA); unpack8(rB, hB);
        #pragma unroll
        for (int d = 0; d < 8; ++d) {
            acc[d] = fmaf(cA, hA[d], acc[d]);
            acc[d] = fmaf(cB, hB[d], acc[d]);
        }
        if (sub == 0) csum += cA + cB;
    }
    #pragma unroll
    for (int d = 0; d < 8; ++d) {
        acc[d] += __shfl_xor(acc[d], 16);
        acc[d] += __shfl_xor(acc[d], 32);
    }
    csum += __shfl_xor(csum, 16);
    csum += __shfl_xor(csum, 32);
    if (grp == 0) {
        f4 o0, o1;
        #pragma unroll
        for (int d = 0; d < 4; ++d) { o0[d] = acc[d]; o1[d] = acc[d + 4]; }
        *(f4*)&agg[to + sub * 8]     = o0;
        *(f4*)&agg[to + sub * 8 + 4] = o1;
        if (sub == 0) sig[t] = csum;
    }
}

extern "C" void kernel_launch(void* const* d_in, const int* in_sizes, int n_in,
                              void* d_out, int out_size, void* d_ws, size_t ws_size,
                              hipStream_t stream)
{
    const int*   eidx   = (const int*)  d_in[0];
    const float* H      = (const float*)d_in[1];
    const float* W_att  = (const float*)d_in[2];
    const float* phi_w  = (const float*)d_in[3];
    const float* phi_b  = (const float*)d_in[4];
    const float* W_p    = (const float*)d_in[5];
    const float* W_pp   = (const float*)d_in[6];
    const float* fdef_w = (const float*)d_in[7];
    const float* fdef_b = (const float*)d_in[8];
    const float* Wself  = (const float*)d_in[9];
    const float* bself  = (const float*)d_in[10];
    const float* WA     = (const float*)d_in[11];
    const float* bA     = (const float*)d_in[12];
    const float* Wstr   = (const float*)d_in[13];
    const float* bstr   = (const float*)d_in[14];
    const float* lng    = (const float*)d_in[15];
    const float* lnb    = (const float*)d_in[16];
    float* out = (float*)d_out;

    const int E = in_sizes[0] / 2;
    const int N = in_sizes[1] / HID;
    const int* esrc = eidx;
    const int* etgt = eidx + E;

    const int NB = (N + 255) >> 8;
    const int NC = (E + CSR_CHUNK - 1) / CSR_CHUNK;
    const int L  = NB * NC;

    // ---- workspace layout (~79 MB) ----
    char* w = (char*)d_ws;
    const size_t NHb  = (size_t)N * HID * sizeof(unsigned short);
    const size_t NH   = (size_t)N * HID * sizeof(float);
    const size_t Epad = (((size_t)E * sizeof(float)) + 255) & ~255ull;
    const size_t Npad = (((size_t)(N + 1) * sizeof(float)) + 255) & ~255ull;
    const size_t Lpad = (((size_t)(L + 1) * sizeof(int)) + 255) & ~255ull;

    float*          Wt    = (float*)w;          w += NH;   // agg aliases after k_score
    unsigned short* UB    = (unsigned short*)w; w += NHb;
    unsigned short* HB    = (unsigned short*)w; w += NHb;
    float* score   = (float*)w; w += Epad;  // CSR-tgt order
    float* pairv   = (float*)w; w += Epad;  // edge-id order
    int*   eid_t   = (int*)  w; w += Epad;
    int*   eid_s   = (int*)  w; w += Epad;
    int*   src_t   = (int*)  w; w += Epad;  // CSR-tgt companion src
    int*   tgt_s   = (int*)  w; w += Epad;  // CSR-src companion tgt
    int*   ebuck_t = (int*)  w; w += Epad;
    int*   ebuck_s = (int*)  w; w += Epad;
    int*   cnt_t = (int*)w; w += Lpad;
    int*   off_t = (int*)w; w += Lpad;
    int*   cnt_s = (int*)w; w += Lpad;
    int*   off_s = (int*)w; w += Lpad;
    int*   base_t   = (int*)  w; w += Npad;   // N+1
    int*   base_s   = (int*)  w; w += Npad;   // N+1
    float* sumt_inv = (float*)w; w += Npad;
    float* psi      = (float*)w; w += Npad;
    float* rho1m    = (float*)w; w += Npad;
    float* sig      = (float*)w; w += Npad;
    float* pbA      = (float*)w; w += 512;   // 128 floats
    unsigned short* WT = (unsigned short*)w;  // 4 slots x 2 planes x 128x128
    w += 4 * 2 * HID * HID * sizeof(unsigned short);
    float* agg = Wt;   // alias: Wt dead after k_score

    const int nblk128 = (N + 127) / 128;
    const int nblkN4  = (N + 3) / 4;
    const size_t lds_mfma = 4 * 128 * KPAD * sizeof(unsigned short);  // 72 KB
    const size_t MSZ = (size_t)2 * HID * HID;

    // slots: 0 = W_att(nat), 1 = Wself(T), 2 = M2, 3 = G  — one launch
    k_prep_all<<<dim3(8, 4), 256, 0, stream>>>(W_att, Wself, W_p, W_pp,
                                               phi_w, WA, phi_b, WT, pbA);

    k_castpsi<<<(N + 15) / 16, 256, 0, stream>>>(H, fdef_w, fdef_b, HB, psi, N);

    GemmArgsT g2;
    g2.Whi[0] = WT;           g2.Wlo[0] = WT + HID * HID;             // W_att
    g2.Whi[1] = WT + 2 * MSZ; g2.Wlo[1] = WT + 2 * MSZ + HID * HID;   // M2
    g2.O[0] = Wt;  g2.of32[0] = 1;
    g2.O[1] = UB;  g2.of32[1] = 0;
    k_gemm<<<dim3(nblk128, 2), 256, lds_mfma, stream>>>(H, g2, N);

    // ---- CSR build (no global atomics) ----
    k_csr_count<<<dim3(NC, 2), 256, 0, stream>>>(etgt, esrc, cnt_t, cnt_s, NB, NC, E);
    k_csr_scan<<<2, 1024, 0, stream>>>(cnt_t, off_t, cnt_s, off_s, L);
    k_csr_bucket<<<dim3(NC, 2), 256, 0, stream>>>(etgt, esrc, off_t, off_s,
                                                  ebuck_t, ebuck_s, NB, NC, E);
    k_csr_final<<<dim3(NB, 2), 256, 0, stream>>>(etgt, esrc, off_t, off_s,
                                                 ebuck_t, ebuck_s, base_t, base_s,
                                                 eid_t, eid_s, src_t, tgt_s,
                                                 NB, NC, N, E);

    k_score<<<nblkN4, 256, 0, stream>>>(eid_t, base_t, src_t, Wt, UB, HB,
                                        score, pairv, sumt_inv, N);
    k_beta2<<<nblkN4, 256, 0, stream>>>(base_s, eid_s, tgt_s, pairv, psi, rho1m, N);

    k_matt<<<nblkN4, 256, 0, stream>>>(src_t, base_t, score, sumt_inv,
                                       rho1m, HB, agg, sig, N);

    k_final<<<nblk128, 256, lds_mfma, stream>>>(agg, H, sig, pbA,
                                                WT + 3 * MSZ, WT + 3 * MSZ + HID * HID,
                                                WT + 1 * MSZ, WT + 1 * MSZ + HID * HID,
                                                Wstr, bself, bA, bstr, lng, lnb, out, N);
}

// Round 16
// 294.006 us; speedup vs baseline: 1.6141x; 1.0383x over previous
//
#include <hip/hip_runtime.h>
#include <math.h>

#define HID 128
#define NSTR 6              // STRUCT-1
#define GAMMA 1.0f
#define DELTA 0.5f
#define LN_EPS 1e-5f
#define KPAD 72             // bf16 elems per LDS row (64 + 8 pad)
#define CSR_CHUNK 8192      // edges per block in CSR build

typedef __attribute__((ext_vector_type(4))) float f4;
typedef __attribute__((ext_vector_type(8))) short bf16x8;
typedef __attribute__((ext_vector_type(4))) float f32x4;

// f32 -> bf16 (round-to-nearest-even) and helpers
__device__ __forceinline__ unsigned short f2bf(float f) {
    unsigned u = __float_as_uint(f);
    unsigned r = u + 0x7FFFu + ((u >> 16) & 1u);
    return (unsigned short)(r >> 16);
}
__device__ __forceinline__ float bf2f(unsigned short h) {
    return __uint_as_float((unsigned)h << 16);
}
__device__ __forceinline__ void split2(float v, unsigned short& h, unsigned short& l) {
    h = f2bf(v);
    l = f2bf(v - bf2f(h));
}
__device__ __forceinline__ void bf2f2(unsigned u, float& lo, float& hi) {
    lo = __uint_as_float(u << 16);
    hi = __uint_as_float(u & 0xFFFF0000u);
}
__device__ __forceinline__ void unpack8(const uint4 u, float* f) {
    bf2f2(u.x, f[0], f[1]); bf2f2(u.y, f[2], f[3]);
    bf2f2(u.z, f[4], f[5]); bf2f2(u.w, f[6], f[7]);
}

// ---------------------------------------------------------------------------
// k_prep_all: all weight-table prep in ONE launch, grid (8, 4).
// mode 0: slot0 = W_att natural; mode 1: slot1 = Wself^T;
// mode 2: slot2 = M2 = W_p @ W_pp^T; mode 3: slot3 = G (+ pbA).
// ---------------------------------------------------------------------------
__global__ __launch_bounds__(256) void k_prep_all(
    const float* __restrict__ W_att, const float* __restrict__ Wself,
    const float* __restrict__ Wp,    const float* __restrict__ Wpp,
    const float* __restrict__ phiw,  const float* __restrict__ WA,
    const float* __restrict__ phib,
    unsigned short* __restrict__ WT, float* __restrict__ pbA)
{
    __shared__ float Bs[128][129];
    __shared__ float As[16][129];
    const int mode = blockIdx.y, c0 = blockIdx.x * 16;
    const int tid = threadIdx.x;
    const size_t MSZ = (size_t)2 * HID * HID;
    unsigned short* hi = WT + (size_t)mode * MSZ;
    unsigned short* lo = hi + HID * HID;

    if (mode == 0) {
        for (int idx = tid; idx < 2048; idx += 256) {
            const int c = idx >> 7, k = idx & 127;
            unsigned short h, l;
            split2(W_att[(size_t)(c0 + c) * HID + k], h, l);
            hi[(size_t)(c0 + c) * HID + k] = h;
            lo[(size_t)(c0 + c) * HID + k] = l;
        }
    } else if (mode == 1) {
        for (int idx = tid; idx < 2048; idx += 256) {
            const int k = idx >> 4, c = idx & 15;
            Bs[k][c] = Wself[k * HID + c0 + c];
        }
        __syncthreads();
        for (int idx = tid; idx < 2048; idx += 256) {
            const int c = idx >> 7, k = idx & 127;
            unsigned short h, l;
            split2(Bs[k][c], h, l);
            hi[(size_t)(c0 + c) * HID + k] = h;
            lo[(size_t)(c0 + c) * HID + k] = l;
        }
    } else if (mode == 2) {
        for (int idx = tid; idx < 128 * 128; idx += 256)
            Bs[idx >> 7][idx & 127] = Wpp[idx];
        for (int idx = tid; idx < 16 * 128; idx += 256)
            As[idx >> 7][idx & 127] = Wp[(size_t)(c0 + (idx >> 7)) * HID + (idx & 127)];
        __syncthreads();
        for (int it = 0; it < 8; ++it) {
            const int idx = tid + 256 * it;
            const int c = idx >> 7, k = idx & 127;
            float a = 0.f;
            #pragma unroll 4
            for (int j = 0; j < 128; ++j)
                a = fmaf(As[c][j], Bs[k][j], a);
            unsigned short h, l;
            split2(a, h, l);
            hi[(size_t)(c0 + c) * HID + k] = h;
            lo[(size_t)(c0 + c) * HID + k] = l;
        }
    } else {
        for (int idx = tid; idx < 128 * 128; idx += 256)
            Bs[idx >> 7][idx & 127] = phiw[idx];
        for (int idx = tid; idx < 16 * 128; idx += 256) {
            const int c = idx >> 7, j = idx & 127;
            As[c][j] = WA[(size_t)j * HID + c0 + c];
        }
        __syncthreads();
        for (int it = 0; it < 8; ++it) {
            const int idx = tid + 256 * it;
            const int c = idx >> 7, k = idx & 127;
            float a = 0.f;
            #pragma unroll 4
            for (int j = 0; j < 128; ++j)
                a = fmaf(As[c][j], Bs[k][j], a);
            unsigned short h, l;
            split2(a, h, l);
            hi[(size_t)(c0 + c) * HID + k] = h;
            lo[(size_t)(c0 + c) * HID + k] = l;
        }
        if (tid < 16) {
            float a = 0.f;
            #pragma unroll 4
            for (int j = 0; j < 128; ++j)
                a = fmaf(phib[j], As[tid][j], a);
            pbA[c0 + tid] = a;
        }
    }
}

// ---------------------------------------------------------------------------
// k_cast_count: merged launch. Blocks [0, nbCast) do HB=bf16(H) + psi;
// blocks [nbCast, nbCast+2*NC) do the CSR bucket histogram.
// ---------------------------------------------------------------------------
__global__ __launch_bounds__(256) void k_cast_count(
    const float* __restrict__ H, const float* __restrict__ fw,
    const float* __restrict__ fb,
    unsigned short* __restrict__ HB, float* __restrict__ psi,
    const int* __restrict__ etgt, const int* __restrict__ esrc,
    int* __restrict__ cnt_t, int* __restrict__ cnt_s,
    int nbCast, int NB, int NC, int E, int N)
{
    __shared__ int cnt[256];
    const int tid = threadIdx.x;
    const int bid = blockIdx.x;
    if (bid < nbCast) {
        const int row = bid * 16 + (tid >> 4), sub = tid & 15;
        if (row >= N) return;
        const size_t o = (size_t)row * HID + sub * 8;
        const f4 v0 = *(const f4*)&H[o];
        const f4 v1 = *(const f4*)&H[o + 4];
        ushort4 a, b;
        a.x = f2bf(v0[0]); a.y = f2bf(v0[1]); a.z = f2bf(v0[2]); a.w = f2bf(v0[3]);
        b.x = f2bf(v1[0]); b.y = f2bf(v1[1]); b.z = f2bf(v1[2]); b.w = f2bf(v1[3]);
        *(ushort4*)&HB[o] = a;
        *(ushort4*)&HB[o + 4] = b;
        const f4 w0 = *(const f4*)&fw[sub * 8];
        const f4 w1 = *(const f4*)&fw[sub * 8 + 4];
        float s = v0[0]*w0[0] + v0[1]*w0[1] + v0[2]*w0[2] + v0[3]*w0[3]
                + v1[0]*w1[0] + v1[1]*w1[1] + v1[2]*w1[2] + v1[3]*w1[3];
        #pragma unroll
        for (int mk = 1; mk < 16; mk <<= 1) s += __shfl_xor(s, mk);
        if (sub == 0) psi[row] = s + fb[0];
    } else {
        const int rem = bid - nbCast;
        const int which = rem / NC, blk = rem % NC;
        const int* __restrict__ key = which ? esrc : etgt;
        int* __restrict__ outc = which ? cnt_s : cnt_t;
        for (int i = tid; i < NB; i += 256) cnt[i] = 0;
        __syncthreads();
        const int e0 = blk * CSR_CHUNK;
        const int e1 = min(e0 + CSR_CHUNK, E);
        for (int e = e0 + tid; e < e1; e += 256)
            atomicAdd(&cnt[key[e] >> 8], 1);
        __syncthreads();
        for (int k = tid; k < NB; k += 256)
            outc[(size_t)k * NC + blk] = cnt[k];
    }
}

struct GemmArgsT {
    const unsigned short* Whi[2];
    const unsigned short* Wlo[2];
    void*                 O[2];
    int                   of32[2];
};

// ---------------------------------------------------------------------------
// MFMA GEMM: O[ph] = A @ B[ph], split-precision (hi/lo bf16, 3 MFMA).
// ---------------------------------------------------------------------------
__global__ __launch_bounds__(256, 2) void k_gemm(const float* __restrict__ A,
                                                 GemmArgsT g, int N)
{
    extern __shared__ unsigned short lds[];
    unsigned short* Ahi = lds;
    unsigned short* Alo = lds + 128 * KPAD;
    unsigned short* Bhi = lds + 2 * 128 * KPAD;
    unsigned short* Blo = lds + 3 * 128 * KPAD;
    const int tid  = threadIdx.x;
    const int row0 = blockIdx.x * 128;
    const int nrows = min(128, N - row0);
    const int ph   = blockIdx.y;
    const int w    = tid >> 6, lane = tid & 63;
    const int lrow = lane & 15, kgrp = lane >> 4;

    f32x4 acc[2][8];
    #pragma unroll
    for (int tc = 0; tc < 8; ++tc) {
        acc[0][tc] = f32x4{0.f, 0.f, 0.f, 0.f};
        acc[1][tc] = f32x4{0.f, 0.f, 0.f, 0.f};
    }

    const unsigned short* __restrict__ Wh = g.Whi[ph];
    const unsigned short* __restrict__ Wl = g.Wlo[ph];

    for (int ch = 0; ch < 2; ++ch) {
        __syncthreads();
        #pragma unroll
        for (int it = 0; it < 8; ++it) {
            const int idx = tid + 256 * it;
            const int r = idx >> 4, kq = (idx & 15) * 4;
            f4 v = {0.f, 0.f, 0.f, 0.f};
            if (r < nrows) v = *(const f4*)&A[(size_t)(row0 + r) * HID + ch * 64 + kq];
            ushort4 h, l;
            split2(v[0], h.x, l.x); split2(v[1], h.y, l.y);
            split2(v[2], h.z, l.z); split2(v[3], h.w, l.w);
            *(ushort4*)&Ahi[r * KPAD + kq] = h;
            *(ushort4*)&Alo[r * KPAD + kq] = l;
        }
        #pragma unroll
        for (int it = 0; it < 4; ++it) {
            const int idx = tid + 256 * it;
            const int c = idx >> 3, k8 = (idx & 7) * 8;
            *(uint4*)&Bhi[c * KPAD + k8] = *(const uint4*)&Wh[(size_t)c * HID + ch * 64 + k8];
            *(uint4*)&Blo[c * KPAD + k8] = *(const uint4*)&Wl[(size_t)c * HID + ch * 64 + k8];
        }
        __syncthreads();

        #pragma unroll
        for (int ks = 0; ks < 2; ++ks) {
            const int ko = ks * 32 + kgrp * 8;
            bf16x8 ah[2], al[2], bh[8], bl[8];
            #pragma unroll
            for (int tr = 0; tr < 2; ++tr) {
                const int rr = w * 32 + tr * 16 + lrow;
                ah[tr] = *(const bf16x8*)&Ahi[rr * KPAD + ko];
                al[tr] = *(const bf16x8*)&Alo[rr * KPAD + ko];
            }
            #pragma unroll
            for (int tc = 0; tc < 8; ++tc) {
                const int cc = tc * 16 + lrow;
                bh[tc] = *(const bf16x8*)&Bhi[cc * KPAD + ko];
                bl[tc] = *(const bf16x8*)&Blo[cc * KPAD + ko];
            }
            #pragma unroll
            for (int tr = 0; tr < 2; ++tr)
                #pragma unroll
                for (int tc = 0; tc < 8; ++tc) {
                    acc[tr][tc] = __builtin_amdgcn_mfma_f32_16x16x32_bf16(ah[tr], bh[tc], acc[tr][tc], 0, 0, 0);
                    acc[tr][tc] = __builtin_amdgcn_mfma_f32_16x16x32_bf16(al[tr], bh[tc], acc[tr][tc], 0, 0, 0);
                    acc[tr][tc] = __builtin_amdgcn_mfma_f32_16x16x32_bf16(ah[tr], bl[tc], acc[tr][tc], 0, 0, 0);
                }
        }
    }

    #pragma unroll
    for (int tr = 0; tr < 2; ++tr)
        #pragma unroll
        for (int j = 0; j < 4; ++j) {
            const int r = w * 32 + tr * 16 + kgrp * 4 + j;
            if (r < nrows) {
                if (g.of32[ph]) {
                    float* O = (float*)g.O[ph];
                    #pragma unroll
                    for (int tc = 0; tc < 8; ++tc)
                        O[(size_t)(row0 + r) * HID + tc * 16 + lrow] = acc[tr][tc][j];
                } else {
                    unsigned short* O = (unsigned short*)g.O[ph];
                    #pragma unroll
                    for (int tc = 0; tc < 8; ++tc)
                        O[(size_t)(row0 + r) * HID + tc * 16 + lrow] = f2bf(acc[tr][tc][j]);
                }
            }
        }
}

// ---------------------------------------------------------------------------
// k_final: out = LN(relu(agg@G + sig*pbA + H@Wself + s@Wstr + biases) + H)
// ---------------------------------------------------------------------------
__global__ __launch_bounds__(256, 2) void k_final(
    const float* __restrict__ Agg, const float* __restrict__ H,
    const float* __restrict__ sig, const float* __restrict__ pbA,
    const unsigned short* __restrict__ Ghi, const unsigned short* __restrict__ Glo,
    const unsigned short* __restrict__ WShi, const unsigned short* __restrict__ WSlo,
    const float* __restrict__ Wstr,
    const float* __restrict__ bself, const float* __restrict__ bA,
    const float* __restrict__ bstr,
    const float* __restrict__ lng, const float* __restrict__ lnb,
    float* __restrict__ out, int N)
{
    extern __shared__ unsigned short lds[];
    unsigned short* Ahi = lds;
    unsigned short* Alo = lds + 128 * KPAD;
    unsigned short* Bhi = lds + 2 * 128 * KPAD;
    unsigned short* Blo = lds + 3 * 128 * KPAD;
    const int tid  = threadIdx.x;
    const int row0 = blockIdx.x * 128;
    const int nrows = min(128, N - row0);
    const int w    = tid >> 6, lane = tid & 63;
    const int lrow = lane & 15, kgrp = lane >> 4;

    f32x4 acc[2][8];
    float gl[8], bl_[8], pb[8];
    #pragma unroll
    for (int tc = 0; tc < 8; ++tc) {
        const int c = tc * 16 + lrow;
        const float bv = bself[c] + bA[c] + bstr[c];
        acc[0][tc] = f32x4{bv, bv, bv, bv};
        acc[1][tc] = f32x4{bv, bv, bv, bv};
        gl[tc] = lng[c]; bl_[tc] = lnb[c]; pb[tc] = pbA[c];
    }

    for (int ph = 0; ph < 2; ++ph) {
        const float* __restrict__ Am = ph ? H : Agg;
        const unsigned short* __restrict__ Wh = ph ? WShi : Ghi;
        const unsigned short* __restrict__ Wl = ph ? WSlo : Glo;
        for (int ch = 0; ch < 2; ++ch) {
            __syncthreads();
            #pragma unroll
            for (int it = 0; it < 8; ++it) {
                const int idx = tid + 256 * it;
                const int r = idx >> 4, kq = (idx & 15) * 4;
                f4 v = {0.f, 0.f, 0.f, 0.f};
                if (r < nrows) v = *(const f4*)&Am[(size_t)(row0 + r) * HID + ch * 64 + kq];
                ushort4 h, l;
                split2(v[0], h.x, l.x); split2(v[1], h.y, l.y);
                split2(v[2], h.z, l.z); split2(v[3], h.w, l.w);
                *(ushort4*)&Ahi[r * KPAD + kq] = h;
                *(ushort4*)&Alo[r * KPAD + kq] = l;
            }
            #pragma unroll
            for (int it = 0; it < 4; ++it) {
                const int idx = tid + 256 * it;
                const int c = idx >> 3, k8 = (idx & 7) * 8;
                *(uint4*)&Bhi[c * KPAD + k8] = *(const uint4*)&Wh[(size_t)c * HID + ch * 64 + k8];
                *(uint4*)&Blo[c * KPAD + k8] = *(const uint4*)&Wl[(size_t)c * HID + ch * 64 + k8];
            }
            __syncthreads();

            #pragma unroll
            for (int ks = 0; ks < 2; ++ks) {
                const int ko = ks * 32 + kgrp * 8;
                bf16x8 ah[2], al[2], bh[8], bl[8];
                #pragma unroll
                for (int tr = 0; tr < 2; ++tr) {
                    const int rr = w * 32 + tr * 16 + lrow;
                    ah[tr] = *(const bf16x8*)&Ahi[rr * KPAD + ko];
                    al[tr] = *(const bf16x8*)&Alo[rr * KPAD + ko];
                }
                #pragma unroll
                for (int tc = 0; tc < 8; ++tc) {
                    const int cc = tc * 16 + lrow;
                    bh[tc] = *(const bf16x8*)&Bhi[cc * KPAD + ko];
                    bl[tc] = *(const bf16x8*)&Blo[cc * KPAD + ko];
                }
                #pragma unroll
                for (int tr = 0; tr < 2; ++tr)
                    #pragma unroll
                    for (int tc = 0; tc < 8; ++tc) {
                        acc[tr][tc] = __builtin_amdgcn_mfma_f32_16x16x32_bf16(ah[tr], bh[tc], acc[tr][tc], 0, 0, 0);
                        acc[tr][tc] = __builtin_amdgcn_mfma_f32_16x16x32_bf16(al[tr], bh[tc], acc[tr][tc], 0, 0, 0);
                        acc[tr][tc] = __builtin_amdgcn_mfma_f32_16x16x32_bf16(ah[tr], bl[tc], acc[tr][tc], 0, 0, 0);
                    }
            }

            if (ph == 1 && ch == 0) {
                #pragma unroll
                for (int tr = 0; tr < 2; ++tr)
                    #pragma unroll
                    for (int j = 0; j < 4; ++j) {
                        const int rr = w * 32 + tr * 16 + kgrp * 4 + j;
                        float s[NSTR];
                        #pragma unroll
                        for (int k = 0; k < NSTR; ++k)
                            s[k] = bf2f(Ahi[rr * KPAD + k]) + bf2f(Alo[rr * KPAD + k]);
                        #pragma unroll
                        for (int tc = 0; tc < 8; ++tc) {
                            float a = 0.f;
                            #pragma unroll
                            for (int k = 0; k < NSTR; ++k)
                                a = fmaf(s[k], Wstr[k * HID + tc * 16 + lrow], a);
                            acc[tr][tc][j] += a;
                        }
                    }
            }
        }
    }

    #pragma unroll
    for (int tr = 0; tr < 2; ++tr)
        #pragma unroll
        for (int j = 0; j < 4; ++j) {
            const int r = w * 32 + tr * 16 + kgrp * 4 + j;
            const bool valid = r < nrows;
            const size_t rb = (size_t)(row0 + r) * HID;
            const float sg = valid ? sig[row0 + r] : 0.f;
            float v[8], s1 = 0.f, s2 = 0.f;
            #pragma unroll
            for (int tc = 0; tc < 8; ++tc) {
                float x = fmaxf(acc[tr][tc][j] + sg * pb[tc], 0.f);
                if (valid) x += H[rb + tc * 16 + lrow];
                v[tc] = x;
                s1 += x; s2 += x * x;
            }
            #pragma unroll
            for (int mk = 1; mk < 16; mk <<= 1) {
                s1 += __shfl_xor(s1, mk);
                s2 += __shfl_xor(s2, mk);
            }
            const float mean = s1 * (1.f / HID);
            const float var  = s2 * (1.f / HID) - mean * mean;
            const float rs   = rsqrtf(var + LN_EPS);
            if (valid) {
                #pragma unroll
                for (int tc = 0; tc < 8; ++tc)
                    out[rb + tc * 16 + lrow] = (v[tc] - mean) * rs * gl[tc] + bl_[tc];
            }
        }
}

// ---------------------------------------------------------------------------
// CSR build (scan / bucket / final) — ZERO global atomics.
// ---------------------------------------------------------------------------
__global__ __launch_bounds__(1024) void k_csr_scan(
    const int* __restrict__ cnt_t, int* __restrict__ off_t,
    const int* __restrict__ cnt_s, int* __restrict__ off_s, int L)
{
    const int* __restrict__ cnt = blockIdx.x ? cnt_s : cnt_t;
    int* __restrict__ off = blockIdx.x ? off_s : off_t;
    __shared__ int warp_sums[16];
    __shared__ int carry_s;
    const int tid = threadIdx.x, lane = tid & 63, wid = tid >> 6;
    if (tid == 0) carry_s = 0;
    __syncthreads();
    for (int i0 = 0; i0 < L; i0 += 1024) {
        const int i = i0 + tid;
        const int v = (i < L) ? cnt[i] : 0;
        int x = v;
        #pragma unroll
        for (int d = 1; d < 64; d <<= 1) {
            const int y = __shfl_up(x, d);
            if (lane >= d) x += y;
        }
        if (lane == 63) warp_sums[wid] = x;
        __syncthreads();
        if (wid == 0) {
            int ws = (lane < 16) ? warp_sums[lane] : 0;
            #pragma unroll
            for (int d = 1; d < 16; d <<= 1) {
                const int y = __shfl_up(ws, d);
                if (lane >= d) ws += y;
            }
            if (lane < 16) warp_sums[lane] = ws;
        }
        __syncthreads();
        const int carry = carry_s;
        if (i < L) off[i] = carry + (wid ? warp_sums[wid - 1] : 0) + x - v;
        __syncthreads();
        if (tid == 1023) carry_s = carry + warp_sums[15];
        __syncthreads();
    }
    if (tid == 0) off[L] = carry_s;
}

__global__ __launch_bounds__(256) void k_csr_bucket(
    const int* __restrict__ etgt, const int* __restrict__ esrc,
    const int* __restrict__ off_t, const int* __restrict__ off_s,
    int* __restrict__ ebuck_t, int* __restrict__ ebuck_s,
    int NB, int NC, int E)
{
    __shared__ int cur[256];
    const int which = blockIdx.y;
    const int* __restrict__ key = which ? esrc : etgt;
    const int* __restrict__ off = which ? off_s : off_t;
    int* __restrict__ ebuck = which ? ebuck_s : ebuck_t;
    const int tid = threadIdx.x;
    for (int k = tid; k < NB; k += 256)
        cur[k] = off[(size_t)k * NC + blockIdx.x];
    __syncthreads();
    const int e0 = blockIdx.x * CSR_CHUNK;
    const int e1 = min(e0 + CSR_CHUNK, E);
    for (int e = e0 + tid; e < e1; e += 256) {
        const int p = atomicAdd(&cur[key[e] >> 8], 1);
        ebuck[p] = e;
    }
}

__global__ __launch_bounds__(256) void k_csr_final(
    const int* __restrict__ etgt, const int* __restrict__ esrc,
    const int* __restrict__ off_t, const int* __restrict__ off_s,
    const int* __restrict__ ebuck_t, const int* __restrict__ ebuck_s,
    int* __restrict__ base_t, int* __restrict__ base_s,
    int* __restrict__ eid_t, int* __restrict__ eid_s,
    int* __restrict__ src_t, int* __restrict__ tgt_s,
    int NB, int NC, int N, int E)
{
    __shared__ int cnt[256], excl[256], wsum[4];
    const int which = blockIdx.y;
    const int* __restrict__ key   = which ? esrc : etgt;
    const int* __restrict__ oth   = which ? etgt : esrc;
    const int* __restrict__ off   = which ? off_s : off_t;
    const int* __restrict__ ebuck = which ? ebuck_s : ebuck_t;
    int* __restrict__ base = which ? base_s : base_t;
    int* __restrict__ eid  = which ? eid_s : eid_t;
    int* __restrict__ aux  = which ? tgt_s : src_t;
    const int tid = threadIdx.x, lane = tid & 63, wv = tid >> 6;
    const int k = blockIdx.x;
    const int segb = off[(size_t)k * NC];
    const int sege = (k + 1 < NB) ? off[(size_t)(k + 1) * NC] : E;
    cnt[tid] = 0;
    __syncthreads();
    for (int i = segb + tid; i < sege; i += 256)
        atomicAdd(&cnt[key[ebuck[i]] & 255], 1);
    __syncthreads();
    {
        const int orig = cnt[tid];
        int x = orig;
        #pragma unroll
        for (int d = 1; d < 64; d <<= 1) {
            const int y = __shfl_up(x, d);
            if (lane >= d) x += y;
        }
        if (lane == 63) wsum[wv] = x;
        __syncthreads();
        if (tid == 0) {
            int a = 0;
            #pragma unroll
            for (int i = 0; i < 4; ++i) { const int t = wsum[i]; wsum[i] = a; a += t; }
        }
        __syncthreads();
        excl[tid] = x - orig + wsum[wv];
    }
    __syncthreads();
    const int node = k * 256 + tid;
    if (node < N) base[node] = segb + excl[tid];
    if (k == NB - 1 && tid == 0) base[N] = E;
    cnt[tid] = excl[tid];
    __syncthreads();
    for (int i = segb + tid; i < sege; i += 256) {
        const int e = ebuck[i];
        const int r = atomicAdd(&cnt[key[e] & 255], 1);
        eid[segb + r] = e;
        aux[segb + r] = oth[e];
    }
}

// ---------------------------------------------------------------------------
// k_score: wave per TARGET, 16-lane groups, src from contiguous src_t
// (2-deep chain: contig load -> gather), index prefetch.
// ---------------------------------------------------------------------------
__global__ __launch_bounds__(256) void k_score(
    const int* __restrict__ eid_t, const int* __restrict__ base_t,
    const int* __restrict__ src_t,
    const float* __restrict__ Wt, const unsigned short* __restrict__ UB,
    const unsigned short* __restrict__ HB,
    float* __restrict__ score, float* __restrict__ pairv,
    float* __restrict__ sumt_inv, int N)
{
    const int lane = threadIdx.x & 63, wv = threadIdx.x >> 6;
    const int t = blockIdx.x * 4 + wv;
    if (t >= N) return;
    const int b0 = base_t[t], deg = base_t[t + 1] - b0;
    if (deg == 0) { if (lane == 0) sumt_inv[t] = 0.f; return; }
    const int sub = lane & 15, grp = lane >> 4;
    const size_t to = (size_t)t * HID;

    float wt[8], u[8], htg[8];
    {
        const f4 w0 = *(const f4*)&Wt[to + sub * 8];
        const f4 w1 = *(const f4*)&Wt[to + sub * 8 + 4];
        wt[0] = w0[0]; wt[1] = w0[1]; wt[2] = w0[2]; wt[3] = w0[3];
        wt[4] = w1[0]; wt[5] = w1[1]; wt[6] = w1[2]; wt[7] = w1[3];
        unpack8(*(const uint4*)&UB[to + sub * 8], u);
        unpack8(*(const uint4*)&HB[to + sub * 8], htg);
    }

    bool valN = grp < deg;
    int eidN = 0, srcN = 0;
    if (valN) { eidN = eid_t[b0 + grp]; srcN = src_t[b0 + grp]; }

    for (int j0 = 0; j0 < deg; j0 += 4) {
        const bool val = valN;
        const int eid = eidN, src = srcN;
        const uint4 raw = *(const uint4*)&HB[(size_t)src * HID + sub * 8];
        const int jn = j0 + 4 + grp;
        valN = jn < deg;
        eidN = 0; srcN = 0;
        if (valN) { eidN = eid_t[b0 + jn]; srcN = src_t[b0 + jn]; }

        float hs[8];
        unpack8(raw, hs);
        float ps = 0.f, pp = 0.f;
        #pragma unroll
        for (int d = 0; d < 8; ++d) {
            ps = fmaf(wt[d], hs[d], ps);
            pp = fmaf(u[d], hs[d], pp);
        }
        if (sub == 0) {
            #pragma unroll
            for (int d = 0; d < NSTR; ++d) ps = fmaf(htg[d], hs[d], ps);
        }
        #pragma unroll
        for (int mk = 1; mk < 16; mk <<= 1) {
            ps += __shfl_xor(ps, mk);
            pp += __shfl_xor(pp, mk);
        }
        if (sub == 0 && val) {
            score[b0 + j0 + grp] = ps;
            pairv[eid] = pp;
        }
    }

    float m = -1e30f;
    for (int i = lane; i < deg; i += 64) m = fmaxf(m, score[b0 + i]);
    #pragma unroll
    for (int mk = 1; mk < 64; mk <<= 1) m = fmaxf(m, __shfl_xor(m, mk));
    float psum = 0.f;
    for (int i = lane; i < deg; i += 64) {
        const float e = expf(score[b0 + i] - m);
        score[b0 + i] = e;
        psum += e;
    }
    #pragma unroll
    for (int mk = 1; mk < 64; mk <<= 1) psum += __shfl_xor(psum, mk);
    if (lane == 0) sumt_inv[t] = 1.f / psum;
}

// ---------------------------------------------------------------------------
// k_beta2: wave per SOURCE node, streaming; fuses rho.
// Fast path for deg<=64: single gather pass, values cached in registers.
// ---------------------------------------------------------------------------
__global__ __launch_bounds__(256) void k_beta2(
    const int* __restrict__ base_s, const int* __restrict__ eid_s,
    const int* __restrict__ tgt_s,
    const float* __restrict__ pairv, const float* __restrict__ psi,
    float* __restrict__ rho1m, int N)
{
    const int lane = threadIdx.x & 63, wv = threadIdx.x >> 6;
    const int s = blockIdx.x * 4 + wv;
    if (s >= N) return;
    const int b0 = base_s[s], deg = base_s[s + 1] - b0;

    float se = 0.f, sn = 0.f;
    if (deg <= 64) {
        const bool v = lane < deg;
        float pv = -1e30f;
        int tg = 0;
        if (v) { pv = pairv[eid_s[b0 + lane]]; tg = tgt_s[b0 + lane]; }
        float m = pv;
        #pragma unroll
        for (int mk = 1; mk < 64; mk <<= 1) m = fmaxf(m, __shfl_xor(m, mk));
        const float ex = v ? expf(pv - m) : 0.f;
        se = ex;
        sn = v ? ex * expf(-psi[tg]) : 0.f;
    } else {
        float m = -1e30f;
        for (int i = lane; i < deg; i += 64) m = fmaxf(m, pairv[eid_s[b0 + i]]);
        #pragma unroll
        for (int mk = 1; mk < 64; mk <<= 1) m = fmaxf(m, __shfl_xor(m, mk));
        for (int i = lane; i < deg; i += 64) {
            const float ex = expf(pairv[eid_s[b0 + i]] - m);
            se += ex;
            sn += ex * expf(-psi[tgt_s[b0 + i]]);
        }
    }
    #pragma unroll
    for (int mk = 1; mk < 64; mk <<= 1) {
        se += __shfl_xor(se, mk);
        sn += __shfl_xor(sn, mk);
    }
    if (lane == 0) {
        const float st = (deg > 0 && se > 0.f) ? sn / se : 0.f;
        const float d  = -logf(st + 1e-8f);
        rho1m[s] = 1.f - 1.f / (1.f + expf(-(GAMMA * (d - DELTA))));
    }
}

// ---------------------------------------------------------------------------
// k_matt: wave per TARGET, 8 edges in flight + index/coef prefetch;
// src from contiguous src_t; gathers HB (warm from k_score).
// ---------------------------------------------------------------------------
__global__ __launch_bounds__(256) void k_matt(
    const int* __restrict__ src_t, const int* __restrict__ base_t,
    const float* __restrict__ score, const float* __restrict__ sumt_inv,
    const float* __restrict__ rho1m,
    const unsigned short* __restrict__ HB,
    float* __restrict__ agg, float* __restrict__ sig, int N)
{
    const int lane = threadIdx.x & 63, wv = threadIdx.x >> 6;
    const int t = blockIdx.x * 4 + wv;
    if (t >= N) return;
    const int b0 = base_t[t], deg = base_t[t + 1] - b0;
    const int sub = lane & 15, grp = lane >> 4;
    const size_t to = (size_t)t * HID;

    float acc[8];
    #pragma unroll
    for (int d = 0; d < 8; ++d) acc[d] = 0.f;
    float csum = 0.f;
    const float inv = (deg > 0) ? sumt_inv[t] : 0.f;

    // prologue: prefetch first pair's contiguous indices/coefs
    bool vA = grp < deg, vB = 4 + grp < deg;
    int sA = 0, sB = 0;
    float scA = 0.f, scB = 0.f;
    if (vA) { sA = src_t[b0 + grp];     scA = score[b0 + grp]; }
    if (vB) { sB = src_t[b0 + 4 + grp]; scB = score[b0 + 4 + grp]; }

    for (int j0 = 0; j0 < deg; j0 += 8) {
        const bool cvA = vA, cvB = vB;
        const int csA = sA, csB = sB;
        const float cscA = scA, cscB = scB;
        // issue current gathers (rho + HB rows) ASAP
        const float rhoA = cvA ? rho1m[csA] : 0.f;
        const float rhoB = cvB ? rho1m[csB] : 0.f;
        const uint4 rA = *(const uint4*)&HB[(size_t)csA * HID + sub * 8];
        const uint4 rB = *(const uint4*)&HB[(size_t)csB * HID + sub * 8];
        // prefetch next iteration's contiguous loads
        const int jA = j0 + 8 + grp, jB = j0 + 12 + grp;
        vA = jA < deg; vB = jB < deg;
        sA = sB = 0; scA = scB = 0.f;
        if (vA) { sA = src_t[b0 + jA]; scA = score[b0 + jA]; }
        if (vB) { sB = src_t[b0 + jB]; scB = score[b0 + jB]; }

        const float cA = cvA ? cscA * inv * rhoA : 0.f;
        const float cB = cvB ? cscB * inv * rhoB : 0.f;
        float hA[8], hB[8];
        unpack8(rA, hA); unpack8(rB, hB);
        #pragma unroll
        for (int d = 0; d < 8; ++d) {
            acc[d] = fmaf(cA, hA[d], acc[d]);
            acc[d] = fmaf(cB, hB[d], acc[d]);
        }
        if (sub == 0) csum += cA + cB;
    }
    #pragma unroll
    for (int d = 0; d < 8; ++d) {
        acc[d] += __shfl_xor(acc[d], 16);
        acc[d] += __shfl_xor(acc[d], 32);
    }
    csum += __shfl_xor(csum, 16);
    csum += __shfl_xor(csum, 32);
    if (grp == 0) {
        f4 o0, o1;
        #pragma unroll
        for (int d = 0; d < 4; ++d) { o0[d] = acc[d]; o1[d] = acc[d + 4]; }
        *(f4*)&agg[to + sub * 8]     = o0;
        *(f4*)&agg[to + sub * 8 + 4] = o1;
        if (sub == 0) sig[t] = csum;
    }
}

extern "C" void kernel_launch(void* const* d_in, const int* in_sizes, int n_in,
                              void* d_out, int out_size, void* d_ws, size_t ws_size,
                              hipStream_t stream)
{
    const int*   eidx   = (const int*)  d_in[0];
    const float* H      = (const float*)d_in[1];
    const float* W_att  = (const float*)d_in[2];
    const float* phi_w  = (const float*)d_in[3];
    const float* phi_b  = (const float*)d_in[4];
    const float* W_p    = (const float*)d_in[5];
    const float* W_pp   = (const float*)d_in[6];
    const float* fdef_w = (const float*)d_in[7];
    const float* fdef_b = (const float*)d_in[8];
    const float* Wself  = (const float*)d_in[9];
    const float* bself  = (const float*)d_in[10];
    const float* WA     = (const float*)d_in[11];
    const float* bA     = (const float*)d_in[12];
    const float* Wstr   = (const float*)d_in[13];
    const float* bstr   = (const float*)d_in[14];
    const float* lng    = (const float*)d_in[15];
    const float* lnb    = (const float*)d_in[16];
    float* out = (float*)d_out;

    const int E = in_sizes[0] / 2;
    const int N = in_sizes[1] / HID;
    const int* esrc = eidx;
    const int* etgt = eidx + E;

    const int NB = (N + 255) >> 8;
    const int NC = (E + CSR_CHUNK - 1) / CSR_CHUNK;
    const int L  = NB * NC;

    // ---- workspace layout (~79 MB) ----
    char* w = (char*)d_ws;
    const size_t NHb  = (size_t)N * HID * sizeof(unsigned short);
    const size_t NH   = (size_t)N * HID * sizeof(float);
    const size_t Epad = (((size_t)E * sizeof(float)) + 255) & ~255ull;
    const size_t Npad = (((size_t)(N + 1) * sizeof(float)) + 255) & ~255ull;
    const size_t Lpad = (((size_t)(L + 1) * sizeof(int)) + 255) & ~255ull;

    float*          Wt    = (float*)w;          w += NH;   // agg aliases after k_score
    unsigned short* UB    = (unsigned short*)w; w += NHb;
    unsigned short* HB    = (unsigned short*)w; w += NHb;
    float* score   = (float*)w; w += Epad;  // CSR-tgt order
    float* pairv   = (float*)w; w += Epad;  // edge-id order
    int*   eid_t   = (int*)  w; w += Epad;
    int*   eid_s   = (int*)  w; w += Epad;
    int*   src_t   = (int*)  w; w += Epad;  // CSR-tgt companion src
    int*   tgt_s   = (int*)  w; w += Epad;  // CSR-src companion tgt
    int*   ebuck_t = (int*)  w; w += Epad;
    int*   ebuck_s = (int*)  w; w += Epad;
    int*   cnt_t = (int*)w; w += Lpad;
    int*   off_t = (int*)w; w += Lpad;
    int*   cnt_s = (int*)w; w += Lpad;
    int*   off_s = (int*)w; w += Lpad;
    int*   base_t   = (int*)  w; w += Npad;   // N+1
    int*   base_s   = (int*)  w; w += Npad;   // N+1
    float* sumt_inv = (float*)w; w += Npad;
    float* psi      = (float*)w; w += Npad;
    float* rho1m    = (float*)w; w += Npad;
    float* sig      = (float*)w; w += Npad;
    float* pbA      = (float*)w; w += 512;   // 128 floats
    unsigned short* WT = (unsigned short*)w;  // 4 slots x 2 planes x 128x128
    w += 4 * 2 * HID * HID * sizeof(unsigned short);
    float* agg = Wt;   // alias: Wt dead after k_score

    const int nblk128 = (N + 127) / 128;
    const int nblkN4  = (N + 3) / 4;
    const int nbCast  = (N + 15) / 16;
    const size_t lds_mfma = 4 * 128 * KPAD * sizeof(unsigned short);  // 72 KB
    const size_t MSZ = (size_t)2 * HID * HID;

    // slots: 0 = W_att(nat), 1 = Wself(T), 2 = M2, 3 = G  — one launch
    k_prep_all<<<dim3(8, 4), 256, 0, stream>>>(W_att, Wself, W_p, W_pp,
                                               phi_w, WA, phi_b, WT, pbA);

    // HB/psi + CSR histogram in one launch
    k_cast_count<<<nbCast + 2 * NC, 256, 0, stream>>>(H, fdef_w, fdef_b, HB, psi,
                                                      etgt, esrc, cnt_t, cnt_s,
                                                      nbCast, NB, NC, E, N);

    GemmArgsT g2;
    g2.Whi[0] = WT;           g2.Wlo[0] = WT + HID * HID;             // W_att
    g2.Whi[1] = WT + 2 * MSZ; g2.Wlo[1] = WT + 2 * MSZ + HID * HID;   // M2
    g2.O[0] = Wt;  g2.of32[0] = 1;
    g2.O[1] = UB;  g2.of32[1] = 0;
    k_gemm<<<dim3(nblk128, 2), 256, lds_mfma, stream>>>(H, g2, N);

    // ---- CSR build (no global atomics) ----
    k_csr_scan<<<2, 1024, 0, stream>>>(cnt_t, off_t, cnt_s, off_s, L);
    k_csr_bucket<<<dim3(NC, 2), 256, 0, stream>>>(etgt, esrc, off_t, off_s,
                                                  ebuck_t, ebuck_s, NB, NC, E);
    k_csr_final<<<dim3(NB, 2), 256, 0, stream>>>(etgt, esrc, off_t, off_s,
                                                 ebuck_t, ebuck_s, base_t, base_s,
                                                 eid_t, eid_s, src_t, tgt_s,
                                                 NB, NC, N, E);

    k_score<<<nblkN4, 256, 0, stream>>>(eid_t, base_t, src_t, Wt, UB, HB,
                                        score, pairv, sumt_inv, N);
    k_beta2<<<nblkN4, 256, 0, stream>>>(base_s, eid_s, tgt_s, pairv, psi, rho1m, N);

    k_matt<<<nblkN4, 256, 0, stream>>>(src_t, base_t, score, sumt_inv,
                                       rho1m, HB, agg, sig, N);

    k_final<<<nblk128, 256, lds_mfma, stream>>>(agg, H, sig, pbA,
                                                WT + 3 * MSZ, WT + 3 * MSZ + HID * HID,
                                                WT + 1 * MSZ, WT + 1 * MSZ + HID * HID,
                                                Wstr, bself, bA, bstr, lng, lnb, out, N);
}

// Round 17
// 273.393 us; speedup vs baseline: 1.7358x; 1.0754x over previous
//
#include <hip/hip_runtime.h>
#include <math.h>

#define HID 128
#define NSTR 6              // STRUCT-1
#define GAMMA 1.0f
#define DELTA 0.5f
#define LN_EPS 1e-5f
#define KPAD 72             // bf16 elems per LDS row (64 + 8 pad)
#define CSR_CHUNK 8192      // edges per block in CSR build

typedef __attribute__((ext_vector_type(4))) float f4;
typedef __attribute__((ext_vector_type(8))) short bf16x8;
typedef __attribute__((ext_vector_type(4))) float f32x4;

// f32 -> bf16 (round-to-nearest-even) and helpers
__device__ __forceinline__ unsigned short f2bf(float f) {
    unsigned u = __float_as_uint(f);
    unsigned r = u + 0x7FFFu + ((u >> 16) & 1u);
    return (unsigned short)(r >> 16);
}
__device__ __forceinline__ float bf2f(unsigned short h) {
    return __uint_as_float((unsigned)h << 16);
}
__device__ __forceinline__ void split2(float v, unsigned short& h, unsigned short& l) {
    h = f2bf(v);
    l = f2bf(v - bf2f(h));
}
__device__ __forceinline__ void bf2f2(unsigned u, float& lo, float& hi) {
    lo = __uint_as_float(u << 16);
    hi = __uint_as_float(u & 0xFFFF0000u);
}
__device__ __forceinline__ void unpack8(const uint4 u, float* f) {
    bf2f2(u.x, f[0], f[1]); bf2f2(u.y, f[2], f[3]);
    bf2f2(u.z, f[4], f[5]); bf2f2(u.w, f[6], f[7]);
}

// ---------------------------------------------------------------------------
// k_prep_all: all weight-table prep in ONE launch, grid (8, 4).
// mode 0: slot0 = W_att natural; mode 1: slot1 = Wself^T;
// mode 2: slot2 = M2 = W_p @ W_pp^T; mode 3: slot3 = G (+ pbA).
// ---------------------------------------------------------------------------
__global__ __launch_bounds__(256) void k_prep_all(
    const float* __restrict__ W_att, const float* __restrict__ Wself,
    const float* __restrict__ Wp,    const float* __restrict__ Wpp,
    const float* __restrict__ phiw,  const float* __restrict__ WA,
    const float* __restrict__ phib,
    unsigned short* __restrict__ WT, float* __restrict__ pbA)
{
    __shared__ float Bs[128][129];
    __shared__ float As[16][129];
    const int mode = blockIdx.y, c0 = blockIdx.x * 16;
    const int tid = threadIdx.x;
    const size_t MSZ = (size_t)2 * HID * HID;
    unsigned short* hi = WT + (size_t)mode * MSZ;
    unsigned short* lo = hi + HID * HID;

    if (mode == 0) {
        for (int idx = tid; idx < 2048; idx += 256) {
            const int c = idx >> 7, k = idx & 127;
            unsigned short h, l;
            split2(W_att[(size_t)(c0 + c) * HID + k], h, l);
            hi[(size_t)(c0 + c) * HID + k] = h;
            lo[(size_t)(c0 + c) * HID + k] = l;
        }
    } else if (mode == 1) {
        for (int idx = tid; idx < 2048; idx += 256) {
            const int k = idx >> 4, c = idx & 15;
            Bs[k][c] = Wself[k * HID + c0 + c];
        }
        __syncthreads();
        for (int idx = tid; idx < 2048; idx += 256) {
            const int c = idx >> 7, k = idx & 127;
            unsigned short h, l;
            split2(Bs[k][c], h, l);
            hi[(size_t)(c0 + c) * HID + k] = h;
            lo[(size_t)(c0 + c) * HID + k] = l;
        }
    } else if (mode == 2) {
        for (int idx = tid; idx < 128 * 128; idx += 256)
            Bs[idx >> 7][idx & 127] = Wpp[idx];
        for (int idx = tid; idx < 16 * 128; idx += 256)
            As[idx >> 7][idx & 127] = Wp[(size_t)(c0 + (idx >> 7)) * HID + (idx & 127)];
        __syncthreads();
        for (int it = 0; it < 8; ++it) {
            const int idx = tid + 256 * it;
            const int c = idx >> 7, k = idx & 127;
            float a = 0.f;
            #pragma unroll 4
            for (int j = 0; j < 128; ++j)
                a = fmaf(As[c][j], Bs[k][j], a);
            unsigned short h, l;
            split2(a, h, l);
            hi[(size_t)(c0 + c) * HID + k] = h;
            lo[(size_t)(c0 + c) * HID + k] = l;
        }
    } else {
        for (int idx = tid; idx < 128 * 128; idx += 256)
            Bs[idx >> 7][idx & 127] = phiw[idx];
        for (int idx = tid; idx < 16 * 128; idx += 256) {
            const int c = idx >> 7, j = idx & 127;
            As[c][j] = WA[(size_t)j * HID + c0 + c];
        }
        __syncthreads();
        for (int it = 0; it < 8; ++it) {
            const int idx = tid + 256 * it;
            const int c = idx >> 7, k = idx & 127;
            float a = 0.f;
            #pragma unroll 4
            for (int j = 0; j < 128; ++j)
                a = fmaf(As[c][j], Bs[k][j], a);
            unsigned short h, l;
            split2(a, h, l);
            hi[(size_t)(c0 + c) * HID + k] = h;
            lo[(size_t)(c0 + c) * HID + k] = l;
        }
        if (tid < 16) {
            float a = 0.f;
            #pragma unroll 4
            for (int j = 0; j < 128; ++j)
                a = fmaf(phib[j], As[tid][j], a);
            pbA[c0 + tid] = a;
        }
    }
}

// ---------------------------------------------------------------------------
// k_cast_count: merged launch. Blocks [0, nbCast) do HB=bf16(H) + psi;
// blocks [nbCast, nbCast+2*NC) do the CSR bucket histogram.
// ---------------------------------------------------------------------------
__global__ __launch_bounds__(256) void k_cast_count(
    const float* __restrict__ H, const float* __restrict__ fw,
    const float* __restrict__ fb,
    unsigned short* __restrict__ HB, float* __restrict__ psi,
    const int* __restrict__ etgt, const int* __restrict__ esrc,
    int* __restrict__ cnt_t, int* __restrict__ cnt_s,
    int nbCast, int NB, int NC, int E, int N)
{
    __shared__ int cnt[256];
    const int tid = threadIdx.x;
    const int bid = blockIdx.x;
    if (bid < nbCast) {
        const int row = bid * 16 + (tid >> 4), sub = tid & 15;
        if (row >= N) return;
        const size_t o = (size_t)row * HID + sub * 8;
        const f4 v0 = *(const f4*)&H[o];
        const f4 v1 = *(const f4*)&H[o + 4];
        ushort4 a, b;
        a.x = f2bf(v0[0]); a.y = f2bf(v0[1]); a.z = f2bf(v0[2]); a.w = f2bf(v0[3]);
        b.x = f2bf(v1[0]); b.y = f2bf(v1[1]); b.z = f2bf(v1[2]); b.w = f2bf(v1[3]);
        *(ushort4*)&HB[o] = a;
        *(ushort4*)&HB[o + 4] = b;
        const f4 w0 = *(const f4*)&fw[sub * 8];
        const f4 w1 = *(const f4*)&fw[sub * 8 + 4];
        float s = v0[0]*w0[0] + v0[1]*w0[1] + v0[2]*w0[2] + v0[3]*w0[3]
                + v1[0]*w1[0] + v1[1]*w1[1] + v1[2]*w1[2] + v1[3]*w1[3];
        #pragma unroll
        for (int mk = 1; mk < 16; mk <<= 1) s += __shfl_xor(s, mk);
        if (sub == 0) psi[row] = s + fb[0];
    } else {
        const int rem = bid - nbCast;
        const int which = rem / NC, blk = rem % NC;
        const int* __restrict__ key = which ? esrc : etgt;
        int* __restrict__ outc = which ? cnt_s : cnt_t;
        for (int i = tid; i < NB; i += 256) cnt[i] = 0;
        __syncthreads();
        const int e0 = blk * CSR_CHUNK;
        const int e1 = min(e0 + CSR_CHUNK, E);
        for (int e = e0 + tid; e < e1; e += 256)
            atomicAdd(&cnt[key[e] >> 8], 1);
        __syncthreads();
        for (int k = tid; k < NB; k += 256)
            outc[(size_t)k * NC + blk] = cnt[k];
    }
}

struct GemmArgsT {
    const unsigned short* Whi[2];
    const unsigned short* Wlo[2];
    void*                 O[2];
    int                   of32[2];
};

// ---------------------------------------------------------------------------
// MFMA GEMM: O[ph] = A @ B[ph], split-precision (hi/lo bf16, 3 MFMA).
// ---------------------------------------------------------------------------
__global__ __launch_bounds__(256, 2) void k_gemm(const float* __restrict__ A,
                                                 GemmArgsT g, int N)
{
    extern __shared__ unsigned short lds[];
    unsigned short* Ahi = lds;
    unsigned short* Alo = lds + 128 * KPAD;
    unsigned short* Bhi = lds + 2 * 128 * KPAD;
    unsigned short* Blo = lds + 3 * 128 * KPAD;
    const int tid  = threadIdx.x;
    const int row0 = blockIdx.x * 128;
    const int nrows = min(128, N - row0);
    const int ph   = blockIdx.y;
    const int w    = tid >> 6, lane = tid & 63;
    const int lrow = lane & 15, kgrp = lane >> 4;

    f32x4 acc[2][8];
    #pragma unroll
    for (int tc = 0; tc < 8; ++tc) {
        acc[0][tc] = f32x4{0.f, 0.f, 0.f, 0.f};
        acc[1][tc] = f32x4{0.f, 0.f, 0.f, 0.f};
    }

    const unsigned short* __restrict__ Wh = g.Whi[ph];
    const unsigned short* __restrict__ Wl = g.Wlo[ph];

    for (int ch = 0; ch < 2; ++ch) {
        __syncthreads();
        #pragma unroll
        for (int it = 0; it < 8; ++it) {
            const int idx = tid + 256 * it;
            const int r = idx >> 4, kq = (idx & 15) * 4;
            f4 v = {0.f, 0.f, 0.f, 0.f};
            if (r < nrows) v = *(const f4*)&A[(size_t)(row0 + r) * HID + ch * 64 + kq];
            ushort4 h, l;
            split2(v[0], h.x, l.x); split2(v[1], h.y, l.y);
            split2(v[2], h.z, l.z); split2(v[3], h.w, l.w);
            *(ushort4*)&Ahi[r * KPAD + kq] = h;
            *(ushort4*)&Alo[r * KPAD + kq] = l;
        }
        #pragma unroll
        for (int it = 0; it < 4; ++it) {
            const int idx = tid + 256 * it;
            const int c = idx >> 3, k8 = (idx & 7) * 8;
            *(uint4*)&Bhi[c * KPAD + k8] = *(const uint4*)&Wh[(size_t)c * HID + ch * 64 + k8];
            *(uint4*)&Blo[c * KPAD + k8] = *(const uint4*)&Wl[(size_t)c * HID + ch * 64 + k8];
        }
        __syncthreads();

        #pragma unroll
        for (int ks = 0; ks < 2; ++ks) {
            const int ko = ks * 32 + kgrp * 8;
            bf16x8 ah[2], al[2], bh[8], bl[8];
            #pragma unroll
            for (int tr = 0; tr < 2; ++tr) {
                const int rr = w * 32 + tr * 16 + lrow;
                ah[tr] = *(const bf16x8*)&Ahi[rr * KPAD + ko];
                al[tr] = *(const bf16x8*)&Alo[rr * KPAD + ko];
            }
            #pragma unroll
            for (int tc = 0; tc < 8; ++tc) {
                const int cc = tc * 16 + lrow;
                bh[tc] = *(const bf16x8*)&Bhi[cc * KPAD + ko];
                bl[tc] = *(const bf16x8*)&Blo[cc * KPAD + ko];
            }
            #pragma unroll
            for (int tr = 0; tr < 2; ++tr)
                #pragma unroll
                for (int tc = 0; tc < 8; ++tc) {
                    acc[tr][tc] = __builtin_amdgcn_mfma_f32_16x16x32_bf16(ah[tr], bh[tc], acc[tr][tc], 0, 0, 0);
                    acc[tr][tc] = __builtin_amdgcn_mfma_f32_16x16x32_bf16(al[tr], bh[tc], acc[tr][tc], 0, 0, 0);
                    acc[tr][tc] = __builtin_amdgcn_mfma_f32_16x16x32_bf16(ah[tr], bl[tc], acc[tr][tc], 0, 0, 0);
                }
        }
    }

    #pragma unroll
    for (int tr = 0; tr < 2; ++tr)
        #pragma unroll
        for (int j = 0; j < 4; ++j) {
            const int r = w * 32 + tr * 16 + kgrp * 4 + j;
            if (r < nrows) {
                if (g.of32[ph]) {
                    float* O = (float*)g.O[ph];
                    #pragma unroll
                    for (int tc = 0; tc < 8; ++tc)
                        O[(size_t)(row0 + r) * HID + tc * 16 + lrow] = acc[tr][tc][j];
                } else {
                    unsigned short* O = (unsigned short*)g.O[ph];
                    #pragma unroll
                    for (int tc = 0; tc < 8; ++tc)
                        O[(size_t)(row0 + r) * HID + tc * 16 + lrow] = f2bf(acc[tr][tc][j]);
                }
            }
        }
}

// ---------------------------------------------------------------------------
// k_final: out = LN(relu(agg@G + sig*pbA + H@Wself + s@Wstr + biases) + H)
// ---------------------------------------------------------------------------
__global__ __launch_bounds__(256, 2) void k_final(
    const float* __restrict__ Agg, const float* __restrict__ H,
    const float* __restrict__ sig, const float* __restrict__ pbA,
    const unsigned short* __restrict__ Ghi, const unsigned short* __restrict__ Glo,
    const unsigned short* __restrict__ WShi, const unsigned short* __restrict__ WSlo,
    const float* __restrict__ Wstr,
    const float* __restrict__ bself, const float* __restrict__ bA,
    const float* __restrict__ bstr,
    const float* __restrict__ lng, const float* __restrict__ lnb,
    float* __restrict__ out, int N)
{
    extern __shared__ unsigned short lds[];
    unsigned short* Ahi = lds;
    unsigned short* Alo = lds + 128 * KPAD;
    unsigned short* Bhi = lds + 2 * 128 * KPAD;
    unsigned short* Blo = lds + 3 * 128 * KPAD;
    const int tid  = threadIdx.x;
    const int row0 = blockIdx.x * 128;
    const int nrows = min(128, N - row0);
    const int w    = tid >> 6, lane = tid & 63;
    const int lrow = lane & 15, kgrp = lane >> 4;

    f32x4 acc[2][8];
    float gl[8], bl_[8], pb[8];
    #pragma unroll
    for (int tc = 0; tc < 8; ++tc) {
        const int c = tc * 16 + lrow;
        const float bv = bself[c] + bA[c] + bstr[c];
        acc[0][tc] = f32x4{bv, bv, bv, bv};
        acc[1][tc] = f32x4{bv, bv, bv, bv};
        gl[tc] = lng[c]; bl_[tc] = lnb[c]; pb[tc] = pbA[c];
    }

    for (int ph = 0; ph < 2; ++ph) {
        const float* __restrict__ Am = ph ? H : Agg;
        const unsigned short* __restrict__ Wh = ph ? WShi : Ghi;
        const unsigned short* __restrict__ Wl = ph ? WSlo : Glo;
        for (int ch = 0; ch < 2; ++ch) {
            __syncthreads();
            #pragma unroll
            for (int it = 0; it < 8; ++it) {
                const int idx = tid + 256 * it;
                const int r = idx >> 4, kq = (idx & 15) * 4;
                f4 v = {0.f, 0.f, 0.f, 0.f};
                if (r < nrows) v = *(const f4*)&Am[(size_t)(row0 + r) * HID + ch * 64 + kq];
                ushort4 h, l;
                split2(v[0], h.x, l.x); split2(v[1], h.y, l.y);
                split2(v[2], h.z, l.z); split2(v[3], h.w, l.w);
                *(ushort4*)&Ahi[r * KPAD + kq] = h;
                *(ushort4*)&Alo[r * KPAD + kq] = l;
            }
            #pragma unroll
            for (int it = 0; it < 4; ++it) {
                const int idx = tid + 256 * it;
                const int c = idx >> 3, k8 = (idx & 7) * 8;
                *(uint4*)&Bhi[c * KPAD + k8] = *(const uint4*)&Wh[(size_t)c * HID + ch * 64 + k8];
                *(uint4*)&Blo[c * KPAD + k8] = *(const uint4*)&Wl[(size_t)c * HID + ch * 64 + k8];
            }
            __syncthreads();

            #pragma unroll
            for (int ks = 0; ks < 2; ++ks) {
                const int ko = ks * 32 + kgrp * 8;
                bf16x8 ah[2], al[2], bh[8], bl[8];
                #pragma unroll
                for (int tr = 0; tr < 2; ++tr) {
                    const int rr = w * 32 + tr * 16 + lrow;
                    ah[tr] = *(const bf16x8*)&Ahi[rr * KPAD + ko];
                    al[tr] = *(const bf16x8*)&Alo[rr * KPAD + ko];
                }
                #pragma unroll
                for (int tc = 0; tc < 8; ++tc) {
                    const int cc = tc * 16 + lrow;
                    bh[tc] = *(const bf16x8*)&Bhi[cc * KPAD + ko];
                    bl[tc] = *(const bf16x8*)&Blo[cc * KPAD + ko];
                }
                #pragma unroll
                for (int tr = 0; tr < 2; ++tr)
                    #pragma unroll
                    for (int tc = 0; tc < 8; ++tc) {
                        acc[tr][tc] = __builtin_amdgcn_mfma_f32_16x16x32_bf16(ah[tr], bh[tc], acc[tr][tc], 0, 0, 0);
                        acc[tr][tc] = __builtin_amdgcn_mfma_f32_16x16x32_bf16(al[tr], bh[tc], acc[tr][tc], 0, 0, 0);
                        acc[tr][tc] = __builtin_amdgcn_mfma_f32_16x16x32_bf16(ah[tr], bl[tc], acc[tr][tc], 0, 0, 0);
                    }
            }

            if (ph == 1 && ch == 0) {
                #pragma unroll
                for (int tr = 0; tr < 2; ++tr)
                    #pragma unroll
                    for (int j = 0; j < 4; ++j) {
                        const int rr = w * 32 + tr * 16 + kgrp * 4 + j;
                        float s[NSTR];
                        #pragma unroll
                        for (int k = 0; k < NSTR; ++k)
                            s[k] = bf2f(Ahi[rr * KPAD + k]) + bf2f(Alo[rr * KPAD + k]);
                        #pragma unroll
                        for (int tc = 0; tc < 8; ++tc) {
                            float a = 0.f;
                            #pragma unroll
                            for (int k = 0; k < NSTR; ++k)
                                a = fmaf(s[k], Wstr[k * HID + tc * 16 + lrow], a);
                            acc[tr][tc][j] += a;
                        }
                    }
            }
        }
    }

    #pragma unroll
    for (int tr = 0; tr < 2; ++tr)
        #pragma unroll
        for (int j = 0; j < 4; ++j) {
            const int r = w * 32 + tr * 16 + kgrp * 4 + j;
            const bool valid = r < nrows;
            const size_t rb = (size_t)(row0 + r) * HID;
            const float sg = valid ? sig[row0 + r] : 0.f;
            float v[8], s1 = 0.f, s2 = 0.f;
            #pragma unroll
            for (int tc = 0; tc < 8; ++tc) {
                float x = fmaxf(acc[tr][tc][j] + sg * pb[tc], 0.f);
                if (valid) x += H[rb + tc * 16 + lrow];
                v[tc] = x;
                s1 += x; s2 += x * x;
            }
            #pragma unroll
            for (int mk = 1; mk < 16; mk <<= 1) {
                s1 += __shfl_xor(s1, mk);
                s2 += __shfl_xor(s2, mk);
            }
            const float mean = s1 * (1.f / HID);
            const float var  = s2 * (1.f / HID) - mean * mean;
            const float rs   = rsqrtf(var + LN_EPS);
            if (valid) {
                #pragma unroll
                for (int tc = 0; tc < 8; ++tc)
                    out[rb + tc * 16 + lrow] = (v[tc] - mean) * rs * gl[tc] + bl_[tc];
            }
        }
}

// ---------------------------------------------------------------------------
// CSR build (scan / bucket / final) — ZERO global atomics.
// bucket packs {e, (oth<<8)|(key&255)} so csr_final reads are CONTIGUOUS.
// (assumes N < 2^23 — here N = 50000)
// ---------------------------------------------------------------------------
__global__ __launch_bounds__(1024) void k_csr_scan(
    const int* __restrict__ cnt_t, int* __restrict__ off_t,
    const int* __restrict__ cnt_s, int* __restrict__ off_s, int L)
{
    const int* __restrict__ cnt = blockIdx.x ? cnt_s : cnt_t;
    int* __restrict__ off = blockIdx.x ? off_s : off_t;
    __shared__ int warp_sums[16];
    __shared__ int carry_s;
    const int tid = threadIdx.x, lane = tid & 63, wid = tid >> 6;
    if (tid == 0) carry_s = 0;
    __syncthreads();
    for (int i0 = 0; i0 < L; i0 += 1024) {
        const int i = i0 + tid;
        const int v = (i < L) ? cnt[i] : 0;
        int x = v;
        #pragma unroll
        for (int d = 1; d < 64; d <<= 1) {
            const int y = __shfl_up(x, d);
            if (lane >= d) x += y;
        }
        if (lane == 63) warp_sums[wid] = x;
        __syncthreads();
        if (wid == 0) {
            int ws = (lane < 16) ? warp_sums[lane] : 0;
            #pragma unroll
            for (int d = 1; d < 16; d <<= 1) {
                const int y = __shfl_up(ws, d);
                if (lane >= d) ws += y;
            }
            if (lane < 16) warp_sums[lane] = ws;
        }
        __syncthreads();
        const int carry = carry_s;
        if (i < L) off[i] = carry + (wid ? warp_sums[wid - 1] : 0) + x - v;
        __syncthreads();
        if (tid == 1023) carry_s = carry + warp_sums[15];
        __syncthreads();
    }
    if (tid == 0) off[L] = carry_s;
}

__global__ __launch_bounds__(256) void k_csr_bucket(
    const int* __restrict__ etgt, const int* __restrict__ esrc,
    const int* __restrict__ off_t, const int* __restrict__ off_s,
    int2* __restrict__ ebuck_t, int2* __restrict__ ebuck_s,
    int NB, int NC, int E)
{
    __shared__ int cur[256];
    const int which = blockIdx.y;
    const int* __restrict__ key = which ? esrc : etgt;
    const int* __restrict__ oth = which ? etgt : esrc;
    const int* __restrict__ off = which ? off_s : off_t;
    int2* __restrict__ ebuck = which ? ebuck_s : ebuck_t;
    const int tid = threadIdx.x;
    for (int k = tid; k < NB; k += 256)
        cur[k] = off[(size_t)k * NC + blockIdx.x];
    __syncthreads();
    const int e0 = blockIdx.x * CSR_CHUNK;
    const int e1 = min(e0 + CSR_CHUNK, E);
    for (int e = e0 + tid; e < e1; e += 256) {
        const int kk = key[e];
        const int p = atomicAdd(&cur[kk >> 8], 1);
        ebuck[p] = make_int2(e, (oth[e] << 8) | (kk & 255));
    }
}

__global__ __launch_bounds__(256) void k_csr_final(
    const int* __restrict__ off_t, const int* __restrict__ off_s,
    const int2* __restrict__ ebuck_t, const int2* __restrict__ ebuck_s,
    int* __restrict__ base_t, int* __restrict__ base_s,
    int* __restrict__ eid_t, int* __restrict__ eid_s,
    int* __restrict__ src_t, int* __restrict__ tgt_s,
    int NB, int NC, int N, int E)
{
    __shared__ int cnt[256], excl[256], wsum[4];
    const int which = blockIdx.y;
    const int* __restrict__ off   = which ? off_s : off_t;
    const int2* __restrict__ ebuck = which ? ebuck_s : ebuck_t;
    int* __restrict__ base = which ? base_s : base_t;
    int* __restrict__ eid  = which ? eid_s : eid_t;
    int* __restrict__ aux  = which ? tgt_s : src_t;
    const int tid = threadIdx.x, lane = tid & 63, wv = tid >> 6;
    const int k = blockIdx.x;
    const int segb = off[(size_t)k * NC];
    const int sege = (k + 1 < NB) ? off[(size_t)(k + 1) * NC] : E;
    cnt[tid] = 0;
    __syncthreads();
    for (int i = segb + tid; i < sege; i += 256)
        atomicAdd(&cnt[ebuck[i].y & 255], 1);
    __syncthreads();
    {
        const int orig = cnt[tid];
        int x = orig;
        #pragma unroll
        for (int d = 1; d < 64; d <<= 1) {
            const int y = __shfl_up(x, d);
            if (lane >= d) x += y;
        }
        if (lane == 63) wsum[wv] = x;
        __syncthreads();
        if (tid == 0) {
            int a = 0;
            #pragma unroll
            for (int i = 0; i < 4; ++i) { const int t = wsum[i]; wsum[i] = a; a += t; }
        }
        __syncthreads();
        excl[tid] = x - orig + wsum[wv];
    }
    __syncthreads();
    const int node = k * 256 + tid;
    if (node < N) base[node] = segb + excl[tid];
    if (k == NB - 1 && tid == 0) base[N] = E;
    cnt[tid] = excl[tid];
    __syncthreads();
    for (int i = segb + tid; i < sege; i += 256) {
        const int2 p = ebuck[i];
        const int r = atomicAdd(&cnt[p.y & 255], 1);
        eid[segb + r] = p.x;
        aux[segb + r] = p.y >> 8;
    }
}

// ---------------------------------------------------------------------------
// k_score: wave per TARGET, 16-lane groups, src from contiguous src_t
// (2-deep chain: contig load -> gather), index prefetch.
// ---------------------------------------------------------------------------
__global__ __launch_bounds__(256) void k_score(
    const int* __restrict__ eid_t, const int* __restrict__ base_t,
    const int* __restrict__ src_t,
    const float* __restrict__ Wt, const unsigned short* __restrict__ UB,
    const unsigned short* __restrict__ HB,
    float* __restrict__ score, float* __restrict__ pairv,
    float* __restrict__ sumt_inv, int N)
{
    const int lane = threadIdx.x & 63, wv = threadIdx.x >> 6;
    const int t = blockIdx.x * 4 + wv;
    if (t >= N) return;
    const int b0 = base_t[t], deg = base_t[t + 1] - b0;
    if (deg == 0) { if (lane == 0) sumt_inv[t] = 0.f; return; }
    const int sub = lane & 15, grp = lane >> 4;
    const size_t to = (size_t)t * HID;

    float wt[8], u[8], htg[8];
    {
        const f4 w0 = *(const f4*)&Wt[to + sub * 8];
        const f4 w1 = *(const f4*)&Wt[to + sub * 8 + 4];
        wt[0] = w0[0]; wt[1] = w0[1]; wt[2] = w0[2]; wt[3] = w0[3];
        wt[4] = w1[0]; wt[5] = w1[1]; wt[6] = w1[2]; wt[7] = w1[3];
        unpack8(*(const uint4*)&UB[to + sub * 8], u);
        unpack8(*(const uint4*)&HB[to + sub * 8], htg);
    }

    bool valN = grp < deg;
    int eidN = 0, srcN = 0;
    if (valN) { eidN = eid_t[b0 + grp]; srcN = src_t[b0 + grp]; }

    for (int j0 = 0; j0 < deg; j0 += 4) {
        const bool val = valN;
        const int eid = eidN, src = srcN;
        const uint4 raw = *(const uint4*)&HB[(size_t)src * HID + sub * 8];
        const int jn = j0 + 4 + grp;
        valN = jn < deg;
        eidN = 0; srcN = 0;
        if (valN) { eidN = eid_t[b0 + jn]; srcN = src_t[b0 + jn]; }

        float hs[8];
        unpack8(raw, hs);
        float ps = 0.f, pp = 0.f;
        #pragma unroll
        for (int d = 0; d < 8; ++d) {
            ps = fmaf(wt[d], hs[d], ps);
            pp = fmaf(u[d], hs[d], pp);
        }
        if (sub == 0) {
            #pragma unroll
            for (int d = 0; d < NSTR; ++d) ps = fmaf(htg[d], hs[d], ps);
        }
        #pragma unroll
        for (int mk = 1; mk < 16; mk <<= 1) {
            ps += __shfl_xor(ps, mk);
            pp += __shfl_xor(pp, mk);
        }
        if (sub == 0 && val) {
            score[b0 + j0 + grp] = ps;
            pairv[eid] = pp;
        }
    }

    float m = -1e30f;
    for (int i = lane; i < deg; i += 64) m = fmaxf(m, score[b0 + i]);
    #pragma unroll
    for (int mk = 1; mk < 64; mk <<= 1) m = fmaxf(m, __shfl_xor(m, mk));
    float psum = 0.f;
    for (int i = lane; i < deg; i += 64) {
        const float e = expf(score[b0 + i] - m);
        score[b0 + i] = e;
        psum += e;
    }
    #pragma unroll
    for (int mk = 1; mk < 64; mk <<= 1) psum += __shfl_xor(psum, mk);
    if (lane == 0) sumt_inv[t] = 1.f / psum;
}

// ---------------------------------------------------------------------------
// k_beta2: wave per SOURCE node, streaming; fuses rho.
// Fast path for deg<=64: single gather pass, values cached in registers.
// ---------------------------------------------------------------------------
__global__ __launch_bounds__(256) void k_beta2(
    const int* __restrict__ base_s, const int* __restrict__ eid_s,
    const int* __restrict__ tgt_s,
    const float* __restrict__ pairv, const float* __restrict__ psi,
    float* __restrict__ rho1m, int N)
{
    const int lane = threadIdx.x & 63, wv = threadIdx.x >> 6;
    const int s = blockIdx.x * 4 + wv;
    if (s >= N) return;
    const int b0 = base_s[s], deg = base_s[s + 1] - b0;

    float se = 0.f, sn = 0.f;
    if (deg <= 64) {
        const bool v = lane < deg;
        float pv = -1e30f;
        int tg = 0;
        if (v) { pv = pairv[eid_s[b0 + lane]]; tg = tgt_s[b0 + lane]; }
        float m = pv;
        #pragma unroll
        for (int mk = 1; mk < 64; mk <<= 1) m = fmaxf(m, __shfl_xor(m, mk));
        const float ex = v ? expf(pv - m) : 0.f;
        se = ex;
        sn = v ? ex * expf(-psi[tg]) : 0.f;
    } else {
        float m = -1e30f;
        for (int i = lane; i < deg; i += 64) m = fmaxf(m, pairv[eid_s[b0 + i]]);
        #pragma unroll
        for (int mk = 1; mk < 64; mk <<= 1) m = fmaxf(m, __shfl_xor(m, mk));
        for (int i = lane; i < deg; i += 64) {
            const float ex = expf(pairv[eid_s[b0 + i]] - m);
            se += ex;
            sn += ex * expf(-psi[tgt_s[b0 + i]]);
        }
    }
    #pragma unroll
    for (int mk = 1; mk < 64; mk <<= 1) {
        se += __shfl_xor(se, mk);
        sn += __shfl_xor(sn, mk);
    }
    if (lane == 0) {
        const float st = (deg > 0 && se > 0.f) ? sn / se : 0.f;
        const float d  = -logf(st + 1e-8f);
        rho1m[s] = 1.f - 1.f / (1.f + expf(-(GAMMA * (d - DELTA))));
    }
}

// ---------------------------------------------------------------------------
// k_matt: wave per TARGET, 8 edges in flight + index/coef prefetch;
// src from contiguous src_t; gathers HB (warm from k_score).
// ---------------------------------------------------------------------------
__global__ __launch_bounds__(256) void k_matt(
    const int* __restrict__ src_t, const int* __restrict__ base_t,
    const float* __restrict__ score, const float* __restrict__ sumt_inv,
    const float* __restrict__ rho1m,
    const unsigned short* __restrict__ HB,
    float* __restrict__ agg, float* __restrict__ sig, int N)
{
    const int lane = threadIdx.x & 63, wv = threadIdx.x >> 6;
    const int t = blockIdx.x * 4 + wv;
    if (t >= N) return;
    const int b0 = base_t[t], deg = base_t[t + 1] - b0;
    const int sub = lane & 15, grp = lane >> 4;
    const size_t to = (size_t)t * HID;

    float acc[8];
    #pragma unroll
    for (int d = 0; d < 8; ++d) acc[d] = 0.f;
    float csum = 0.f;
    const float inv = (deg > 0) ? sumt_inv[t] : 0.f;

    bool vA = grp < deg, vB = 4 + grp < deg;
    int sA = 0, sB = 0;
    float scA = 0.f, scB = 0.f;
    if (vA) { sA = src_t[b0 + grp];     scA = score[b0 + grp]; }
    if (vB) { sB = src_t[b0 + 4 + grp]; scB = score[b0 + 4 + grp]; }

    for (int j0 = 0; j0 < deg; j0 += 8) {
        const bool cvA = vA, cvB = vB;
        const int csA = sA, csB = sB;
        const float cscA = scA, cscB = scB;
        const float rhoA = cvA ? rho1m[csA] : 0.f;
        const float rhoB = cvB ? rho1m[csB] : 0.f;
        const uint4 rA = *(const uint4*)&HB[(size_t)csA * HID + sub * 8];
        const uint4 rB = *(const uint4*)&HB[(size_t)csB * HID + sub * 8];
        const int jA = j0 + 8 + grp, jB = j0 + 12 + grp;
        vA = jA < deg; vB = jB < deg;
        sA = sB = 0; scA = scB = 0.f;
        if (vA) { sA = src_t[b0 + jA]; scA = score[b0 + jA]; }
        if (vB) { sB = src_t[b0 + jB]; scB = score[b0 + jB]; }

        const float cA = cvA ? cscA * inv * rhoA : 0.f;
        const float cB = cvB ? cscB * inv * rhoB : 0.f;
        float hA[8], hB[8];
        unpack8(rA, hA); unpack8(rB, hB);
        #pragma unroll
        for (int d = 0; d < 8; ++d) {
            acc[d] = fmaf(cA, hA[d], acc[d]);
            acc[d] = fmaf(cB, hB[d], acc[d]);
        }
        if (sub == 0) csum += cA + cB;
    }
    #pragma unroll
    for (int d = 0; d < 8; ++d) {
        acc[d] += __shfl_xor(acc[d], 16);
        acc[d] += __shfl_xor(acc[d], 32);
    }
    csum += __shfl_xor(csum, 16);
    csum += __shfl_xor(csum, 32);
    if (grp == 0) {
        f4 o0, o1;
        #pragma unroll
        for (int d = 0; d < 4; ++d) { o0[d] = acc[d]; o1[d] = acc[d + 4]; }
        *(f4*)&agg[to + sub * 8]     = o0;
        *(f4*)&agg[to + sub * 8 + 4] = o1;
        if (sub == 0) sig[t] = csum;
    }
}

extern "C" void kernel_launch(void* const* d_in, const int* in_sizes, int n_in,
                              void* d_out, int out_size, void* d_ws, size_t ws_size,
                              hipStream_t stream)
{
    const int*   eidx   = (const int*)  d_in[0];
    const float* H      = (const float*)d_in[1];
    const float* W_att  = (const float*)d_in[2];
    const float* phi_w  = (const float*)d_in[3];
    const float* phi_b  = (const float*)d_in[4];
    const float* W_p    = (const float*)d_in[5];
    const float* W_pp   = (const float*)d_in[6];
    const float* fdef_w = (const float*)d_in[7];
    const float* fdef_b = (const float*)d_in[8];
    const float* Wself  = (const float*)d_in[9];
    const float* bself  = (const float*)d_in[10];
    const float* WA     = (const float*)d_in[11];
    const float* bA     = (const float*)d_in[12];
    const float* Wstr   = (const float*)d_in[13];
    const float* bstr   = (const float*)d_in[14];
    const float* lng    = (const float*)d_in[15];
    const float* lnb    = (const float*)d_in[16];
    float* out = (float*)d_out;

    const int E = in_sizes[0] / 2;
    const int N = in_sizes[1] / HID;
    const int* esrc = eidx;
    const int* etgt = eidx + E;

    const int NB = (N + 255) >> 8;
    const int NC = (E + CSR_CHUNK - 1) / CSR_CHUNK;
    const int L  = NB * NC;

    // ---- workspace layout (~85 MB) ----
    char* w = (char*)d_ws;
    const size_t NHb  = (size_t)N * HID * sizeof(unsigned short);
    const size_t NH   = (size_t)N * HID * sizeof(float);
    const size_t Epad = (((size_t)E * sizeof(float)) + 255) & ~255ull;
    const size_t Npad = (((size_t)(N + 1) * sizeof(float)) + 255) & ~255ull;
    const size_t Lpad = (((size_t)(L + 1) * sizeof(int)) + 255) & ~255ull;

    float*          Wt    = (float*)w;          w += NH;   // agg aliases after k_score
    unsigned short* UB    = (unsigned short*)w; w += NHb;
    unsigned short* HB    = (unsigned short*)w; w += NHb;
    float* score   = (float*)w; w += Epad;  // CSR-tgt order
    float* pairv   = (float*)w; w += Epad;  // edge-id order
    int*   eid_t   = (int*)  w; w += Epad;
    int*   eid_s   = (int*)  w; w += Epad;
    int*   src_t   = (int*)  w; w += Epad;  // CSR-tgt companion src
    int*   tgt_s   = (int*)  w; w += Epad;  // CSR-src companion tgt
    int2*  ebuck_t = (int2*) w; w += 2 * Epad;
    int2*  ebuck_s = (int2*) w; w += 2 * Epad;
    int*   cnt_t = (int*)w; w += Lpad;
    int*   off_t = (int*)w; w += Lpad;
    int*   cnt_s = (int*)w; w += Lpad;
    int*   off_s = (int*)w; w += Lpad;
    int*   base_t   = (int*)  w; w += Npad;   // N+1
    int*   base_s   = (int*)  w; w += Npad;   // N+1
    float* sumt_inv = (float*)w; w += Npad;
    float* psi      = (float*)w; w += Npad;
    float* rho1m    = (float*)w; w += Npad;
    float* sig      = (float*)w; w += Npad;
    float* pbA      = (float*)w; w += 512;   // 128 floats
    unsigned short* WT = (unsigned short*)w;  // 4 slots x 2 planes x 128x128
    w += 4 * 2 * HID * HID * sizeof(unsigned short);
    float* agg = Wt;   // alias: Wt dead after k_score

    const int nblk128 = (N + 127) / 128;
    const int nblkN4  = (N + 3) / 4;
    const int nbCast  = (N + 15) / 16;
    const size_t lds_mfma = 4 * 128 * KPAD * sizeof(unsigned short);  // 72 KB
    const size_t MSZ = (size_t)2 * HID * HID;

    // slots: 0 = W_att(nat), 1 = Wself(T), 2 = M2, 3 = G  — one launch
    k_prep_all<<<dim3(8, 4), 256, 0, stream>>>(W_att, Wself, W_p, W_pp,
                                               phi_w, WA, phi_b, WT, pbA);

    // HB/psi + CSR histogram in one launch
    k_cast_count<<<nbCast + 2 * NC, 256, 0, stream>>>(H, fdef_w, fdef_b, HB, psi,
                                                      etgt, esrc, cnt_t, cnt_s,
                                                      nbCast, NB, NC, E, N);

    GemmArgsT g2;
    g2.Whi[0] = WT;           g2.Wlo[0] = WT + HID * HID;             // W_att
    g2.Whi[1] = WT + 2 * MSZ; g2.Wlo[1] = WT + 2 * MSZ + HID * HID;   // M2
    g2.O[0] = Wt;  g2.of32[0] = 1;
    g2.O[1] = UB;  g2.of32[1] = 0;
    k_gemm<<<dim3(nblk128, 2), 256, lds_mfma, stream>>>(H, g2, N);

    // ---- CSR build (no global atomics) ----
    k_csr_scan<<<2, 1024, 0, stream>>>(cnt_t, off_t, cnt_s, off_s, L);
    k_csr_bucket<<<dim3(NC, 2), 256, 0, stream>>>(etgt, esrc, off_t, off_s,
                                                  ebuck_t, ebuck_s, NB, NC, E);
    k_csr_final<<<dim3(NB, 2), 256, 0, stream>>>(off_t, off_s,
                                                 ebuck_t, ebuck_s, base_t, base_s,
                                                 eid_t, eid_s, src_t, tgt_s,
                                                 NB, NC, N, E);

    k_score<<<nblkN4, 256, 0, stream>>>(eid_t, base_t, src_t, Wt, UB, HB,
                                        score, pairv, sumt_inv, N);
    k_beta2<<<nblkN4, 256, 0, stream>>>(base_s, eid_s, tgt_s, pairv, psi, rho1m, N);

    k_matt<<<nblkN4, 256, 0, stream>>>(src_t, base_t, score, sumt_inv,
                                       rho1m, HB, agg, sig, N);

    k_final<<<nblk128, 256, lds_mfma, stream>>>(agg, H, sig, pbA,
                                                WT + 3 * MSZ, WT + 3 * MSZ + HID * HID,
                                                WT + 1 * MSZ, WT + 1 * MSZ + HID * HID,
                                                Wstr, bself, bA, bstr, lng, lnb, out, N);
}

// Round 18
// 273.351 us; speedup vs baseline: 1.7360x; 1.0002x over previous
//
#include <hip/hip_runtime.h>
#include <math.h>

#define HID 128
#define NSTR 6              // STRUCT-1
#define GAMMA 1.0f
#define DELTA 0.5f
#define LN_EPS 1e-5f
#define KPAD 72             // bf16 elems per LDS row (64 + 8 pad)
#define CSR_CHUNK 8192      // edges per block in CSR build

typedef __attribute__((ext_vector_type(4))) float f4;
typedef __attribute__((ext_vector_type(8))) short bf16x8;
typedef __attribute__((ext_vector_type(4))) float f32x4;

// f32 -> bf16 (round-to-nearest-even) and helpers
__device__ __forceinline__ unsigned short f2bf(float f) {
    unsigned u = __float_as_uint(f);
    unsigned r = u + 0x7FFFu + ((u >> 16) & 1u);
    return (unsigned short)(r >> 16);
}
__device__ __forceinline__ float bf2f(unsigned short h) {
    return __uint_as_float((unsigned)h << 16);
}
__device__ __forceinline__ void split2(float v, unsigned short& h, unsigned short& l) {
    h = f2bf(v);
    l = f2bf(v - bf2f(h));
}
__device__ __forceinline__ void bf2f2(unsigned u, float& lo, float& hi) {
    lo = __uint_as_float(u << 16);
    hi = __uint_as_float(u & 0xFFFF0000u);
}
__device__ __forceinline__ void unpack8(const uint4 u, float* f) {
    bf2f2(u.x, f[0], f[1]); bf2f2(u.y, f[2], f[3]);
    bf2f2(u.z, f[4], f[5]); bf2f2(u.w, f[6], f[7]);
}

// ---------------------------------------------------------------------------
// k_prep_all: all weight-table prep in ONE launch, grid (8, 4).
// mode 0: slot0 = W_att natural; mode 1: slot1 = Wself^T;
// mode 2: slot2 = M2 = W_p @ W_pp^T; mode 3: slot3 = G (+ pbA).
// ---------------------------------------------------------------------------
__global__ __launch_bounds__(256) void k_prep_all(
    const float* __restrict__ W_att, const float* __restrict__ Wself,
    const float* __restrict__ Wp,    const float* __restrict__ Wpp,
    const float* __restrict__ phiw,  const float* __restrict__ WA,
    const float* __restrict__ phib,
    unsigned short* __restrict__ WT, float* __restrict__ pbA)
{
    __shared__ float Bs[128][129];
    __shared__ float As[16][129];
    const int mode = blockIdx.y, c0 = blockIdx.x * 16;
    const int tid = threadIdx.x;
    const size_t MSZ = (size_t)2 * HID * HID;
    unsigned short* hi = WT + (size_t)mode * MSZ;
    unsigned short* lo = hi + HID * HID;

    if (mode == 0) {
        for (int idx = tid; idx < 2048; idx += 256) {
            const int c = idx >> 7, k = idx & 127;
            unsigned short h, l;
            split2(W_att[(size_t)(c0 + c) * HID + k], h, l);
            hi[(size_t)(c0 + c) * HID + k] = h;
            lo[(size_t)(c0 + c) * HID + k] = l;
        }
    } else if (mode == 1) {
        for (int idx = tid; idx < 2048; idx += 256) {
            const int k = idx >> 4, c = idx & 15;
            Bs[k][c] = Wself[k * HID + c0 + c];
        }
        __syncthreads();
        for (int idx = tid; idx < 2048; idx += 256) {
            const int c = idx >> 7, k = idx & 127;
            unsigned short h, l;
            split2(Bs[k][c], h, l);
            hi[(size_t)(c0 + c) * HID + k] = h;
            lo[(size_t)(c0 + c) * HID + k] = l;
        }
    } else if (mode == 2) {
        for (int idx = tid; idx < 128 * 128; idx += 256)
            Bs[idx >> 7][idx & 127] = Wpp[idx];
        for (int idx = tid; idx < 16 * 128; idx += 256)
            As[idx >> 7][idx & 127] = Wp[(size_t)(c0 + (idx >> 7)) * HID + (idx & 127)];
        __syncthreads();
        for (int it = 0; it < 8; ++it) {
            const int idx = tid + 256 * it;
            const int c = idx >> 7, k = idx & 127;
            float a = 0.f;
            #pragma unroll 4
            for (int j = 0; j < 128; ++j)
                a = fmaf(As[c][j], Bs[k][j], a);
            unsigned short h, l;
            split2(a, h, l);
            hi[(size_t)(c0 + c) * HID + k] = h;
            lo[(size_t)(c0 + c) * HID + k] = l;
        }
    } else {
        for (int idx = tid; idx < 128 * 128; idx += 256)
            Bs[idx >> 7][idx & 127] = phiw[idx];
        for (int idx = tid; idx < 16 * 128; idx += 256) {
            const int c = idx >> 7, j = idx & 127;
            As[c][j] = WA[(size_t)j * HID + c0 + c];
        }
        __syncthreads();
        for (int it = 0; it < 8; ++it) {
            const int idx = tid + 256 * it;
            const int c = idx >> 7, k = idx & 127;
            float a = 0.f;
            #pragma unroll 4
            for (int j = 0; j < 128; ++j)
                a = fmaf(As[c][j], Bs[k][j], a);
            unsigned short h, l;
            split2(a, h, l);
            hi[(size_t)(c0 + c) * HID + k] = h;
            lo[(size_t)(c0 + c) * HID + k] = l;
        }
        if (tid < 16) {
            float a = 0.f;
            #pragma unroll 4
            for (int j = 0; j < 128; ++j)
                a = fmaf(phib[j], As[tid][j], a);
            pbA[c0 + tid] = a;
        }
    }
}

// ---------------------------------------------------------------------------
// k_cast_count: merged launch. Blocks [0, nbCast) do HB=bf16(H) + psi;
// blocks [nbCast, nbCast+2*NC) do the CSR bucket histogram.
// ---------------------------------------------------------------------------
__global__ __launch_bounds__(256) void k_cast_count(
    const float* __restrict__ H, const float* __restrict__ fw,
    const float* __restrict__ fb,
    unsigned short* __restrict__ HB, float* __restrict__ psi,
    const int* __restrict__ etgt, const int* __restrict__ esrc,
    int* __restrict__ cnt_t, int* __restrict__ cnt_s,
    int nbCast, int NB, int NC, int E, int N)
{
    __shared__ int cnt[256];
    const int tid = threadIdx.x;
    const int bid = blockIdx.x;
    if (bid < nbCast) {
        const int row = bid * 16 + (tid >> 4), sub = tid & 15;
        if (row >= N) return;
        const size_t o = (size_t)row * HID + sub * 8;
        const f4 v0 = *(const f4*)&H[o];
        const f4 v1 = *(const f4*)&H[o + 4];
        ushort4 a, b;
        a.x = f2bf(v0[0]); a.y = f2bf(v0[1]); a.z = f2bf(v0[2]); a.w = f2bf(v0[3]);
        b.x = f2bf(v1[0]); b.y = f2bf(v1[1]); b.z = f2bf(v1[2]); b.w = f2bf(v1[3]);
        *(ushort4*)&HB[o] = a;
        *(ushort4*)&HB[o + 4] = b;
        const f4 w0 = *(const f4*)&fw[sub * 8];
        const f4 w1 = *(const f4*)&fw[sub * 8 + 4];
        float s = v0[0]*w0[0] + v0[1]*w0[1] + v0[2]*w0[2] + v0[3]*w0[3]
                + v1[0]*w1[0] + v1[1]*w1[1] + v1[2]*w1[2] + v1[3]*w1[3];
        #pragma unroll
        for (int mk = 1; mk < 16; mk <<= 1) s += __shfl_xor(s, mk);
        if (sub == 0) psi[row] = s + fb[0];
    } else {
        const int rem = bid - nbCast;
        const int which = rem / NC, blk = rem % NC;
        const int* __restrict__ key = which ? esrc : etgt;
        int* __restrict__ outc = which ? cnt_s : cnt_t;
        for (int i = tid; i < NB; i += 256) cnt[i] = 0;
        __syncthreads();
        const int e0 = blk * CSR_CHUNK;
        const int e1 = min(e0 + CSR_CHUNK, E);
        for (int e = e0 + tid; e < e1; e += 256)
            atomicAdd(&cnt[key[e] >> 8], 1);
        __syncthreads();
        for (int k = tid; k < NB; k += 256)
            outc[(size_t)k * NC + blk] = cnt[k];
    }
}

// ---------------------------------------------------------------------------
// k_splitlo: HBlo = f2bf(H - bf2f(f2bf(H)))   (lo plane; HB is the hi plane)
// ---------------------------------------------------------------------------
__global__ __launch_bounds__(256) void k_splitlo(
    const float* __restrict__ H, unsigned short* __restrict__ HBlo, int total8)
{
    const int idx = blockIdx.x * 256 + threadIdx.x;
    if (idx >= total8) return;
    const size_t o = (size_t)idx * 8;
    const f4 v0 = *(const f4*)&H[o];
    const f4 v1 = *(const f4*)&H[o + 4];
    ushort4 a, b;
    unsigned short h;
    split2(v0[0], h, a.x); split2(v0[1], h, a.y);
    split2(v0[2], h, a.z); split2(v0[3], h, a.w);
    split2(v1[0], h, b.x); split2(v1[1], h, b.y);
    split2(v1[2], h, b.z); split2(v1[3], h, b.w);
    *(ushort4*)&HBlo[o] = a;
    *(ushort4*)&HBlo[o + 4] = b;
}

struct GemmArgsT {
    const unsigned short* Whi[2];
    const unsigned short* Wlo[2];
    void*                 O[2];
    int                   of32[2];
};

// ---------------------------------------------------------------------------
// MFMA GEMM: O[ph] = A @ B[ph], split-precision; A pre-split (hi/lo bf16
// planes) so staging is pure uint4 copies — no split2 VALU.
// ---------------------------------------------------------------------------
__global__ __launch_bounds__(256, 2) void k_gemm(
    const unsigned short* __restrict__ Ah, const unsigned short* __restrict__ Al,
    GemmArgsT g, int N)
{
    extern __shared__ unsigned short lds[];
    unsigned short* Ahi = lds;
    unsigned short* Alo = lds + 128 * KPAD;
    unsigned short* Bhi = lds + 2 * 128 * KPAD;
    unsigned short* Blo = lds + 3 * 128 * KPAD;
    const int tid  = threadIdx.x;
    const int row0 = blockIdx.x * 128;
    const int nrows = min(128, N - row0);
    const int ph   = blockIdx.y;
    const int w    = tid >> 6, lane = tid & 63;
    const int lrow = lane & 15, kgrp = lane >> 4;

    f32x4 acc[2][8];
    #pragma unroll
    for (int tc = 0; tc < 8; ++tc) {
        acc[0][tc] = f32x4{0.f, 0.f, 0.f, 0.f};
        acc[1][tc] = f32x4{0.f, 0.f, 0.f, 0.f};
    }

    const unsigned short* __restrict__ Wh = g.Whi[ph];
    const unsigned short* __restrict__ Wl = g.Wlo[ph];

    for (int ch = 0; ch < 2; ++ch) {
        __syncthreads();
        #pragma unroll
        for (int it = 0; it < 4; ++it) {
            const int idx = tid + 256 * it;      // 1024 uint4 per plane
            const int r = idx >> 3, k8 = (idx & 7) * 8;
            uint4 h = {0u,0u,0u,0u}, l = {0u,0u,0u,0u};
            if (r < nrows) {
                const size_t go = (size_t)(row0 + r) * HID + ch * 64 + k8;
                h = *(const uint4*)&Ah[go];
                l = *(const uint4*)&Al[go];
            }
            *(uint4*)&Ahi[r * KPAD + k8] = h;
            *(uint4*)&Alo[r * KPAD + k8] = l;
        }
        #pragma unroll
        for (int it = 0; it < 4; ++it) {
            const int idx = tid + 256 * it;
            const int c = idx >> 3, k8 = (idx & 7) * 8;
            *(uint4*)&Bhi[c * KPAD + k8] = *(const uint4*)&Wh[(size_t)c * HID + ch * 64 + k8];
            *(uint4*)&Blo[c * KPAD + k8] = *(const uint4*)&Wl[(size_t)c * HID + ch * 64 + k8];
        }
        __syncthreads();

        #pragma unroll
        for (int ks = 0; ks < 2; ++ks) {
            const int ko = ks * 32 + kgrp * 8;
            bf16x8 ah[2], al[2], bh[8], bl[8];
            #pragma unroll
            for (int tr = 0; tr < 2; ++tr) {
                const int rr = w * 32 + tr * 16 + lrow;
                ah[tr] = *(const bf16x8*)&Ahi[rr * KPAD + ko];
                al[tr] = *(const bf16x8*)&Alo[rr * KPAD + ko];
            }
            #pragma unroll
            for (int tc = 0; tc < 8; ++tc) {
                const int cc = tc * 16 + lrow;
                bh[tc] = *(const bf16x8*)&Bhi[cc * KPAD + ko];
                bl[tc] = *(const bf16x8*)&Blo[cc * KPAD + ko];
            }
            #pragma unroll
            for (int tr = 0; tr < 2; ++tr)
                #pragma unroll
                for (int tc = 0; tc < 8; ++tc) {
                    acc[tr][tc] = __builtin_amdgcn_mfma_f32_16x16x32_bf16(ah[tr], bh[tc], acc[tr][tc], 0, 0, 0);
                    acc[tr][tc] = __builtin_amdgcn_mfma_f32_16x16x32_bf16(al[tr], bh[tc], acc[tr][tc], 0, 0, 0);
                    acc[tr][tc] = __builtin_amdgcn_mfma_f32_16x16x32_bf16(ah[tr], bl[tc], acc[tr][tc], 0, 0, 0);
                }
        }
    }

    #pragma unroll
    for (int tr = 0; tr < 2; ++tr)
        #pragma unroll
        for (int j = 0; j < 4; ++j) {
            const int r = w * 32 + tr * 16 + kgrp * 4 + j;
            if (r < nrows) {
                if (g.of32[ph]) {
                    float* O = (float*)g.O[ph];
                    #pragma unroll
                    for (int tc = 0; tc < 8; ++tc)
                        O[(size_t)(row0 + r) * HID + tc * 16 + lrow] = acc[tr][tc][j];
                } else {
                    unsigned short* O = (unsigned short*)g.O[ph];
                    #pragma unroll
                    for (int tc = 0; tc < 8; ++tc)
                        O[(size_t)(row0 + r) * HID + tc * 16 + lrow] = f2bf(acc[tr][tc][j]);
                }
            }
        }
}

// ---------------------------------------------------------------------------
// k_final: out = LN(relu(agg@G + sig*pbA + H@Wself + s@Wstr + biases) + H)
// Both A operands pre-split (AggHi/Lo and HB/HBlo) — staging is pure copies.
// Residual reads H f32 (exact, unchanged).
// ---------------------------------------------------------------------------
__global__ __launch_bounds__(256, 2) void k_final(
    const unsigned short* __restrict__ AggHi, const unsigned short* __restrict__ AggLo,
    const unsigned short* __restrict__ Hhi, const unsigned short* __restrict__ Hlo,
    const float* __restrict__ H,
    const float* __restrict__ sig, const float* __restrict__ pbA,
    const unsigned short* __restrict__ Ghi, const unsigned short* __restrict__ Glo,
    const unsigned short* __restrict__ WShi, const unsigned short* __restrict__ WSlo,
    const float* __restrict__ Wstr,
    const float* __restrict__ bself, const float* __restrict__ bA,
    const float* __restrict__ bstr,
    const float* __restrict__ lng, const float* __restrict__ lnb,
    float* __restrict__ out, int N)
{
    extern __shared__ unsigned short lds[];
    unsigned short* Ahi = lds;
    unsigned short* Alo = lds + 128 * KPAD;
    unsigned short* Bhi = lds + 2 * 128 * KPAD;
    unsigned short* Blo = lds + 3 * 128 * KPAD;
    const int tid  = threadIdx.x;
    const int row0 = blockIdx.x * 128;
    const int nrows = min(128, N - row0);
    const int w    = tid >> 6, lane = tid & 63;
    const int lrow = lane & 15, kgrp = lane >> 4;

    f32x4 acc[2][8];
    float gl[8], bl_[8], pb[8];
    #pragma unroll
    for (int tc = 0; tc < 8; ++tc) {
        const int c = tc * 16 + lrow;
        const float bv = bself[c] + bA[c] + bstr[c];
        acc[0][tc] = f32x4{bv, bv, bv, bv};
        acc[1][tc] = f32x4{bv, bv, bv, bv};
        gl[tc] = lng[c]; bl_[tc] = lnb[c]; pb[tc] = pbA[c];
    }

    for (int ph = 0; ph < 2; ++ph) {
        const unsigned short* __restrict__ Amh = ph ? Hhi : AggHi;
        const unsigned short* __restrict__ Aml = ph ? Hlo : AggLo;
        const unsigned short* __restrict__ Wh = ph ? WShi : Ghi;
        const unsigned short* __restrict__ Wl = ph ? WSlo : Glo;
        for (int ch = 0; ch < 2; ++ch) {
            __syncthreads();
            #pragma unroll
            for (int it = 0; it < 4; ++it) {
                const int idx = tid + 256 * it;
                const int r = idx >> 3, k8 = (idx & 7) * 8;
                uint4 h = {0u,0u,0u,0u}, l = {0u,0u,0u,0u};
                if (r < nrows) {
                    const size_t go = (size_t)(row0 + r) * HID + ch * 64 + k8;
                    h = *(const uint4*)&Amh[go];
                    l = *(const uint4*)&Aml[go];
                }
                *(uint4*)&Ahi[r * KPAD + k8] = h;
                *(uint4*)&Alo[r * KPAD + k8] = l;
            }
            #pragma unroll
            for (int it = 0; it < 4; ++it) {
                const int idx = tid + 256 * it;
                const int c = idx >> 3, k8 = (idx & 7) * 8;
                *(uint4*)&Bhi[c * KPAD + k8] = *(const uint4*)&Wh[(size_t)c * HID + ch * 64 + k8];
                *(uint4*)&Blo[c * KPAD + k8] = *(const uint4*)&Wl[(size_t)c * HID + ch * 64 + k8];
            }
            __syncthreads();

            #pragma unroll
            for (int ks = 0; ks < 2; ++ks) {
                const int ko = ks * 32 + kgrp * 8;
                bf16x8 ah[2], al[2], bh[8], bl[8];
                #pragma unroll
                for (int tr = 0; tr < 2; ++tr) {
                    const int rr = w * 32 + tr * 16 + lrow;
                    ah[tr] = *(const bf16x8*)&Ahi[rr * KPAD + ko];
                    al[tr] = *(const bf16x8*)&Alo[rr * KPAD + ko];
                }
                #pragma unroll
                for (int tc = 0; tc < 8; ++tc) {
                    const int cc = tc * 16 + lrow;
                    bh[tc] = *(const bf16x8*)&Bhi[cc * KPAD + ko];
                    bl[tc] = *(const bf16x8*)&Blo[cc * KPAD + ko];
                }
                #pragma unroll
                for (int tr = 0; tr < 2; ++tr)
                    #pragma unroll
                    for (int tc = 0; tc < 8; ++tc) {
                        acc[tr][tc] = __builtin_amdgcn_mfma_f32_16x16x32_bf16(ah[tr], bh[tc], acc[tr][tc], 0, 0, 0);
                        acc[tr][tc] = __builtin_amdgcn_mfma_f32_16x16x32_bf16(al[tr], bh[tc], acc[tr][tc], 0, 0, 0);
                        acc[tr][tc] = __builtin_amdgcn_mfma_f32_16x16x32_bf16(ah[tr], bl[tc], acc[tr][tc], 0, 0, 0);
                    }
            }

            if (ph == 1 && ch == 0) {
                #pragma unroll
                for (int tr = 0; tr < 2; ++tr)
                    #pragma unroll
                    for (int j = 0; j < 4; ++j) {
                        const int rr = w * 32 + tr * 16 + kgrp * 4 + j;
                        float s[NSTR];
                        #pragma unroll
                        for (int k = 0; k < NSTR; ++k)
                            s[k] = bf2f(Ahi[rr * KPAD + k]) + bf2f(Alo[rr * KPAD + k]);
                        #pragma unroll
                        for (int tc = 0; tc < 8; ++tc) {
                            float a = 0.f;
                            #pragma unroll
                            for (int k = 0; k < NSTR; ++k)
                                a = fmaf(s[k], Wstr[k * HID + tc * 16 + lrow], a);
                            acc[tr][tc][j] += a;
                        }
                    }
            }
        }
    }

    #pragma unroll
    for (int tr = 0; tr < 2; ++tr)
        #pragma unroll
        for (int j = 0; j < 4; ++j) {
            const int r = w * 32 + tr * 16 + kgrp * 4 + j;
            const bool valid = r < nrows;
            const size_t rb = (size_t)(row0 + r) * HID;
            const float sg = valid ? sig[row0 + r] : 0.f;
            float v[8], s1 = 0.f, s2 = 0.f;
            #pragma unroll
            for (int tc = 0; tc < 8; ++tc) {
                float x = fmaxf(acc[tr][tc][j] + sg * pb[tc], 0.f);
                if (valid) x += H[rb + tc * 16 + lrow];
                v[tc] = x;
                s1 += x; s2 += x * x;
            }
            #pragma unroll
            for (int mk = 1; mk < 16; mk <<= 1) {
                s1 += __shfl_xor(s1, mk);
                s2 += __shfl_xor(s2, mk);
            }
            const float mean = s1 * (1.f / HID);
            const float var  = s2 * (1.f / HID) - mean * mean;
            const float rs   = rsqrtf(var + LN_EPS);
            if (valid) {
                #pragma unroll
                for (int tc = 0; tc < 8; ++tc)
                    out[rb + tc * 16 + lrow] = (v[tc] - mean) * rs * gl[tc] + bl_[tc];
            }
        }
}

// ---------------------------------------------------------------------------
// CSR build (scan / bucket / final) — ZERO global atomics.
// bucket packs {e, (oth<<8)|(key&255)} so csr_final reads are CONTIGUOUS.
// ---------------------------------------------------------------------------
__global__ __launch_bounds__(1024) void k_csr_scan(
    const int* __restrict__ cnt_t, int* __restrict__ off_t,
    const int* __restrict__ cnt_s, int* __restrict__ off_s, int L)
{
    const int* __restrict__ cnt = blockIdx.x ? cnt_s : cnt_t;
    int* __restrict__ off = blockIdx.x ? off_s : off_t;
    __shared__ int warp_sums[16];
    __shared__ int carry_s;
    const int tid = threadIdx.x, lane = tid & 63, wid = tid >> 6;
    if (tid == 0) carry_s = 0;
    __syncthreads();
    for (int i0 = 0; i0 < L; i0 += 1024) {
        const int i = i0 + tid;
        const int v = (i < L) ? cnt[i] : 0;
        int x = v;
        #pragma unroll
        for (int d = 1; d < 64; d <<= 1) {
            const int y = __shfl_up(x, d);
            if (lane >= d) x += y;
        }
        if (lane == 63) warp_sums[wid] = x;
        __syncthreads();
        if (wid == 0) {
            int ws = (lane < 16) ? warp_sums[lane] : 0;
            #pragma unroll
            for (int d = 1; d < 16; d <<= 1) {
                const int y = __shfl_up(ws, d);
                if (lane >= d) ws += y;
            }
            if (lane < 16) warp_sums[lane] = ws;
        }
        __syncthreads();
        const int carry = carry_s;
        if (i < L) off[i] = carry + (wid ? warp_sums[wid - 1] : 0) + x - v;
        __syncthreads();
        if (tid == 1023) carry_s = carry + warp_sums[15];
        __syncthreads();
    }
    if (tid == 0) off[L] = carry_s;
}

__global__ __launch_bounds__(256) void k_csr_bucket(
    const int* __restrict__ etgt, const int* __restrict__ esrc,
    const int* __restrict__ off_t, const int* __restrict__ off_s,
    int2* __restrict__ ebuck_t, int2* __restrict__ ebuck_s,
    int NB, int NC, int E)
{
    __shared__ int cur[256];
    const int which = blockIdx.y;
    const int* __restrict__ key = which ? esrc : etgt;
    const int* __restrict__ oth = which ? etgt : esrc;
    const int* __restrict__ off = which ? off_s : off_t;
    int2* __restrict__ ebuck = which ? ebuck_s : ebuck_t;
    const int tid = threadIdx.x;
    for (int k = tid; k < NB; k += 256)
        cur[k] = off[(size_t)k * NC + blockIdx.x];
    __syncthreads();
    const int e0 = blockIdx.x * CSR_CHUNK;
    const int e1 = min(e0 + CSR_CHUNK, E);
    for (int e = e0 + tid; e < e1; e += 256) {
        const int kk = key[e];
        const int p = atomicAdd(&cur[kk >> 8], 1);
        ebuck[p] = make_int2(e, (oth[e] << 8) | (kk & 255));
    }
}

__global__ __launch_bounds__(256) void k_csr_final(
    const int* __restrict__ off_t, const int* __restrict__ off_s,
    const int2* __restrict__ ebuck_t, const int2* __restrict__ ebuck_s,
    int* __restrict__ base_t, int* __restrict__ base_s,
    int* __restrict__ eid_t, int* __restrict__ eid_s,
    int* __restrict__ src_t, int* __restrict__ tgt_s,
    int NB, int NC, int N, int E)
{
    __shared__ int cnt[256], excl[256], wsum[4];
    const int which = blockIdx.y;
    const int* __restrict__ off   = which ? off_s : off_t;
    const int2* __restrict__ ebuck = which ? ebuck_s : ebuck_t;
    int* __restrict__ base = which ? base_s : base_t;
    int* __restrict__ eid  = which ? eid_s : eid_t;
    int* __restrict__ aux  = which ? tgt_s : src_t;
    const int tid = threadIdx.x, lane = tid & 63, wv = tid >> 6;
    const int k = blockIdx.x;
    const int segb = off[(size_t)k * NC];
    const int sege = (k + 1 < NB) ? off[(size_t)(k + 1) * NC] : E;
    cnt[tid] = 0;
    __syncthreads();
    for (int i = segb + tid; i < sege; i += 256)
        atomicAdd(&cnt[ebuck[i].y & 255], 1);
    __syncthreads();
    {
        const int orig = cnt[tid];
        int x = orig;
        #pragma unroll
        for (int d = 1; d < 64; d <<= 1) {
            const int y = __shfl_up(x, d);
            if (lane >= d) x += y;
        }
        if (lane == 63) wsum[wv] = x;
        __syncthreads();
        if (tid == 0) {
            int a = 0;
            #pragma unroll
            for (int i = 0; i < 4; ++i) { const int t = wsum[i]; wsum[i] = a; a += t; }
        }
        __syncthreads();
        excl[tid] = x - orig + wsum[wv];
    }
    __syncthreads();
    const int node = k * 256 + tid;
    if (node < N) base[node] = segb + excl[tid];
    if (k == NB - 1 && tid == 0) base[N] = E;
    cnt[tid] = excl[tid];
    __syncthreads();
    for (int i = segb + tid; i < sege; i += 256) {
        const int2 p = ebuck[i];
        const int r = atomicAdd(&cnt[p.y & 255], 1);
        eid[segb + r] = p.x;
        aux[segb + r] = p.y >> 8;
    }
}

// ---------------------------------------------------------------------------
// k_score: wave per TARGET, 16-lane groups, src from contiguous src_t
// (2-deep chain: contig load -> gather), index prefetch.
// ---------------------------------------------------------------------------
__global__ __launch_bounds__(256) void k_score(
    const int* __restrict__ eid_t, const int* __restrict__ base_t,
    const int* __restrict__ src_t,
    const float* __restrict__ Wt, const unsigned short* __restrict__ UB,
    const unsigned short* __restrict__ HB,
    float* __restrict__ score, float* __restrict__ pairv,
    float* __restrict__ sumt_inv, int N)
{
    const int lane = threadIdx.x & 63, wv = threadIdx.x >> 6;
    const int t = blockIdx.x * 4 + wv;
    if (t >= N) return;
    const int b0 = base_t[t], deg = base_t[t + 1] - b0;
    if (deg == 0) { if (lane == 0) sumt_inv[t] = 0.f; return; }
    const int sub = lane & 15, grp = lane >> 4;
    const size_t to = (size_t)t * HID;

    float wt[8], u[8], htg[8];
    {
        const f4 w0 = *(const f4*)&Wt[to + sub * 8];
        const f4 w1 = *(const f4*)&Wt[to + sub * 8 + 4];
        wt[0] = w0[0]; wt[1] = w0[1]; wt[2] = w0[2]; wt[3] = w0[3];
        wt[4] = w1[0]; wt[5] = w1[1]; wt[6] = w1[2]; wt[7] = w1[3];
        unpack8(*(const uint4*)&UB[to + sub * 8], u);
        unpack8(*(const uint4*)&HB[to + sub * 8], htg);
    }

    bool valN = grp < deg;
    int eidN = 0, srcN = 0;
    if (valN) { eidN = eid_t[b0 + grp]; srcN = src_t[b0 + grp]; }

    for (int j0 = 0; j0 < deg; j0 += 4) {
        const bool val = valN;
        const int eid = eidN, src = srcN;
        const uint4 raw = *(const uint4*)&HB[(size_t)src * HID + sub * 8];
        const int jn = j0 + 4 + grp;
        valN = jn < deg;
        eidN = 0; srcN = 0;
        if (valN) { eidN = eid_t[b0 + jn]; srcN = src_t[b0 + jn]; }

        float hs[8];
        unpack8(raw, hs);
        float ps = 0.f, pp = 0.f;
        #pragma unroll
        for (int d = 0; d < 8; ++d) {
            ps = fmaf(wt[d], hs[d], ps);
            pp = fmaf(u[d], hs[d], pp);
        }
        if (sub == 0) {
            #pragma unroll
            for (int d = 0; d < NSTR; ++d) ps = fmaf(htg[d], hs[d], ps);
        }
        #pragma unroll
        for (int mk = 1; mk < 16; mk <<= 1) {
            ps += __shfl_xor(ps, mk);
            pp += __shfl_xor(pp, mk);
        }
        if (sub == 0 && val) {
            score[b0 + j0 + grp] = ps;
            pairv[eid] = pp;
        }
    }

    float m = -1e30f;
    for (int i = lane; i < deg; i += 64) m = fmaxf(m, score[b0 + i]);
    #pragma unroll
    for (int mk = 1; mk < 64; mk <<= 1) m = fmaxf(m, __shfl_xor(m, mk));
    float psum = 0.f;
    for (int i = lane; i < deg; i += 64) {
        const float e = expf(score[b0 + i] - m);
        score[b0 + i] = e;
        psum += e;
    }
    #pragma unroll
    for (int mk = 1; mk < 64; mk <<= 1) psum += __shfl_xor(psum, mk);
    if (lane == 0) sumt_inv[t] = 1.f / psum;
}

// ---------------------------------------------------------------------------
// k_beta2: wave per SOURCE node, streaming; fuses rho.
// ---------------------------------------------------------------------------
__global__ __launch_bounds__(256) void k_beta2(
    const int* __restrict__ base_s, const int* __restrict__ eid_s,
    const int* __restrict__ tgt_s,
    const float* __restrict__ pairv, const float* __restrict__ psi,
    float* __restrict__ rho1m, int N)
{
    const int lane = threadIdx.x & 63, wv = threadIdx.x >> 6;
    const int s = blockIdx.x * 4 + wv;
    if (s >= N) return;
    const int b0 = base_s[s], deg = base_s[s + 1] - b0;

    float se = 0.f, sn = 0.f;
    if (deg <= 64) {
        const bool v = lane < deg;
        float pv = -1e30f;
        int tg = 0;
        if (v) { pv = pairv[eid_s[b0 + lane]]; tg = tgt_s[b0 + lane]; }
        float m = pv;
        #pragma unroll
        for (int mk = 1; mk < 64; mk <<= 1) m = fmaxf(m, __shfl_xor(m, mk));
        const float ex = v ? expf(pv - m) : 0.f;
        se = ex;
        sn = v ? ex * expf(-psi[tg]) : 0.f;
    } else {
        float m = -1e30f;
        for (int i = lane; i < deg; i += 64) m = fmaxf(m, pairv[eid_s[b0 + i]]);
        #pragma unroll
        for (int mk = 1; mk < 64; mk <<= 1) m = fmaxf(m, __shfl_xor(m, mk));
        for (int i = lane; i < deg; i += 64) {
            const float ex = expf(pairv[eid_s[b0 + i]] - m);
            se += ex;
            sn += ex * expf(-psi[tgt_s[b0 + i]]);
        }
    }
    #pragma unroll
    for (int mk = 1; mk < 64; mk <<= 1) {
        se += __shfl_xor(se, mk);
        sn += __shfl_xor(sn, mk);
    }
    if (lane == 0) {
        const float st = (deg > 0 && se > 0.f) ? sn / se : 0.f;
        const float d  = -logf(st + 1e-8f);
        rho1m[s] = 1.f - 1.f / (1.f + expf(-(GAMMA * (d - DELTA))));
    }
}

// ---------------------------------------------------------------------------
// k_matt: wave per TARGET, 8 edges in flight + index/coef prefetch;
// writes agg pre-split as hi/lo bf16 planes (consumed by k_final directly).
// ---------------------------------------------------------------------------
__global__ __launch_bounds__(256) void k_matt(
    const int* __restrict__ src_t, const int* __restrict__ base_t,
    const float* __restrict__ score, const float* __restrict__ sumt_inv,
    const float* __restrict__ rho1m,
    const unsigned short* __restrict__ HB,
    unsigned short* __restrict__ aggHi, unsigned short* __restrict__ aggLo,
    float* __restrict__ sig, int N)
{
    const int lane = threadIdx.x & 63, wv = threadIdx.x >> 6;
    const int t = blockIdx.x * 4 + wv;
    if (t >= N) return;
    const int b0 = base_t[t], deg = base_t[t + 1] - b0;
    const int sub = lane & 15, grp = lane >> 4;
    const size_t to = (size_t)t * HID;

    float acc[8];
    #pragma unroll
    for (int d = 0; d < 8; ++d) acc[d] = 0.f;
    float csum = 0.f;
    const float inv = (deg > 0) ? sumt_inv[t] : 0.f;

    bool vA = grp < deg, vB = 4 + grp < deg;
    int sA = 0, sB = 0;
    float scA = 0.f, scB = 0.f;
    if (vA) { sA = src_t[b0 + grp];     scA = score[b0 + grp]; }
    if (vB) { sB = src_t[b0 + 4 + grp]; scB = score[b0 + 4 + grp]; }

    for (int j0 = 0; j0 < deg; j0 += 8) {
        const bool cvA = vA, cvB = vB;
        const int csA = sA, csB = sB;
        const float cscA = scA, cscB = scB;
        const float rhoA = cvA ? rho1m[csA] : 0.f;
        const float rhoB = cvB ? rho1m[csB] : 0.f;
        const uint4 rA = *(const uint4*)&HB[(size_t)csA * HID + sub * 8];
        const uint4 rB = *(const uint4*)&HB[(size_t)csB * HID + sub * 8];
        const int jA = j0 + 8 + grp, jB = j0 + 12 + grp;
        vA = jA < deg; vB = jB < deg;
        sA = sB = 0; scA = scB = 0.f;
        if (vA) { sA = src_t[b0 + jA]; scA = score[b0 + jA]; }
        if (vB) { sB = src_t[b0 + jB]; scB = score[b0 + jB]; }

        const float cA = cvA ? cscA * inv * rhoA : 0.f;
        const float cB = cvB ? cscB * inv * rhoB : 0.f;
        float hA[8], hB[8];
        unpack8(rA, hA); unpack8(rB, hB);
        #pragma unroll
        for (int d = 0; d < 8; ++d) {
            acc[d] = fmaf(cA, hA[d], acc[d]);
            acc[d] = fmaf(cB, hB[d], acc[d]);
        }
        if (sub == 0) csum += cA + cB;
    }
    #pragma unroll
    for (int d = 0; d < 8; ++d) {
        acc[d] += __shfl_xor(acc[d], 16);
        acc[d] += __shfl_xor(acc[d], 32);
    }
    csum += __shfl_xor(csum, 16);
    csum += __shfl_xor(csum, 32);
    if (grp == 0) {
        ushort4 h0, h1, l0, l1;
        split2(acc[0], h0.x, l0.x); split2(acc[1], h0.y, l0.y);
        split2(acc[2], h0.z, l0.z); split2(acc[3], h0.w, l0.w);
        split2(acc[4], h1.x, l1.x); split2(acc[5], h1.y, l1.y);
        split2(acc[6], h1.z, l1.z); split2(acc[7], h1.w, l1.w);
        *(ushort4*)&aggHi[to + sub * 8]     = h0;
        *(ushort4*)&aggHi[to + sub * 8 + 4] = h1;
        *(ushort4*)&aggLo[to + sub * 8]     = l0;
        *(ushort4*)&aggLo[to + sub * 8 + 4] = l1;
        if (sub == 0) sig[t] = csum;
    }
}

extern "C" void kernel_launch(void* const* d_in, const int* in_sizes, int n_in,
                              void* d_out, int out_size, void* d_ws, size_t ws_size,
                              hipStream_t stream)
{
    const int*   eidx   = (const int*)  d_in[0];
    const float* H      = (const float*)d_in[1];
    const float* W_att  = (const float*)d_in[2];
    const float* phi_w  = (const float*)d_in[3];
    const float* phi_b  = (const float*)d_in[4];
    const float* W_p    = (const float*)d_in[5];
    const float* W_pp   = (const float*)d_in[6];
    const float* fdef_w = (const float*)d_in[7];
    const float* fdef_b = (const float*)d_in[8];
    const float* Wself  = (const float*)d_in[9];
    const float* bself  = (const float*)d_in[10];
    const float* WA     = (const float*)d_in[11];
    const float* bA     = (const float*)d_in[12];
    const float* Wstr   = (const float*)d_in[13];
    const float* bstr   = (const float*)d_in[14];
    const float* lng    = (const float*)d_in[15];
    const float* lnb    = (const float*)d_in[16];
    float* out = (float*)d_out;

    const int E = in_sizes[0] / 2;
    const int N = in_sizes[1] / HID;
    const int* esrc = eidx;
    const int* etgt = eidx + E;

    const int NB = (N + 255) >> 8;
    const int NC = (E + CSR_CHUNK - 1) / CSR_CHUNK;
    const int L  = NB * NC;

    // ---- workspace layout (~85 MB; HBlo aliases the dead ebuck region) ----
    char* w = (char*)d_ws;
    const size_t NHb  = (size_t)N * HID * sizeof(unsigned short);
    const size_t NH   = (size_t)N * HID * sizeof(float);
    const size_t Epad = (((size_t)E * sizeof(float)) + 255) & ~255ull;
    const size_t Npad = (((size_t)(N + 1) * sizeof(float)) + 255) & ~255ull;
    const size_t Lpad = (((size_t)(L + 1) * sizeof(int)) + 255) & ~255ull;

    float*          Wt    = (float*)w;          w += NH;   // aggHi/aggLo alias after k_score
    unsigned short* UB    = (unsigned short*)w; w += NHb;
    unsigned short* HB    = (unsigned short*)w; w += NHb;
    float* score   = (float*)w; w += Epad;  // CSR-tgt order
    float* pairv   = (float*)w; w += Epad;  // edge-id order
    int*   eid_t   = (int*)  w; w += Epad;
    int*   eid_s   = (int*)  w; w += Epad;
    int*   src_t   = (int*)  w; w += Epad;  // CSR-tgt companion src
    int*   tgt_s   = (int*)  w; w += Epad;  // CSR-src companion tgt
    int2*  ebuck_t = (int2*) w; w += 2 * Epad;
    int2*  ebuck_s = (int2*) w; w += 2 * Epad;
    int*   cnt_t = (int*)w; w += Lpad;
    int*   off_t = (int*)w; w += Lpad;
    int*   cnt_s = (int*)w; w += Lpad;
    int*   off_s = (int*)w; w += Lpad;
    int*   base_t   = (int*)  w; w += Npad;   // N+1
    int*   base_s   = (int*)  w; w += Npad;   // N+1
    float* sumt_inv = (float*)w; w += Npad;
    float* psi      = (float*)w; w += Npad;
    float* rho1m    = (float*)w; w += Npad;
    float* sig      = (float*)w; w += Npad;
    float* pbA      = (float*)w; w += 512;   // 128 floats
    unsigned short* WT = (unsigned short*)w;  // 4 slots x 2 planes x 128x128
    w += 4 * 2 * HID * HID * sizeof(unsigned short);
    // aliases (lifetime-disjoint):
    unsigned short* HBlo  = (unsigned short*)ebuck_t;   // written AFTER csr_final
    unsigned short* aggHi = (unsigned short*)Wt;        // Wt dead after k_score
    unsigned short* aggLo = aggHi + (size_t)N * HID;

    const int nblk128 = (N + 127) / 128;
    const int nblkN4  = (N + 3) / 4;
    const int nbCast  = (N + 15) / 16;
    const size_t lds_mfma = 4 * 128 * KPAD * sizeof(unsigned short);  // 72 KB
    const size_t MSZ = (size_t)2 * HID * HID;

    // slots: 0 = W_att(nat), 1 = Wself(T), 2 = M2, 3 = G  — one launch
    k_prep_all<<<dim3(8, 4), 256, 0, stream>>>(W_att, Wself, W_p, W_pp,
                                               phi_w, WA, phi_b, WT, pbA);

    // HB/psi + CSR histogram in one launch
    k_cast_count<<<nbCast + 2 * NC, 256, 0, stream>>>(H, fdef_w, fdef_b, HB, psi,
                                                      etgt, esrc, cnt_t, cnt_s,
                                                      nbCast, NB, NC, E, N);

    // ---- CSR build (no global atomics) ----
    k_csr_scan<<<2, 1024, 0, stream>>>(cnt_t, off_t, cnt_s, off_s, L);
    k_csr_bucket<<<dim3(NC, 2), 256, 0, stream>>>(etgt, esrc, off_t, off_s,
                                                  ebuck_t, ebuck_s, NB, NC, E);
    k_csr_final<<<dim3(NB, 2), 256, 0, stream>>>(off_t, off_s,
                                                 ebuck_t, ebuck_s, base_t, base_s,
                                                 eid_t, eid_s, src_t, tgt_s,
                                                 NB, NC, N, E);

    // HBlo into the now-dead ebuck region
    k_splitlo<<<(N * HID / 8 + 255) / 256, 256, 0, stream>>>(H, HBlo, N * HID / 8);

    GemmArgsT g2;
    g2.Whi[0] = WT;           g2.Wlo[0] = WT + HID * HID;             // W_att
    g2.Whi[1] = WT + 2 * MSZ; g2.Wlo[1] = WT + 2 * MSZ + HID * HID;   // M2
    g2.O[0] = Wt;  g2.of32[0] = 1;
    g2.O[1] = UB;  g2.of32[1] = 0;
    k_gemm<<<dim3(nblk128, 2), 256, lds_mfma, stream>>>(HB, HBlo, g2, N);

    k_score<<<nblkN4, 256, 0, stream>>>(eid_t, base_t, src_t, Wt, UB, HB,
                                        score, pairv, sumt_inv, N);
    k_beta2<<<nblkN4, 256, 0, stream>>>(base_s, eid_s, tgt_s, pairv, psi, rho1m, N);

    k_matt<<<nblkN4, 256, 0, stream>>>(src_t, base_t, score, sumt_inv,
                                       rho1m, HB, aggHi, aggLo, sig, N);

    k_final<<<nblk128, 256, lds_mfma, stream>>>(aggHi, aggLo, HB, HBlo, H,
                                                sig, pbA,
                                                WT + 3 * MSZ, WT + 3 * MSZ + HID * HID,
                                                WT + 1 * MSZ, WT + 1 * MSZ + HID * HID,
                                                Wstr, bself, bA, bstr, lng, lnb, out, N);
}